// Round 1
// baseline (1284.419 us; speedup 1.0000x reference)
//
#include <hip/hip_runtime.h>

#define B_ 2
#define N_ 8192
#define NP 16384   // B_*N_
#define K_ 16
#define H_ 128

typedef short bf16x8 __attribute__((ext_vector_type(8)));
typedef float f32x4 __attribute__((ext_vector_type(4)));

__device__ inline unsigned short f2b(float f) {
    unsigned u = __builtin_bit_cast(unsigned, f);
    unsigned r = (u + 0x7fff + ((u >> 16) & 1)) >> 16;
    return (unsigned short)r;
}
__device__ inline bf16x8 ldb8(const unsigned short* p) {
    return *(const bf16x8*)p;
}

// ---------------- Kernel A: pf = relu(relu(x@We1+be1)@We2+be2); zero gf ----
__global__ __launch_bounds__(256) void k_pf(
    const float* __restrict__ pts, const float* __restrict__ nrm,
    const float* __restrict__ We1, const float* __restrict__ be1,
    const float* __restrict__ We2, const float* __restrict__ be2,
    float* __restrict__ pf, float* __restrict__ gf) {
    __shared__ float w2s[128 * 128];
    __shared__ float w1s[6 * 128];
    __shared__ float b1s[128], b2s[128];
    __shared__ float xs[2][6];
    __shared__ float h1s[2][128];
    int t = threadIdx.x;
    for (int i = t; i < 128 * 128; i += 256) w2s[i] = We2[i];
    for (int i = t; i < 6 * 128; i += 256) w1s[i] = We1[i];
    if (t < 128) { b1s[t] = be1[t]; b2s[t] = be2[t]; }
    if (blockIdx.x == 0) { gf[t] = 0.f; gf[256 + t] = 0.f; }
    __syncthreads();
    int g = t >> 7, h = t & 127;
    int base = blockIdx.x * 64;
    for (int it = 0; it < 32; ++it) {
        int p = base + it * 2 + g;
        if (h < 3) xs[g][h] = pts[p * 3 + h];
        else if (h < 6) xs[g][h] = nrm[p * 3 + h - 3];
        __syncthreads();
        float a = b1s[h];
        #pragma unroll
        for (int c = 0; c < 6; ++c) a += xs[g][c] * w1s[c * 128 + h];
        h1s[g][h] = fmaxf(a, 0.f);
        __syncthreads();
        float o = b2s[h];
        #pragma unroll 8
        for (int c = 0; c < 128; ++c) o += h1s[g][c] * w2s[c * 128 + h];
        pf[p * 128 + h] = fmaxf(o, 0.f);
        __syncthreads();
    }
}

// ---------------- Kernel B: 16-NN (exact f32 formula match, lex tiebreak) --
__global__ __launch_bounds__(64) void k_knn(
    const float* __restrict__ pts, int* __restrict__ knn) {
    int q = blockIdx.x;
    int b = q >> 13, n = q & 8191;
    int l = threadIdx.x;
    const float* pb = pts + b * N_ * 3;
    float qx = pb[n * 3], qy = pb[n * 3 + 1], qz = pb[n * 3 + 2];
    float sq_q = __fadd_rn(__fadd_rn(__fmul_rn(qx, qx), __fmul_rn(qy, qy)), __fmul_rn(qz, qz));
    float bd[16]; int bi[16];
    #pragma unroll
    for (int s = 0; s < 16; ++s) { bd[s] = 1e30f; bi[s] = 0x7fffffff; }
    float wd = 1e30f; int wi = 0x7fffffff; int wslot = 0;
    for (int j = l; j < N_; j += 64) {
        if (j == n) continue;
        float x = pb[j * 3], y = pb[j * 3 + 1], z = pb[j * 3 + 2];
        float sq_j = __fadd_rn(__fadd_rn(__fmul_rn(x, x), __fmul_rn(y, y)), __fmul_rn(z, z));
        float dot = __fadd_rn(__fadd_rn(__fmul_rn(qx, x), __fmul_rn(qy, y)), __fmul_rn(qz, z));
        float d2 = __fsub_rn(__fadd_rn(sq_q, sq_j), __fmul_rn(2.f, dot));
        if (d2 < wd || (d2 == wd && j < wi)) {
            #pragma unroll
            for (int s = 0; s < 16; ++s) if (s == wslot) { bd[s] = d2; bi[s] = j; }
            wd = -1.f; wi = -1; wslot = 0;
            #pragma unroll
            for (int s = 0; s < 16; ++s) {
                bool gt = (bd[s] > wd) || (bd[s] == wd && bi[s] > wi);
                if (gt) { wd = bd[s]; wi = bi[s]; wslot = s; }
            }
        }
    }
    // wave merge: 16 rounds of lex-min extraction
    float md; int mi2, ms2;
    {
        md = 1e30f; mi2 = 0x7fffffff; ms2 = 0;
        #pragma unroll
        for (int s = 0; s < 16; ++s) {
            bool lt = (bd[s] < md) || (bd[s] == md && bi[s] < mi2);
            if (lt) { md = bd[s]; mi2 = bi[s]; ms2 = s; }
        }
    }
    for (int r = 0; r < 16; ++r) {
        float d = md; int i = mi2;
        #pragma unroll
        for (int m = 1; m < 64; m <<= 1) {
            float od = __shfl_xor(d, m);
            int   oi = __shfl_xor(i, m);
            if (od < d || (od == d && oi < i)) { d = od; i = oi; }
        }
        if (l == 0) knn[q * 16 + r] = b * N_ + i;
        if (i == mi2) {
            #pragma unroll
            for (int s = 0; s < 16; ++s) if (s == ms2) { bd[s] = 1e30f; bi[s] = 0x7fffffff; }
            md = 1e30f; mi2 = 0x7fffffff; ms2 = 0;
            #pragma unroll
            for (int s = 0; s < 16; ++s) {
                bool lt = (bd[s] < md) || (bd[s] == md && bi[s] < mi2);
                if (lt) { md = bd[s]; mi2 = bi[s]; ms2 = s; }
            }
        }
    }
}

// ---------------- Kernel C: edge MLP (2 bf16 MFMA GEMMs) + max over K ------
__global__ __launch_bounds__(256) void k_edge(
    const float* __restrict__ pf, const int* __restrict__ knn,
    const float* __restrict__ Wl1, const float* __restrict__ bl1,
    const float* __restrict__ Wl2, const float* __restrict__ bl2,
    float* __restrict__ lf) {
    __shared__ __align__(16) char smem[69632];
    unsigned short* As  = (unsigned short*)smem;             // [128][40] layer1
    unsigned short* Bs  = (unsigned short*)(smem + 10240);   // [128][40] n-major
    unsigned short* h1s = (unsigned short*)smem;             // [128][136]
    unsigned short* w2s = (unsigned short*)(smem + 34816);   // [128][136]
    float* h2f = (float*)smem;                               // [128][132]

    int t = threadIdx.x;
    int l = t & 63, w = t >> 6;
    int wr = w >> 1, wcn = w & 1;
    int rowbase = blockIdx.x * 128;

    f32x4 acc[4][4];
    #pragma unroll
    for (int i = 0; i < 4; ++i)
        #pragma unroll
        for (int j = 0; j < 4; ++j) acc[i][j] = (f32x4){0.f, 0.f, 0.f, 0.f};

    for (int kb = 0; kb < 8; ++kb) {
        #pragma unroll
        for (int ii = 0; ii < 16; ++ii) {
            int i = t + ii * 256;
            int r = i >> 5, c = i & 31;
            int cg = kb * 32 + c;
            int R = rowbase + r, p = R >> 4;
            float v;
            if (cg < 128) v = pf[p * 128 + cg];
            else { int nb = knn[R]; v = pf[nb * 128 + (cg - 128)] - pf[p * 128 + (cg - 128)]; }
            As[r * 40 + c] = f2b(v);
        }
        #pragma unroll
        for (int ii = 0; ii < 16; ++ii) {
            int i = t + ii * 256;
            int c = i >> 7, n = i & 127;
            Bs[n * 40 + c] = f2b(Wl1[(kb * 32 + c) * 128 + n]);
        }
        __syncthreads();
        bf16x8 af[4], bfr[4];
        #pragma unroll
        for (int mi = 0; mi < 4; ++mi)
            af[mi] = ldb8(&As[(wr * 64 + mi * 16 + (l & 15)) * 40 + (l >> 4) * 8]);
        #pragma unroll
        for (int nj = 0; nj < 4; ++nj)
            bfr[nj] = ldb8(&Bs[(wcn * 64 + nj * 16 + (l & 15)) * 40 + (l >> 4) * 8]);
        #pragma unroll
        for (int mi = 0; mi < 4; ++mi)
            #pragma unroll
            for (int nj = 0; nj < 4; ++nj)
                acc[mi][nj] = __builtin_amdgcn_mfma_f32_16x16x32_bf16(af[mi], bfr[nj], acc[mi][nj], 0, 0, 0);
        __syncthreads();
    }
    // h1 = relu(acc + bl1) -> LDS bf16; stage Wl2 transposed
    #pragma unroll
    for (int mi = 0; mi < 4; ++mi)
        #pragma unroll
        for (int nj = 0; nj < 4; ++nj)
            #pragma unroll
            for (int rg = 0; rg < 4; ++rg) {
                int row = wr * 64 + mi * 16 + (l >> 4) * 4 + rg;
                int col = wcn * 64 + nj * 16 + (l & 15);
                float v = acc[mi][nj][rg] + bl1[col];
                h1s[row * 136 + col] = f2b(fmaxf(v, 0.f));
            }
    for (int i = t; i < 128 * 128; i += 256) {
        int c = i >> 7, n = i & 127;
        w2s[n * 136 + c] = f2b(Wl2[c * 128 + n]);
    }
    __syncthreads();
    f32x4 acc2[4][4];
    #pragma unroll
    for (int i = 0; i < 4; ++i)
        #pragma unroll
        for (int j = 0; j < 4; ++j) acc2[i][j] = (f32x4){0.f, 0.f, 0.f, 0.f};
    #pragma unroll
    for (int ks = 0; ks < 4; ++ks) {
        bf16x8 a2[4], b2[4];
        #pragma unroll
        for (int mi = 0; mi < 4; ++mi)
            a2[mi] = ldb8(&h1s[(wr * 64 + mi * 16 + (l & 15)) * 136 + ks * 32 + (l >> 4) * 8]);
        #pragma unroll
        for (int nj = 0; nj < 4; ++nj)
            b2[nj] = ldb8(&w2s[(wcn * 64 + nj * 16 + (l & 15)) * 136 + ks * 32 + (l >> 4) * 8]);
        #pragma unroll
        for (int mi = 0; mi < 4; ++mi)
            #pragma unroll
            for (int nj = 0; nj < 4; ++nj)
                acc2[mi][nj] = __builtin_amdgcn_mfma_f32_16x16x32_bf16(a2[mi], b2[nj], acc2[mi][nj], 0, 0, 0);
    }
    __syncthreads();
    #pragma unroll
    for (int mi = 0; mi < 4; ++mi)
        #pragma unroll
        for (int nj = 0; nj < 4; ++nj)
            #pragma unroll
            for (int rg = 0; rg < 4; ++rg) {
                int row = wr * 64 + mi * 16 + (l >> 4) * 4 + rg;
                int col = wcn * 64 + nj * 16 + (l & 15);
                h2f[row * 132 + col] = fmaxf(acc2[mi][nj][rg] + bl2[col], 0.f);
            }
    __syncthreads();
    for (int o = t; o < 8 * 128; o += 256) {
        int pt = o >> 7, col = o & 127;
        const float* src = &h2f[(pt * 16) * 132 + col];
        float m = src[0];
        #pragma unroll
        for (int r = 1; r < 16; ++r) m = fmaxf(m, src[r * 132]);
        lf[(blockIdx.x * 8 + pt) * 128 + col] = m;
    }
}

// ---------------- Kernel D: ctx = relu([pf,lf]@Wc+bc); gf = max over N -----
__global__ __launch_bounds__(256) void k_ctx(
    const float* __restrict__ pf, const float* __restrict__ lf,
    const float* __restrict__ Wc, const float* __restrict__ bc,
    float* __restrict__ gf) {
    __shared__ __align__(16) char smem[67584];
    unsigned short* As = (unsigned short*)smem;            // [128][40]
    unsigned short* Bs = (unsigned short*)(smem + 10240);  // [128][40]
    float* cs = (float*)smem;                              // [128][132]
    int t = threadIdx.x;
    int l = t & 63, w = t >> 6;
    int wr = w >> 1, wcn = w & 1;
    int rowbase = blockIdx.x * 128;
    int ncol0 = blockIdx.y * 128;
    int b = rowbase >> 13;

    f32x4 acc[4][4];
    #pragma unroll
    for (int i = 0; i < 4; ++i)
        #pragma unroll
        for (int j = 0; j < 4; ++j) acc[i][j] = (f32x4){0.f, 0.f, 0.f, 0.f};

    for (int kb = 0; kb < 8; ++kb) {
        #pragma unroll
        for (int ii = 0; ii < 16; ++ii) {
            int i = t + ii * 256;
            int r = i >> 5, c = i & 31;
            int cg = kb * 32 + c;
            int p = rowbase + r;
            float v = (cg < 128) ? pf[p * 128 + cg] : lf[p * 128 + (cg - 128)];
            As[r * 40 + c] = f2b(v);
        }
        #pragma unroll
        for (int ii = 0; ii < 16; ++ii) {
            int i = t + ii * 256;
            int c = i >> 7, n = i & 127;
            Bs[n * 40 + c] = f2b(Wc[(kb * 32 + c) * 256 + ncol0 + n]);
        }
        __syncthreads();
        bf16x8 af[4], bfr[4];
        #pragma unroll
        for (int mi = 0; mi < 4; ++mi)
            af[mi] = ldb8(&As[(wr * 64 + mi * 16 + (l & 15)) * 40 + (l >> 4) * 8]);
        #pragma unroll
        for (int nj = 0; nj < 4; ++nj)
            bfr[nj] = ldb8(&Bs[(wcn * 64 + nj * 16 + (l & 15)) * 40 + (l >> 4) * 8]);
        #pragma unroll
        for (int mi = 0; mi < 4; ++mi)
            #pragma unroll
            for (int nj = 0; nj < 4; ++nj)
                acc[mi][nj] = __builtin_amdgcn_mfma_f32_16x16x32_bf16(af[mi], bfr[nj], acc[mi][nj], 0, 0, 0);
        __syncthreads();
    }
    #pragma unroll
    for (int mi = 0; mi < 4; ++mi)
        #pragma unroll
        for (int nj = 0; nj < 4; ++nj)
            #pragma unroll
            for (int rg = 0; rg < 4; ++rg) {
                int row = wr * 64 + mi * 16 + (l >> 4) * 4 + rg;
                int col = wcn * 64 + nj * 16 + (l & 15);
                cs[row * 132 + col] = fmaxf(acc[mi][nj][rg] + bc[ncol0 + col], 0.f);
            }
    __syncthreads();
    if (t < 128) {
        float m = 0.f;
        for (int r = 0; r < 128; ++r) m = fmaxf(m, cs[r * 132 + t]);
        atomicMax((unsigned int*)&gf[b * 256 + ncol0 + t], __float_as_uint(m));
    }
}

// ---------------- Kernel E: heads (Wk / Wp branch via blockIdx.y) ----------
__global__ __launch_bounds__(256) void k_head(
    const float* __restrict__ pf, const float* __restrict__ lf, const float* __restrict__ gf,
    const float* __restrict__ Wk1, const float* __restrict__ bk1,
    const float* __restrict__ Wk2, const float* __restrict__ bk2,
    const float* __restrict__ Wp1, const float* __restrict__ bp1,
    const float* __restrict__ Wp2, const float* __restrict__ bp2,
    float* __restrict__ out) {
    __shared__ __align__(16) char smem[67584];
    unsigned short* As = (unsigned short*)smem;
    unsigned short* Bs = (unsigned short*)(smem + 10240);
    float* hs = (float*)smem;  // [128][132]
    int t = threadIdx.x;
    int l = t & 63, w = t >> 6;
    int wr = w >> 1, wcn = w & 1;
    int rowbase = blockIdx.x * 128;
    int br = blockIdx.y;
    const float* W1 = br ? Wp1 : Wk1;
    const float* b1 = br ? bp1 : bk1;
    const float* W2 = br ? Wp2 : Wk2;
    const float* b2p = br ? bp2 : bk2;
    int OC = br ? 8 : 10;
    float* obase = out + (br ? (size_t)NP * 10 : 0);

    f32x4 acc[4][4];
    #pragma unroll
    for (int i = 0; i < 4; ++i)
        #pragma unroll
        for (int j = 0; j < 4; ++j) acc[i][j] = (f32x4){0.f, 0.f, 0.f, 0.f};

    for (int kb = 0; kb < 16; ++kb) {
        #pragma unroll
        for (int ii = 0; ii < 16; ++ii) {
            int i = t + ii * 256;
            int r = i >> 5, c = i & 31;
            int cg = kb * 32 + c;
            int p = rowbase + r;
            float v;
            if (cg < 128) v = pf[p * 128 + cg];
            else if (cg < 256) v = lf[p * 128 + (cg - 128)];
            else v = gf[(p >> 13) * 256 + (cg - 256)];
            As[r * 40 + c] = f2b(v);
        }
        #pragma unroll
        for (int ii = 0; ii < 16; ++ii) {
            int i = t + ii * 256;
            int c = i >> 7, n = i & 127;
            Bs[n * 40 + c] = f2b(W1[(kb * 32 + c) * 128 + n]);
        }
        __syncthreads();
        bf16x8 af[4], bfr[4];
        #pragma unroll
        for (int mi = 0; mi < 4; ++mi)
            af[mi] = ldb8(&As[(wr * 64 + mi * 16 + (l & 15)) * 40 + (l >> 4) * 8]);
        #pragma unroll
        for (int nj = 0; nj < 4; ++nj)
            bfr[nj] = ldb8(&Bs[(wcn * 64 + nj * 16 + (l & 15)) * 40 + (l >> 4) * 8]);
        #pragma unroll
        for (int mi = 0; mi < 4; ++mi)
            #pragma unroll
            for (int nj = 0; nj < 4; ++nj)
                acc[mi][nj] = __builtin_amdgcn_mfma_f32_16x16x32_bf16(af[mi], bfr[nj], acc[mi][nj], 0, 0, 0);
        __syncthreads();
    }
    #pragma unroll
    for (int mi = 0; mi < 4; ++mi)
        #pragma unroll
        for (int nj = 0; nj < 4; ++nj)
            #pragma unroll
            for (int rg = 0; rg < 4; ++rg) {
                int row = wr * 64 + mi * 16 + (l >> 4) * 4 + rg;
                int col = wcn * 64 + nj * 16 + (l & 15);
                hs[row * 132 + col] = fmaxf(acc[mi][nj][rg] + b1[col], 0.f);
            }
    __syncthreads();
    for (int o = t; o < 128 * OC; o += 256) {
        int r = o / OC, c = o % OC;
        float a = b2p[c];
        for (int k2 = 0; k2 < 128; ++k2) a += hs[r * 132 + k2] * W2[k2 * OC + c];
        obase[(size_t)(rowbase + r) * OC + c] = a;
    }
}

extern "C" void kernel_launch(void* const* d_in, const int* in_sizes, int n_in,
                              void* d_out, int out_size, void* d_ws, size_t ws_size,
                              hipStream_t stream) {
    const float* pts = (const float*)d_in[0];
    const float* nrm = (const float*)d_in[1];
    const float* We1 = (const float*)d_in[2];
    const float* be1 = (const float*)d_in[3];
    const float* We2 = (const float*)d_in[4];
    const float* be2 = (const float*)d_in[5];
    const float* Wl1 = (const float*)d_in[6];
    const float* bl1 = (const float*)d_in[7];
    const float* Wl2 = (const float*)d_in[8];
    const float* bl2 = (const float*)d_in[9];
    const float* Wc  = (const float*)d_in[10];
    const float* bc  = (const float*)d_in[11];
    const float* Wk1 = (const float*)d_in[12];
    const float* bk1 = (const float*)d_in[13];
    const float* Wk2 = (const float*)d_in[14];
    const float* bk2 = (const float*)d_in[15];
    const float* Wp1 = (const float*)d_in[16];
    const float* bp1 = (const float*)d_in[17];
    const float* Wp2 = (const float*)d_in[18];
    const float* bp2 = (const float*)d_in[19];
    float* out = (float*)d_out;

    char* ws = (char*)d_ws;
    float* pf = (float*)ws;                                          // 8.39 MB
    float* lf = (float*)(ws + (size_t)NP * 128 * 4);                 // 8.39 MB
    int* knn  = (int*)(ws + (size_t)2 * NP * 128 * 4);               // 1.05 MB
    float* gf = (float*)(ws + (size_t)2 * NP * 128 * 4 + (size_t)NP * 16 * 4);  // 2 KB

    hipLaunchKernelGGL(k_pf, dim3(256), dim3(256), 0, stream,
                       pts, nrm, We1, be1, We2, be2, pf, gf);
    hipLaunchKernelGGL(k_knn, dim3(NP), dim3(64), 0, stream, pts, knn);
    hipLaunchKernelGGL(k_edge, dim3(2048), dim3(256), 0, stream,
                       pf, knn, Wl1, bl1, Wl2, bl2, lf);
    hipLaunchKernelGGL(k_ctx, dim3(128, 2), dim3(256), 0, stream,
                       pf, lf, Wc, bc, gf);
    hipLaunchKernelGGL(k_head, dim3(128, 2), dim3(256), 0, stream,
                       pf, lf, gf, Wk1, bk1, Wk2, bk2, Wp1, bp1, Wp2, bp2, out);
}

// Round 2
// 842.425 us; speedup vs baseline: 1.5247x; 1.5247x over previous
//
#include <hip/hip_runtime.h>

#define B_ 2
#define N_ 8192
#define NP 16384   // B_*N_
#define K_ 16
#define H_ 128
#define KCAP 512

typedef short bf16x8 __attribute__((ext_vector_type(8)));
typedef float f32x4 __attribute__((ext_vector_type(4)));

__device__ inline unsigned short f2b(float f) {
    unsigned u = __builtin_bit_cast(unsigned, f);
    unsigned r = (u + 0x7fff + ((u >> 16) & 1)) >> 16;
    return (unsigned short)r;
}
__device__ inline bf16x8 ldb8(const unsigned short* p) {
    return *(const bf16x8*)p;
}

// ---------------- Kernel A: pf = relu(relu(x@We1+be1)@We2+be2); zero gf ----
__global__ __launch_bounds__(256) void k_pf(
    const float* __restrict__ pts, const float* __restrict__ nrm,
    const float* __restrict__ We1, const float* __restrict__ be1,
    const float* __restrict__ We2, const float* __restrict__ be2,
    float* __restrict__ pf, float* __restrict__ gf) {
    __shared__ float w2s[128 * 128];
    __shared__ float w1s[6 * 128];
    __shared__ float b1s[128], b2s[128];
    __shared__ float xs[2][6];
    __shared__ float h1s[2][128];
    int t = threadIdx.x;
    for (int i = t; i < 128 * 128; i += 256) w2s[i] = We2[i];
    for (int i = t; i < 6 * 128; i += 256) w1s[i] = We1[i];
    if (t < 128) { b1s[t] = be1[t]; b2s[t] = be2[t]; }
    if (blockIdx.x == 0) { gf[t] = 0.f; gf[256 + t] = 0.f; }
    __syncthreads();
    int g = t >> 7, h = t & 127;
    int base = blockIdx.x * 64;
    for (int it = 0; it < 32; ++it) {
        int p = base + it * 2 + g;
        if (h < 3) xs[g][h] = pts[p * 3 + h];
        else if (h < 6) xs[g][h] = nrm[p * 3 + h - 3];
        __syncthreads();
        float a = b1s[h];
        #pragma unroll
        for (int c = 0; c < 6; ++c) a += xs[g][c] * w1s[c * 128 + h];
        h1s[g][h] = fmaxf(a, 0.f);
        __syncthreads();
        float o = b2s[h];
        #pragma unroll 8
        for (int c = 0; c < 128; ++c) o += h1s[g][c] * w2s[c * 128 + h];
        pf[p * 128 + h] = fmaxf(o, 0.f);
        __syncthreads();
    }
}

// ---------------- Kernel A2: pack points to float4 (x,y,z,|p|^2) ----------
__global__ __launch_bounds__(256) void k_pack(
    const float* __restrict__ pts, float4* __restrict__ pts4) {
    int p = blockIdx.x * 256 + threadIdx.x;
    float x = pts[p * 3], y = pts[p * 3 + 1], z = pts[p * 3 + 2];
    // exact same op order as reference sum(p*p, -1): (x*x + y*y) + z*z
    float sq = __fadd_rn(__fadd_rn(__fmul_rn(x, x), __fmul_rn(y, y)), __fmul_rn(z, z));
    pts4[p] = make_float4(x, y, z, sq);
}

// ---------------- Kernel B: 16-NN via histogram filter (exact) ------------
__global__ __launch_bounds__(64) void k_knn(
    const float4* __restrict__ pts4, int* __restrict__ knn) {
    __shared__ int hist[256];
    __shared__ int cnt;
    __shared__ float bufd[KCAP];
    __shared__ int bufi[KCAP];
    int q = blockIdx.x;
    int b = q >> 13, n = q & 8191;
    int l = threadIdx.x;
    const float4* pb = pts4 + b * N_;
    float4 qp = pb[n];  // x,y,z,sq

    for (int i = l; i < 256; i += 64) hist[i] = 0;
    if (l == 0) cnt = 0;
    __syncthreads();

    // pass 1: histogram of d2 (exponent + 2 mantissa bits, offset 400)
    for (int j = l; j < N_; j += 64) {
        float4 c = pb[j];
        float dot = __fadd_rn(__fadd_rn(__fmul_rn(qp.x, c.x), __fmul_rn(qp.y, c.y)), __fmul_rn(qp.z, c.z));
        float d2 = __fsub_rn(__fadd_rn(qp.w, c.w), __fmul_rn(2.f, dot));
        d2 = (j == n) ? 1e30f : d2;  // self -> bucket 255, never selected
        unsigned u = __float_as_uint(d2);
        int bk = (d2 < 0.f) ? 0 : min(255, max(0, (int)(u >> 21) - 400));
        atomicAdd(&hist[bk], 1);
    }
    __syncthreads();

    // wave scan over 256 buckets (4 per lane) -> first bucket with cum >= 16
    int h0 = hist[4 * l], h1 = hist[4 * l + 1], h2 = hist[4 * l + 2], h3 = hist[4 * l + 3];
    int c0 = h0, c1 = c0 + h1, c2 = c1 + h2, c3 = c2 + h3;
    int tot = c3;
    int inc = tot;
    for (int off = 1; off < 64; off <<= 1) {
        int v = __shfl_up(inc, off);
        if (l >= off) inc += v;
    }
    int excl = inc - tot;
    int Bcand = 1024;
    if      (excl + c0 >= 16) Bcand = 4 * l;
    else if (excl + c1 >= 16) Bcand = 4 * l + 1;
    else if (excl + c2 >= 16) Bcand = 4 * l + 2;
    else if (excl + c3 >= 16) Bcand = 4 * l + 3;
    for (int m = 1; m < 64; m <<= 1) Bcand = min(Bcand, __shfl_xor(Bcand, m));
    int B = Bcand;

    // pass 2: append all candidates with bucket <= B (superset of true top-16)
    for (int j = l; j < N_; j += 64) {
        float4 c = pb[j];
        float dot = __fadd_rn(__fadd_rn(__fmul_rn(qp.x, c.x), __fmul_rn(qp.y, c.y)), __fmul_rn(qp.z, c.z));
        float d2 = __fsub_rn(__fadd_rn(qp.w, c.w), __fmul_rn(2.f, dot));
        d2 = (j == n) ? 1e30f : d2;
        unsigned u = __float_as_uint(d2);
        int bk = (d2 < 0.f) ? 0 : min(255, max(0, (int)(u >> 21) - 400));
        if (bk <= B) {
            int pos = atomicAdd(&cnt, 1);
            if (pos < KCAP) { bufd[pos] = d2; bufi[pos] = j; }
        }
    }
    __syncthreads();
    int m_ = min(cnt, KCAP);

    // load keys: monotone-mapped d2 bits << 32 | idx  (u64 compare == lex compare)
    unsigned long long key[8];
    #pragma unroll
    for (int r = 0; r < 8; ++r) {
        int e = l + 64 * r;
        if (e < m_) {
            unsigned du = __float_as_uint(bufd[e]);
            unsigned mu = du ^ (unsigned)(((int)du >> 31) | 0x80000000);
            key[r] = ((unsigned long long)mu << 32) | (unsigned)bufi[e];
        } else key[r] = ~0ull;
    }
    // 16 rounds of wave-min extraction
    for (int r16 = 0; r16 < 16; ++r16) {
        unsigned long long mn = key[0];
        #pragma unroll
        for (int r = 1; r < 8; ++r) mn = (key[r] < mn) ? key[r] : mn;
        unsigned long long w = mn;
        for (int m = 1; m < 64; m <<= 1) {
            unsigned long long o = __shfl_xor(w, m);
            w = (o < w) ? o : w;
        }
        if (l == 0) knn[(size_t)q * 16 + r16] = b * N_ + (int)(w & 0xffffffffu);
        #pragma unroll
        for (int r = 0; r < 8; ++r) if (key[r] == w) key[r] = ~0ull;
    }
}

// ---------------- Kernel C: edge MLP (2 bf16 MFMA GEMMs) + max over K ------
__global__ __launch_bounds__(256) void k_edge(
    const float* __restrict__ pf, const int* __restrict__ knn,
    const float* __restrict__ Wl1, const float* __restrict__ bl1,
    const float* __restrict__ Wl2, const float* __restrict__ bl2,
    float* __restrict__ lf) {
    __shared__ __align__(16) char smem[69632];
    unsigned short* As  = (unsigned short*)smem;             // [128][40] layer1
    unsigned short* Bs  = (unsigned short*)(smem + 10240);   // [128][40] n-major
    unsigned short* h1s = (unsigned short*)smem;             // [128][136]
    unsigned short* w2s = (unsigned short*)(smem + 34816);   // [128][136]
    float* h2f = (float*)smem;                               // [128][132]

    int t = threadIdx.x;
    int l = t & 63, w = t >> 6;
    int wr = w >> 1, wcn = w & 1;
    int rowbase = blockIdx.x * 128;

    f32x4 acc[4][4];
    #pragma unroll
    for (int i = 0; i < 4; ++i)
        #pragma unroll
        for (int j = 0; j < 4; ++j) acc[i][j] = (f32x4){0.f, 0.f, 0.f, 0.f};

    for (int kb = 0; kb < 8; ++kb) {
        #pragma unroll
        for (int ii = 0; ii < 16; ++ii) {
            int i = t + ii * 256;
            int r = i >> 5, c = i & 31;
            int cg = kb * 32 + c;
            int R = rowbase + r, p = R >> 4;
            float v;
            if (cg < 128) v = pf[p * 128 + cg];
            else { int nb = knn[R]; v = pf[nb * 128 + (cg - 128)] - pf[p * 128 + (cg - 128)]; }
            As[r * 40 + c] = f2b(v);
        }
        #pragma unroll
        for (int ii = 0; ii < 16; ++ii) {
            int i = t + ii * 256;
            int c = i >> 7, n = i & 127;
            Bs[n * 40 + c] = f2b(Wl1[(kb * 32 + c) * 128 + n]);
        }
        __syncthreads();
        bf16x8 af[4], bfr[4];
        #pragma unroll
        for (int mi = 0; mi < 4; ++mi)
            af[mi] = ldb8(&As[(wr * 64 + mi * 16 + (l & 15)) * 40 + (l >> 4) * 8]);
        #pragma unroll
        for (int nj = 0; nj < 4; ++nj)
            bfr[nj] = ldb8(&Bs[(wcn * 64 + nj * 16 + (l & 15)) * 40 + (l >> 4) * 8]);
        #pragma unroll
        for (int mi = 0; mi < 4; ++mi)
            #pragma unroll
            for (int nj = 0; nj < 4; ++nj)
                acc[mi][nj] = __builtin_amdgcn_mfma_f32_16x16x32_bf16(af[mi], bfr[nj], acc[mi][nj], 0, 0, 0);
        __syncthreads();
    }
    // h1 = relu(acc + bl1) -> LDS bf16; stage Wl2 transposed
    #pragma unroll
    for (int mi = 0; mi < 4; ++mi)
        #pragma unroll
        for (int nj = 0; nj < 4; ++nj)
            #pragma unroll
            for (int rg = 0; rg < 4; ++rg) {
                int row = wr * 64 + mi * 16 + (l >> 4) * 4 + rg;
                int col = wcn * 64 + nj * 16 + (l & 15);
                float v = acc[mi][nj][rg] + bl1[col];
                h1s[row * 136 + col] = f2b(fmaxf(v, 0.f));
            }
    for (int i = t; i < 128 * 128; i += 256) {
        int c = i >> 7, n = i & 127;
        w2s[n * 136 + c] = f2b(Wl2[c * 128 + n]);
    }
    __syncthreads();
    f32x4 acc2[4][4];
    #pragma unroll
    for (int i = 0; i < 4; ++i)
        #pragma unroll
        for (int j = 0; j < 4; ++j) acc2[i][j] = (f32x4){0.f, 0.f, 0.f, 0.f};
    #pragma unroll
    for (int ks = 0; ks < 4; ++ks) {
        bf16x8 a2[4], b2[4];
        #pragma unroll
        for (int mi = 0; mi < 4; ++mi)
            a2[mi] = ldb8(&h1s[(wr * 64 + mi * 16 + (l & 15)) * 136 + ks * 32 + (l >> 4) * 8]);
        #pragma unroll
        for (int nj = 0; nj < 4; ++nj)
            b2[nj] = ldb8(&w2s[(wcn * 64 + nj * 16 + (l & 15)) * 136 + ks * 32 + (l >> 4) * 8]);
        #pragma unroll
        for (int mi = 0; mi < 4; ++mi)
            #pragma unroll
            for (int nj = 0; nj < 4; ++nj)
                acc2[mi][nj] = __builtin_amdgcn_mfma_f32_16x16x32_bf16(a2[mi], b2[nj], acc2[mi][nj], 0, 0, 0);
    }
    __syncthreads();
    #pragma unroll
    for (int mi = 0; mi < 4; ++mi)
        #pragma unroll
        for (int nj = 0; nj < 4; ++nj)
            #pragma unroll
            for (int rg = 0; rg < 4; ++rg) {
                int row = wr * 64 + mi * 16 + (l >> 4) * 4 + rg;
                int col = wcn * 64 + nj * 16 + (l & 15);
                h2f[row * 132 + col] = fmaxf(acc2[mi][nj][rg] + bl2[col], 0.f);
            }
    __syncthreads();
    for (int o = t; o < 8 * 128; o += 256) {
        int pt = o >> 7, col = o & 127;
        const float* src = &h2f[(pt * 16) * 132 + col];
        float m = src[0];
        #pragma unroll
        for (int r = 1; r < 16; ++r) m = fmaxf(m, src[r * 132]);
        lf[(blockIdx.x * 8 + pt) * 128 + col] = m;
    }
}

// ---------------- Kernel D: ctx = relu([pf,lf]@Wc+bc); gf = max over N -----
__global__ __launch_bounds__(256) void k_ctx(
    const float* __restrict__ pf, const float* __restrict__ lf,
    const float* __restrict__ Wc, const float* __restrict__ bc,
    float* __restrict__ gf) {
    __shared__ __align__(16) char smem[67584];
    unsigned short* As = (unsigned short*)smem;            // [128][40]
    unsigned short* Bs = (unsigned short*)(smem + 10240);  // [128][40]
    float* cs = (float*)smem;                              // [128][132]
    int t = threadIdx.x;
    int l = t & 63, w = t >> 6;
    int wr = w >> 1, wcn = w & 1;
    int rowbase = blockIdx.x * 128;
    int ncol0 = blockIdx.y * 128;
    int b = rowbase >> 13;

    f32x4 acc[4][4];
    #pragma unroll
    for (int i = 0; i < 4; ++i)
        #pragma unroll
        for (int j = 0; j < 4; ++j) acc[i][j] = (f32x4){0.f, 0.f, 0.f, 0.f};

    for (int kb = 0; kb < 8; ++kb) {
        #pragma unroll
        for (int ii = 0; ii < 16; ++ii) {
            int i = t + ii * 256;
            int r = i >> 5, c = i & 31;
            int cg = kb * 32 + c;
            int p = rowbase + r;
            float v = (cg < 128) ? pf[p * 128 + cg] : lf[p * 128 + (cg - 128)];
            As[r * 40 + c] = f2b(v);
        }
        #pragma unroll
        for (int ii = 0; ii < 16; ++ii) {
            int i = t + ii * 256;
            int c = i >> 7, n = i & 127;
            Bs[n * 40 + c] = f2b(Wc[(kb * 32 + c) * 256 + ncol0 + n]);
        }
        __syncthreads();
        bf16x8 af[4], bfr[4];
        #pragma unroll
        for (int mi = 0; mi < 4; ++mi)
            af[mi] = ldb8(&As[(wr * 64 + mi * 16 + (l & 15)) * 40 + (l >> 4) * 8]);
        #pragma unroll
        for (int nj = 0; nj < 4; ++nj)
            bfr[nj] = ldb8(&Bs[(wcn * 64 + nj * 16 + (l & 15)) * 40 + (l >> 4) * 8]);
        #pragma unroll
        for (int mi = 0; mi < 4; ++mi)
            #pragma unroll
            for (int nj = 0; nj < 4; ++nj)
                acc[mi][nj] = __builtin_amdgcn_mfma_f32_16x16x32_bf16(af[mi], bfr[nj], acc[mi][nj], 0, 0, 0);
        __syncthreads();
    }
    #pragma unroll
    for (int mi = 0; mi < 4; ++mi)
        #pragma unroll
        for (int nj = 0; nj < 4; ++nj)
            #pragma unroll
            for (int rg = 0; rg < 4; ++rg) {
                int row = wr * 64 + mi * 16 + (l >> 4) * 4 + rg;
                int col = wcn * 64 + nj * 16 + (l & 15);
                cs[row * 132 + col] = fmaxf(acc[mi][nj][rg] + bc[ncol0 + col], 0.f);
            }
    __syncthreads();
    if (t < 128) {
        float m = 0.f;
        for (int r = 0; r < 128; ++r) m = fmaxf(m, cs[r * 132 + t]);
        atomicMax((unsigned int*)&gf[b * 256 + ncol0 + t], __float_as_uint(m));
    }
}

// ---------------- Kernel E: heads (Wk / Wp branch via blockIdx.y) ----------
__global__ __launch_bounds__(256) void k_head(
    const float* __restrict__ pf, const float* __restrict__ lf, const float* __restrict__ gf,
    const float* __restrict__ Wk1, const float* __restrict__ bk1,
    const float* __restrict__ Wk2, const float* __restrict__ bk2,
    const float* __restrict__ Wp1, const float* __restrict__ bp1,
    const float* __restrict__ Wp2, const float* __restrict__ bp2,
    float* __restrict__ out) {
    __shared__ __align__(16) char smem[67584];
    unsigned short* As = (unsigned short*)smem;
    unsigned short* Bs = (unsigned short*)(smem + 10240);
    float* hs = (float*)smem;  // [128][132]
    int t = threadIdx.x;
    int l = t & 63, w = t >> 6;
    int wr = w >> 1, wcn = w & 1;
    int rowbase = blockIdx.x * 128;
    int br = blockIdx.y;
    const float* W1 = br ? Wp1 : Wk1;
    const float* b1 = br ? bp1 : bk1;
    const float* W2 = br ? Wp2 : Wk2;
    const float* b2p = br ? bp2 : bk2;
    int OC = br ? 8 : 10;
    float* obase = out + (br ? (size_t)NP * 10 : 0);

    f32x4 acc[4][4];
    #pragma unroll
    for (int i = 0; i < 4; ++i)
        #pragma unroll
        for (int j = 0; j < 4; ++j) acc[i][j] = (f32x4){0.f, 0.f, 0.f, 0.f};

    for (int kb = 0; kb < 16; ++kb) {
        #pragma unroll
        for (int ii = 0; ii < 16; ++ii) {
            int i = t + ii * 256;
            int r = i >> 5, c = i & 31;
            int cg = kb * 32 + c;
            int p = rowbase + r;
            float v;
            if (cg < 128) v = pf[p * 128 + cg];
            else if (cg < 256) v = lf[p * 128 + (cg - 128)];
            else v = gf[(p >> 13) * 256 + (cg - 256)];
            As[r * 40 + c] = f2b(v);
        }
        #pragma unroll
        for (int ii = 0; ii < 16; ++ii) {
            int i = t + ii * 256;
            int c = i >> 7, n = i & 127;
            Bs[n * 40 + c] = f2b(W1[(kb * 32 + c) * 128 + n]);
        }
        __syncthreads();
        bf16x8 af[4], bfr[4];
        #pragma unroll
        for (int mi = 0; mi < 4; ++mi)
            af[mi] = ldb8(&As[(wr * 64 + mi * 16 + (l & 15)) * 40 + (l >> 4) * 8]);
        #pragma unroll
        for (int nj = 0; nj < 4; ++nj)
            bfr[nj] = ldb8(&Bs[(wcn * 64 + nj * 16 + (l & 15)) * 40 + (l >> 4) * 8]);
        #pragma unroll
        for (int mi = 0; mi < 4; ++mi)
            #pragma unroll
            for (int nj = 0; nj < 4; ++nj)
                acc[mi][nj] = __builtin_amdgcn_mfma_f32_16x16x32_bf16(af[mi], bfr[nj], acc[mi][nj], 0, 0, 0);
        __syncthreads();
    }
    #pragma unroll
    for (int mi = 0; mi < 4; ++mi)
        #pragma unroll
        for (int nj = 0; nj < 4; ++nj)
            #pragma unroll
            for (int rg = 0; rg < 4; ++rg) {
                int row = wr * 64 + mi * 16 + (l >> 4) * 4 + rg;
                int col = wcn * 64 + nj * 16 + (l & 15);
                hs[row * 132 + col] = fmaxf(acc[mi][nj][rg] + b1[col], 0.f);
            }
    __syncthreads();
    for (int o = t; o < 128 * OC; o += 256) {
        int r = o / OC, c = o % OC;
        float a = b2p[c];
        for (int k2 = 0; k2 < 128; ++k2) a += hs[r * 132 + k2] * W2[k2 * OC + c];
        obase[(size_t)(rowbase + r) * OC + c] = a;
    }
}

extern "C" void kernel_launch(void* const* d_in, const int* in_sizes, int n_in,
                              void* d_out, int out_size, void* d_ws, size_t ws_size,
                              hipStream_t stream) {
    const float* pts = (const float*)d_in[0];
    const float* nrm = (const float*)d_in[1];
    const float* We1 = (const float*)d_in[2];
    const float* be1 = (const float*)d_in[3];
    const float* We2 = (const float*)d_in[4];
    const float* be2 = (const float*)d_in[5];
    const float* Wl1 = (const float*)d_in[6];
    const float* bl1 = (const float*)d_in[7];
    const float* Wl2 = (const float*)d_in[8];
    const float* bl2 = (const float*)d_in[9];
    const float* Wc  = (const float*)d_in[10];
    const float* bc  = (const float*)d_in[11];
    const float* Wk1 = (const float*)d_in[12];
    const float* bk1 = (const float*)d_in[13];
    const float* Wk2 = (const float*)d_in[14];
    const float* bk2 = (const float*)d_in[15];
    const float* Wp1 = (const float*)d_in[16];
    const float* bp1 = (const float*)d_in[17];
    const float* Wp2 = (const float*)d_in[18];
    const float* bp2 = (const float*)d_in[19];
    float* out = (float*)d_out;

    char* ws = (char*)d_ws;
    float* pf = (float*)ws;                                          // 8.39 MB
    float* lf = (float*)(ws + (size_t)NP * 128 * 4);                 // 8.39 MB
    int* knn  = (int*)(ws + (size_t)2 * NP * 128 * 4);               // 1.05 MB
    float* gf = (float*)(ws + (size_t)2 * NP * 128 * 4 + (size_t)NP * 16 * 4);  // 2 KB
    float4* pts4 = (float4*)(ws + (size_t)2 * NP * 128 * 4 + (size_t)NP * 16 * 4 + 2048);  // 256 KB

    hipLaunchKernelGGL(k_pf, dim3(256), dim3(256), 0, stream,
                       pts, nrm, We1, be1, We2, be2, pf, gf);
    hipLaunchKernelGGL(k_pack, dim3(NP / 256), dim3(256), 0, stream, pts, pts4);
    hipLaunchKernelGGL(k_knn, dim3(NP), dim3(64), 0, stream, pts4, knn);
    hipLaunchKernelGGL(k_edge, dim3(2048), dim3(256), 0, stream,
                       pf, knn, Wl1, bl1, Wl2, bl2, lf);
    hipLaunchKernelGGL(k_ctx, dim3(128, 2), dim3(256), 0, stream,
                       pf, lf, Wc, bc, gf);
    hipLaunchKernelGGL(k_head, dim3(128, 2), dim3(256), 0, stream,
                       pf, lf, gf, Wk1, bk1, Wk2, bk2, Wp1, bp1, Wp2, bp2, out);
}

// Round 4
// 494.500 us; speedup vs baseline: 2.5974x; 1.7036x over previous
//
#include <hip/hip_runtime.h>

#define B_ 2
#define N_ 8192
#define NP 16384   // B_*N_
#define K_ 16
#define H_ 128

typedef short bf16x8 __attribute__((ext_vector_type(8)));
typedef float f32x4 __attribute__((ext_vector_type(4)));

__device__ inline unsigned short f2b(float f) {
    unsigned u = __builtin_bit_cast(unsigned, f);
    unsigned r = (u + 0x7fff + ((u >> 16) & 1)) >> 16;
    return (unsigned short)r;
}
__device__ inline bf16x8 ldb8(const unsigned short* p) {
    return *(const bf16x8*)p;
}

// ---------------- Kernel A: pf = relu(relu(x@We1+be1)@We2+be2); zero gf ----
__global__ __launch_bounds__(256) void k_pf(
    const float* __restrict__ pts, const float* __restrict__ nrm,
    const float* __restrict__ We1, const float* __restrict__ be1,
    const float* __restrict__ We2, const float* __restrict__ be2,
    float* __restrict__ pf, float* __restrict__ gf) {
    __shared__ float w2s[128 * 128];
    __shared__ float w1s[6 * 128];
    __shared__ float b1s[128], b2s[128];
    __shared__ float xs[2][6];
    __shared__ float h1s[2][128];
    int t = threadIdx.x;
    for (int i = t; i < 128 * 128; i += 256) w2s[i] = We2[i];
    for (int i = t; i < 6 * 128; i += 256) w1s[i] = We1[i];
    if (t < 128) { b1s[t] = be1[t]; b2s[t] = be2[t]; }
    if (blockIdx.x == 0) { gf[t] = 0.f; gf[256 + t] = 0.f; }
    __syncthreads();
    int g = t >> 7, h = t & 127;
    int base = blockIdx.x * 64;
    for (int it = 0; it < 32; ++it) {
        int p = base + it * 2 + g;
        if (h < 3) xs[g][h] = pts[p * 3 + h];
        else if (h < 6) xs[g][h] = nrm[p * 3 + h - 3];
        __syncthreads();
        float a = b1s[h];
        #pragma unroll
        for (int c = 0; c < 6; ++c) a += xs[g][c] * w1s[c * 128 + h];
        h1s[g][h] = fmaxf(a, 0.f);
        __syncthreads();
        float o = b2s[h];
        #pragma unroll 8
        for (int c = 0; c < 128; ++c) o += h1s[g][c] * w2s[c * 128 + h];
        pf[p * 128 + h] = fmaxf(o, 0.f);
        __syncthreads();
    }
}

// ---------------- Kernel A2: pack points to float4 (x,y,z,|p|^2) ----------
__global__ __launch_bounds__(256) void k_pack(
    const float* __restrict__ pts, float4* __restrict__ pts4) {
    int p = blockIdx.x * 256 + threadIdx.x;
    float x = pts[p * 3], y = pts[p * 3 + 1], z = pts[p * 3 + 2];
    float sq = __fadd_rn(__fadd_rn(__fmul_rn(x, x), __fmul_rn(y, y)), __fmul_rn(z, z));
    pts4[p] = make_float4(x, y, z, sq);
}

// ---------------- Kernel P: prep factored weights ---------------------------
// Wuvcat[k][n]: n<128 -> Wl1_top - Wl1_bot ; n>=128 -> Wl1_bot
// bias_cat: [bl1, 0]; Wl2T bf16 [n][k]
__global__ __launch_bounds__(256) void k_prep(
    const float* __restrict__ Wl1, const float* __restrict__ bl1,
    const float* __restrict__ Wl2,
    float* __restrict__ Wuvcat, float* __restrict__ bias_cat,
    unsigned short* __restrict__ Wl2T) {
    int tid = blockIdx.x * 256 + threadIdx.x;
    int stride = gridDim.x * 256;
    for (int i = tid; i < 128 * 256; i += stride) {
        int k = i >> 8, n = i & 255;
        float val;
        if (n < 128) val = Wl1[k * 128 + n] - Wl1[(k + 128) * 128 + n];
        else         val = Wl1[(k + 128) * 128 + (n - 128)];
        Wuvcat[i] = val;
    }
    for (int i = tid; i < 256; i += stride) bias_cat[i] = (i < 128) ? bl1[i] : 0.f;
    for (int i = tid; i < 128 * 128; i += stride) {
        int n = i >> 7, k = i & 127;
        Wl2T[i] = f2b(Wl2[k * 128 + n]);
    }
}

// ---------------- Kernel B: 16-NN, 4 queries/block, LDS-tiled candidates ---
__global__ __launch_bounds__(256) void k_knn(
    const float4* __restrict__ pts4, int* __restrict__ knn) {
    __shared__ float4 tile[1024];                  // 16 KB
    __shared__ int hist[4][256];                   // 4 KB
    __shared__ unsigned long long buf[4][256];     // 8 KB
    int t = threadIdx.x, w = t >> 6, l = t & 63;
    int b = blockIdx.x >> 11;
    int q = (blockIdx.x & 2047) * 4 + w;
    const float4* pb = pts4 + b * N_;
    float4 qp = pb[q];
    for (int i = l; i < 256; i += 64) hist[w][i] = 0;
    __syncthreads();

    // pass 1: per-wave histogram over all candidates (LDS-tiled)
    for (int t0 = 0; t0 < N_; t0 += 1024) {
        #pragma unroll
        for (int i = 0; i < 4; ++i) tile[t + 256 * i] = pb[t0 + t + 256 * i];
        __syncthreads();
        #pragma unroll 4
        for (int j = l; j < 1024; j += 64) {
            float4 c = tile[j];
            float dot = __fadd_rn(__fadd_rn(__fmul_rn(qp.x, c.x), __fmul_rn(qp.y, c.y)), __fmul_rn(qp.z, c.z));
            float d2 = __fsub_rn(__fadd_rn(qp.w, c.w), __fmul_rn(2.f, dot));
            d2 = (t0 + j == q) ? 1e30f : d2;
            unsigned uu = __float_as_uint(d2);
            int bk = (d2 < 0.f) ? 0 : min(255, max(0, (int)(uu >> 21) - 400));
            atomicAdd(&hist[w][bk], 1);
        }
        __syncthreads();
    }

    // per-wave scan: first bucket B with cumcount >= 16
    int h0 = hist[w][4 * l], h1 = hist[w][4 * l + 1], h2 = hist[w][4 * l + 2], h3 = hist[w][4 * l + 3];
    int c0 = h0, c1 = c0 + h1, c2 = c1 + h2, c3 = c2 + h3;
    int tot = c3;
    int inc = tot;
    for (int off = 1; off < 64; off <<= 1) {
        int vv = __shfl_up(inc, off);
        if (l >= off) inc += vv;
    }
    int excl = inc - tot;
    int Bc = 1024;
    if      (excl + c0 >= 16) Bc = 4 * l;
    else if (excl + c1 >= 16) Bc = 4 * l + 1;
    else if (excl + c2 >= 16) Bc = 4 * l + 2;
    else if (excl + c3 >= 16) Bc = 4 * l + 3;
    for (int m = 1; m < 64; m <<= 1) Bc = min(Bc, __shfl_xor(Bc, m));
    int Bsel = Bc;

    // pass 2: append survivors (ballot-compacted, no atomics)
    int cntw = 0;
    for (int t0 = 0; t0 < N_; t0 += 1024) {
        #pragma unroll
        for (int i = 0; i < 4; ++i) tile[t + 256 * i] = pb[t0 + t + 256 * i];
        __syncthreads();
        for (int j = l; j < 1024; j += 64) {
            float4 c = tile[j];
            float dot = __fadd_rn(__fadd_rn(__fmul_rn(qp.x, c.x), __fmul_rn(qp.y, c.y)), __fmul_rn(qp.z, c.z));
            float d2 = __fsub_rn(__fadd_rn(qp.w, c.w), __fmul_rn(2.f, dot));
            d2 = (t0 + j == q) ? 1e30f : d2;
            unsigned uu = __float_as_uint(d2);
            int bk = (d2 < 0.f) ? 0 : min(255, max(0, (int)(uu >> 21) - 400));
            bool take = (bk <= Bsel);
            unsigned long long mask = __ballot(take);
            if (take) {
                unsigned du = __float_as_uint(d2);
                unsigned mu = du ^ (unsigned)(((int)du >> 31) | 0x80000000);
                int pos = cntw + __popcll(mask & ((1ull << l) - 1ull));
                if (pos < 256) buf[w][pos] = ((unsigned long long)mu << 32) | (unsigned)(t0 + j);
            }
            cntw += __popcll(mask);
        }
        __syncthreads();
    }
    int m_ = min(cntw, 256);

    unsigned long long key[4];
    #pragma unroll
    for (int r = 0; r < 4; ++r) {
        int e = l + 64 * r;
        key[r] = (e < m_) ? buf[w][e] : ~0ull;
    }
    for (int r16 = 0; r16 < 16; ++r16) {
        unsigned long long mn = key[0];
        #pragma unroll
        for (int r = 1; r < 4; ++r) mn = (key[r] < mn) ? key[r] : mn;
        unsigned long long wv = mn;
        for (int m = 1; m < 64; m <<= 1) {
            unsigned long long o = __shfl_xor(wv, m);
            wv = (o < wv) ? o : wv;
        }
        if (l == 0) knn[((size_t)b * N_ + q) * 16 + r16] = b * N_ + (int)(wv & 0xffffffffu);
        #pragma unroll
        for (int r = 0; r < 4; ++r) if (key[r] == wv) key[r] = ~0ull;
    }
}

// ---------------- Kernel U: uv = pf @ Wuvcat + bias_cat (no relu) ----------
__global__ __launch_bounds__(256) void k_uv(
    const float* __restrict__ pf, const float* __restrict__ Wuvcat,
    const float* __restrict__ bias_cat,
    float* __restrict__ u, float* __restrict__ v) {
    __shared__ __align__(16) char smem[20480];
    unsigned short* As = (unsigned short*)smem;            // [128][40]
    unsigned short* Bs = (unsigned short*)(smem + 10240);  // [128][40]
    int t = threadIdx.x;
    int l = t & 63, w = t >> 6;
    int wr = w >> 1, wcn = w & 1;
    int rowbase = blockIdx.x * 128;
    int ncol0 = blockIdx.y * 128;

    f32x4 acc[4][4];
    #pragma unroll
    for (int i = 0; i < 4; ++i)
        #pragma unroll
        for (int j = 0; j < 4; ++j) acc[i][j] = (f32x4){0.f, 0.f, 0.f, 0.f};

    for (int kb = 0; kb < 4; ++kb) {
        #pragma unroll
        for (int ii = 0; ii < 16; ++ii) {
            int i = t + ii * 256;
            int r = i >> 5, c = i & 31;
            As[r * 40 + c] = f2b(pf[(rowbase + r) * 128 + kb * 32 + c]);
        }
        #pragma unroll
        for (int ii = 0; ii < 16; ++ii) {
            int i = t + ii * 256;
            int c = i >> 7, n = i & 127;
            Bs[n * 40 + c] = f2b(Wuvcat[(kb * 32 + c) * 256 + ncol0 + n]);
        }
        __syncthreads();
        bf16x8 af[4], bfr[4];
        #pragma unroll
        for (int mi = 0; mi < 4; ++mi)
            af[mi] = ldb8(&As[(wr * 64 + mi * 16 + (l & 15)) * 40 + (l >> 4) * 8]);
        #pragma unroll
        for (int nj = 0; nj < 4; ++nj)
            bfr[nj] = ldb8(&Bs[(wcn * 64 + nj * 16 + (l & 15)) * 40 + (l >> 4) * 8]);
        #pragma unroll
        for (int mi = 0; mi < 4; ++mi)
            #pragma unroll
            for (int nj = 0; nj < 4; ++nj)
                acc[mi][nj] = __builtin_amdgcn_mfma_f32_16x16x32_bf16(af[mi], bfr[nj], acc[mi][nj], 0, 0, 0);
        __syncthreads();
    }
    float* outp = (ncol0 == 0) ? u : v;
    #pragma unroll
    for (int mi = 0; mi < 4; ++mi)
        #pragma unroll
        for (int nj = 0; nj < 4; ++nj) {
            int col = wcn * 64 + nj * 16 + (l & 15);
            float bias = bias_cat[ncol0 + col];
            #pragma unroll
            for (int rg = 0; rg < 4; ++rg) {
                int row = wr * 64 + mi * 16 + (l >> 4) * 4 + rg;
                outp[(size_t)(rowbase + row) * 128 + col] = acc[mi][nj][rg] + bias;
            }
        }
}

// ---------------- Kernel C: edge layer2 GEMM + max over K ------------------
// h1[p,k] = relu(u[p] + v[nbr]) staged bf16; lf = max_k relu(h1@Wl2 + bl2)
__global__ __launch_bounds__(256) void k_edge(
    const float* __restrict__ u, const float* __restrict__ v,
    const int* __restrict__ knn, const unsigned short* __restrict__ Wl2T,
    const float* __restrict__ bl2, float* __restrict__ lf) {
    __shared__ __align__(16) unsigned short h1s[128 * 136];  // 34816 B
    int t = threadIdx.x;
    int l = t & 63, w = t >> 6;
    int wr = w >> 1, wcn = w & 1;
    int rowbase = blockIdx.x * 128;
    int p0 = blockIdx.x * 8;

    // stage h1 tile: 2048 chunks of 8 bf16 (b128 writes)
    #pragma unroll 2
    for (int i = 0; i < 8; ++i) {
        int ci = t + 256 * i;
        int r = ci >> 4, c8 = (ci & 15) * 8;
        int nb = knn[rowbase + r];
        int pt = p0 + (r >> 4);
        const float4* vp = (const float4*)(v + (size_t)nb * 128 + c8);
        const float4* up = (const float4*)(u + (size_t)pt * 128 + c8);
        float4 va = vp[0], vb = vp[1];
        float4 ua = up[0], ub = up[1];
        unsigned d0 = (unsigned)f2b(fmaxf(ua.x + va.x, 0.f)) | ((unsigned)f2b(fmaxf(ua.y + va.y, 0.f)) << 16);
        unsigned d1 = (unsigned)f2b(fmaxf(ua.z + va.z, 0.f)) | ((unsigned)f2b(fmaxf(ua.w + va.w, 0.f)) << 16);
        unsigned d2 = (unsigned)f2b(fmaxf(ub.x + vb.x, 0.f)) | ((unsigned)f2b(fmaxf(ub.y + vb.y, 0.f)) << 16);
        unsigned d3 = (unsigned)f2b(fmaxf(ub.z + vb.z, 0.f)) | ((unsigned)f2b(fmaxf(ub.w + vb.w, 0.f)) << 16);
        uint4 pk; pk.x = d0; pk.y = d1; pk.z = d2; pk.w = d3;
        *(uint4*)&h1s[r * 136 + c8] = pk;
    }
    __syncthreads();

    f32x4 acc[4][4];
    #pragma unroll
    for (int i = 0; i < 4; ++i)
        #pragma unroll
        for (int j = 0; j < 4; ++j) acc[i][j] = (f32x4){0.f, 0.f, 0.f, 0.f};

    #pragma unroll
    for (int ks = 0; ks < 4; ++ks) {
        bf16x8 bfr[4], afr[4];
        #pragma unroll
        for (int nj = 0; nj < 4; ++nj)
            bfr[nj] = ldb8(&Wl2T[(size_t)(wcn * 64 + nj * 16 + (l & 15)) * 128 + ks * 32 + (l >> 4) * 8]);
        #pragma unroll
        for (int mi = 0; mi < 4; ++mi)
            afr[mi] = ldb8(&h1s[(wr * 64 + mi * 16 + (l & 15)) * 136 + ks * 32 + (l >> 4) * 8]);
        #pragma unroll
        for (int mi = 0; mi < 4; ++mi)
            #pragma unroll
            for (int nj = 0; nj < 4; ++nj)
                acc[mi][nj] = __builtin_amdgcn_mfma_f32_16x16x32_bf16(afr[mi], bfr[nj], acc[mi][nj], 0, 0, 0);
    }

    // epilogue: relu(acc + bl2), max over the 16 rows (= K neighbors) per point
    #pragma unroll
    for (int mi = 0; mi < 4; ++mi)
        #pragma unroll
        for (int nj = 0; nj < 4; ++nj) {
            int col = wcn * 64 + nj * 16 + (l & 15);
            float bias = bl2[col];
            float m = fmaxf(acc[mi][nj][0] + bias, 0.f);
            m = fmaxf(m, fmaxf(acc[mi][nj][1] + bias, 0.f));
            m = fmaxf(m, fmaxf(acc[mi][nj][2] + bias, 0.f));
            m = fmaxf(m, fmaxf(acc[mi][nj][3] + bias, 0.f));
            m = fmaxf(m, __shfl_xor(m, 16));
            m = fmaxf(m, __shfl_xor(m, 32));
            if (l < 16) lf[(size_t)(p0 + wr * 4 + mi) * 128 + col] = m;
        }
}

// ---------------- Kernel D: ctx = relu([pf,lf]@Wc+bc); gf = max over N -----
__global__ __launch_bounds__(256) void k_ctx(
    const float* __restrict__ pf, const float* __restrict__ lf,
    const float* __restrict__ Wc, const float* __restrict__ bc,
    float* __restrict__ gf) {
    __shared__ __align__(16) char smem[67584];
    unsigned short* As = (unsigned short*)smem;            // [128][40]
    unsigned short* Bs = (unsigned short*)(smem + 10240);  // [128][40]
    float* cs = (float*)smem;                              // [128][132]
    int t = threadIdx.x;
    int l = t & 63, w = t >> 6;
    int wr = w >> 1, wcn = w & 1;
    int rowbase = blockIdx.x * 128;
    int ncol0 = blockIdx.y * 128;
    int b = rowbase >> 13;

    f32x4 acc[4][4];
    #pragma unroll
    for (int i = 0; i < 4; ++i)
        #pragma unroll
        for (int j = 0; j < 4; ++j) acc[i][j] = (f32x4){0.f, 0.f, 0.f, 0.f};

    for (int kb = 0; kb < 8; ++kb) {
        #pragma unroll
        for (int ii = 0; ii < 16; ++ii) {
            int i = t + ii * 256;
            int r = i >> 5, c = i & 31;
            int cg = kb * 32 + c;
            int p = rowbase + r;
            float v = (cg < 128) ? pf[p * 128 + cg] : lf[p * 128 + (cg - 128)];
            As[r * 40 + c] = f2b(v);
        }
        #pragma unroll
        for (int ii = 0; ii < 16; ++ii) {
            int i = t + ii * 256;
            int c = i >> 7, n = i & 127;
            Bs[n * 40 + c] = f2b(Wc[(kb * 32 + c) * 256 + ncol0 + n]);
        }
        __syncthreads();
        bf16x8 af[4], bfr[4];
        #pragma unroll
        for (int mi = 0; mi < 4; ++mi)
            af[mi] = ldb8(&As[(wr * 64 + mi * 16 + (l & 15)) * 40 + (l >> 4) * 8]);
        #pragma unroll
        for (int nj = 0; nj < 4; ++nj)
            bfr[nj] = ldb8(&Bs[(wcn * 64 + nj * 16 + (l & 15)) * 40 + (l >> 4) * 8]);
        #pragma unroll
        for (int mi = 0; mi < 4; ++mi)
            #pragma unroll
            for (int nj = 0; nj < 4; ++nj)
                acc[mi][nj] = __builtin_amdgcn_mfma_f32_16x16x32_bf16(af[mi], bfr[nj], acc[mi][nj], 0, 0, 0);
        __syncthreads();
    }
    #pragma unroll
    for (int mi = 0; mi < 4; ++mi)
        #pragma unroll
        for (int nj = 0; nj < 4; ++nj)
            #pragma unroll
            for (int rg = 0; rg < 4; ++rg) {
                int row = wr * 64 + mi * 16 + (l >> 4) * 4 + rg;
                int col = wcn * 64 + nj * 16 + (l & 15);
                cs[row * 132 + col] = fmaxf(acc[mi][nj][rg] + bc[ncol0 + col], 0.f);
            }
    __syncthreads();
    if (t < 128) {
        float m = 0.f;
        for (int r = 0; r < 128; ++r) m = fmaxf(m, cs[r * 132 + t]);
        atomicMax((unsigned int*)&gf[b * 256 + ncol0 + t], __float_as_uint(m));
    }
}

// ---------------- Kernel E: heads (Wk / Wp branch via blockIdx.y) ----------
__global__ __launch_bounds__(256) void k_head(
    const float* __restrict__ pf, const float* __restrict__ lf, const float* __restrict__ gf,
    const float* __restrict__ Wk1, const float* __restrict__ bk1,
    const float* __restrict__ Wk2, const float* __restrict__ bk2,
    const float* __restrict__ Wp1, const float* __restrict__ bp1,
    const float* __restrict__ Wp2, const float* __restrict__ bp2,
    float* __restrict__ out) {
    __shared__ __align__(16) char smem[67584];
    unsigned short* As = (unsigned short*)smem;
    unsigned short* Bs = (unsigned short*)(smem + 10240);
    float* hs = (float*)smem;  // [128][132]
    int t = threadIdx.x;
    int l = t & 63, w = t >> 6;
    int wr = w >> 1, wcn = w & 1;
    int rowbase = blockIdx.x * 128;
    int br = blockIdx.y;
    const float* W1 = br ? Wp1 : Wk1;
    const float* b1 = br ? bp1 : bk1;
    const float* W2 = br ? Wp2 : Wk2;
    const float* b2p = br ? bp2 : bk2;
    int OC = br ? 8 : 10;
    float* obase = out + (br ? (size_t)NP * 10 : 0);

    f32x4 acc[4][4];
    #pragma unroll
    for (int i = 0; i < 4; ++i)
        #pragma unroll
        for (int j = 0; j < 4; ++j) acc[i][j] = (f32x4){0.f, 0.f, 0.f, 0.f};

    for (int kb = 0; kb < 16; ++kb) {
        #pragma unroll
        for (int ii = 0; ii < 16; ++ii) {
            int i = t + ii * 256;
            int r = i >> 5, c = i & 31;
            int cg = kb * 32 + c;
            int p = rowbase + r;
            float v;
            if (cg < 128) v = pf[p * 128 + cg];
            else if (cg < 256) v = lf[p * 128 + (cg - 128)];
            else v = gf[(p >> 13) * 256 + (cg - 256)];
            As[r * 40 + c] = f2b(v);
        }
        #pragma unroll
        for (int ii = 0; ii < 16; ++ii) {
            int i = t + ii * 256;
            int c = i >> 7, n = i & 127;
            Bs[n * 40 + c] = f2b(W1[(kb * 32 + c) * 128 + n]);
        }
        __syncthreads();
        bf16x8 af[4], bfr[4];
        #pragma unroll
        for (int mi = 0; mi < 4; ++mi)
            af[mi] = ldb8(&As[(wr * 64 + mi * 16 + (l & 15)) * 40 + (l >> 4) * 8]);
        #pragma unroll
        for (int nj = 0; nj < 4; ++nj)
            bfr[nj] = ldb8(&Bs[(wcn * 64 + nj * 16 + (l & 15)) * 40 + (l >> 4) * 8]);
        #pragma unroll
        for (int mi = 0; mi < 4; ++mi)
            #pragma unroll
            for (int nj = 0; nj < 4; ++nj)
                acc[mi][nj] = __builtin_amdgcn_mfma_f32_16x16x32_bf16(af[mi], bfr[nj], acc[mi][nj], 0, 0, 0);
        __syncthreads();
    }
    #pragma unroll
    for (int mi = 0; mi < 4; ++mi)
        #pragma unroll
        for (int nj = 0; nj < 4; ++nj)
            #pragma unroll
            for (int rg = 0; rg < 4; ++rg) {
                int row = wr * 64 + mi * 16 + (l >> 4) * 4 + rg;
                int col = wcn * 64 + nj * 16 + (l & 15);
                hs[row * 132 + col] = fmaxf(acc[mi][nj][rg] + b1[col], 0.f);
            }
    __syncthreads();
    for (int o = t; o < 128 * OC; o += 256) {
        int r = o / OC, c = o % OC;
        float a = b2p[c];
        for (int k2 = 0; k2 < 128; ++k2) a += hs[r * 132 + k2] * W2[k2 * OC + c];
        obase[(size_t)(rowbase + r) * OC + c] = a;
    }
}

extern "C" void kernel_launch(void* const* d_in, const int* in_sizes, int n_in,
                              void* d_out, int out_size, void* d_ws, size_t ws_size,
                              hipStream_t stream) {
    const float* pts = (const float*)d_in[0];
    const float* nrm = (const float*)d_in[1];
    const float* We1 = (const float*)d_in[2];
    const float* be1 = (const float*)d_in[3];
    const float* We2 = (const float*)d_in[4];
    const float* be2 = (const float*)d_in[5];
    const float* Wl1 = (const float*)d_in[6];
    const float* bl1 = (const float*)d_in[7];
    const float* Wl2 = (const float*)d_in[8];
    const float* bl2 = (const float*)d_in[9];
    const float* Wc  = (const float*)d_in[10];
    const float* bc  = (const float*)d_in[11];
    const float* Wk1 = (const float*)d_in[12];
    const float* bk1 = (const float*)d_in[13];
    const float* Wk2 = (const float*)d_in[14];
    const float* bk2 = (const float*)d_in[15];
    const float* Wp1 = (const float*)d_in[16];
    const float* bp1 = (const float*)d_in[17];
    const float* Wp2 = (const float*)d_in[18];
    const float* bp2 = (const float*)d_in[19];
    float* out = (float*)d_out;

    char* ws = (char*)d_ws;
    size_t off = 0;
    float* pf = (float*)(ws + off);       off += (size_t)NP * 128 * 4;   // 8.39 MB
    float* lf = (float*)(ws + off);       off += (size_t)NP * 128 * 4;   // 8.39 MB
    float* u  = (float*)(ws + off);       off += (size_t)NP * 128 * 4;   // 8.39 MB
    float* v  = (float*)(ws + off);       off += (size_t)NP * 128 * 4;   // 8.39 MB
    int* knn  = (int*)(ws + off);         off += (size_t)NP * 16 * 4;    // 1.05 MB
    float* gf = (float*)(ws + off);       off += 2048;
    float4* pts4 = (float4*)(ws + off);   off += (size_t)NP * 16;        // 256 KB
    float* Wuvcat = (float*)(ws + off);   off += 128 * 256 * 4;          // 128 KB
    float* bias_cat = (float*)(ws + off); off += 1024;
    unsigned short* Wl2T = (unsigned short*)(ws + off); off += 128 * 128 * 2;

    hipLaunchKernelGGL(k_pf, dim3(256), dim3(256), 0, stream,
                       pts, nrm, We1, be1, We2, be2, pf, gf);
    hipLaunchKernelGGL(k_prep, dim3(64), dim3(256), 0, stream,
                       Wl1, bl1, Wl2, Wuvcat, bias_cat, Wl2T);
    hipLaunchKernelGGL(k_pack, dim3(NP / 256), dim3(256), 0, stream, pts, pts4);
    hipLaunchKernelGGL(k_knn, dim3(4096), dim3(256), 0, stream, pts4, knn);
    hipLaunchKernelGGL(k_uv, dim3(128, 2), dim3(256), 0, stream,
                       pf, Wuvcat, bias_cat, u, v);
    hipLaunchKernelGGL(k_edge, dim3(2048), dim3(256), 0, stream,
                       u, v, knn, Wl2T, bl2, lf);
    hipLaunchKernelGGL(k_ctx, dim3(128, 2), dim3(256), 0, stream,
                       pf, lf, Wc, bc, gf);
    hipLaunchKernelGGL(k_head, dim3(128, 2), dim3(256), 0, stream,
                       pf, lf, gf, Wk1, bk1, Wk2, bk2, Wp1, bp1, Wp2, bp2, out);
}

// Round 5
// 477.733 us; speedup vs baseline: 2.6886x; 1.0351x over previous
//
#include <hip/hip_runtime.h>

#define B_ 2
#define N_ 8192
#define NP 16384   // B_*N_
#define K_ 16
#define H_ 128

typedef short bf16x8 __attribute__((ext_vector_type(8)));
typedef float f32x4 __attribute__((ext_vector_type(4)));

__device__ inline unsigned short f2b(float f) {
    unsigned u = __builtin_bit_cast(unsigned, f);
    unsigned r = (u + 0x7fff + ((u >> 16) & 1)) >> 16;
    return (unsigned short)r;
}
__device__ inline bf16x8 ldb8(const unsigned short* p) {
    return *(const bf16x8*)p;
}

// ------- Kernel A: pf = relu(relu(x@We1+be1)@We2+be2); zero gf; pack pts4 --
__global__ __launch_bounds__(256) void k_pf(
    const float* __restrict__ pts, const float* __restrict__ nrm,
    const float* __restrict__ We1, const float* __restrict__ be1,
    const float* __restrict__ We2, const float* __restrict__ be2,
    float* __restrict__ pf, float* __restrict__ gf, float4* __restrict__ pts4) {
    __shared__ float w2s[128 * 128];
    __shared__ float w1s[6 * 128];
    __shared__ float b1s[128], b2s[128];
    __shared__ float xs[2][6];
    __shared__ float h1s[2][128];
    int t = threadIdx.x;
    for (int i = t; i < 128 * 128; i += 256) w2s[i] = We2[i];
    for (int i = t; i < 6 * 128; i += 256) w1s[i] = We1[i];
    if (t < 128) { b1s[t] = be1[t]; b2s[t] = be2[t]; }
    if (blockIdx.x == 0) { gf[t] = 0.f; gf[256 + t] = 0.f; }
    int base = blockIdx.x * 64;
    if (t < 64) {  // fold of k_pack: this block's 64 points
        int p = base + t;
        float x = pts[p * 3], y = pts[p * 3 + 1], z = pts[p * 3 + 2];
        float sq = __fadd_rn(__fadd_rn(__fmul_rn(x, x), __fmul_rn(y, y)), __fmul_rn(z, z));
        pts4[p] = make_float4(x, y, z, sq);
    }
    __syncthreads();
    int g = t >> 7, h = t & 127;
    for (int it = 0; it < 32; ++it) {
        int p = base + it * 2 + g;
        if (h < 3) xs[g][h] = pts[p * 3 + h];
        else if (h < 6) xs[g][h] = nrm[p * 3 + h - 3];
        __syncthreads();
        float a = b1s[h];
        #pragma unroll
        for (int c = 0; c < 6; ++c) a += xs[g][c] * w1s[c * 128 + h];
        h1s[g][h] = fmaxf(a, 0.f);
        __syncthreads();
        float o = b2s[h];
        #pragma unroll 8
        for (int c = 0; c < 128; ++c) o += h1s[g][c] * w2s[c * 128 + h];
        pf[p * 128 + h] = fmaxf(o, 0.f);
        __syncthreads();
    }
}

// ---------------- Kernel P: prep factored weights ---------------------------
__global__ __launch_bounds__(256) void k_prep(
    const float* __restrict__ Wl1, const float* __restrict__ bl1,
    const float* __restrict__ Wl2,
    float* __restrict__ Wuvcat, float* __restrict__ bias_cat,
    unsigned short* __restrict__ Wl2T) {
    int tid = blockIdx.x * 256 + threadIdx.x;
    int stride = gridDim.x * 256;
    for (int i = tid; i < 128 * 256; i += stride) {
        int k = i >> 8, n = i & 255;
        float val;
        if (n < 128) val = Wl1[k * 128 + n] - Wl1[(k + 128) * 128 + n];
        else         val = Wl1[(k + 128) * 128 + (n - 128)];
        Wuvcat[i] = val;
    }
    for (int i = tid; i < 256; i += stride) bias_cat[i] = (i < 128) ? bl1[i] : 0.f;
    for (int i = tid; i < 128 * 128; i += stride) {
        int n = i >> 7, k = i & 127;
        Wl2T[i] = f2b(Wl2[k * 128 + n]);
    }
}

// ------- Kernel B: 16-NN, single streaming pass with running threshold -----
__global__ __launch_bounds__(256) void k_knn(
    const float4* __restrict__ pts4, int* __restrict__ knn) {
    __shared__ float4 tile[1024];                  // 16 KB
    __shared__ int hist[4][2][256];                // 8 KB (2 sub-hists/wave)
    __shared__ unsigned long long buf[4][256];     // 8 KB
    int t = threadIdx.x, w = t >> 6, l = t & 63;
    int b = blockIdx.x >> 11;
    int q = (blockIdx.x & 2047) * 4 + w;
    const float4* pb = pts4 + b * N_;
    float4 qp = pb[q];
    int* hw = &hist[w][0][0];
    int sub = l >> 5;
    for (int i = l; i < 512; i += 64) hw[i] = 0;
    int cntw = 0;
    int Bsel = 255;

    for (int t0 = 0; t0 < N_; t0 += 1024) {
        __syncthreads();   // all waves done with previous tile round
        #pragma unroll
        for (int i = 0; i < 4; ++i) tile[t + 256 * i] = pb[t0 + t + 256 * i];
        __syncthreads();

        // hist (+ insert with current Bsel for rounds > 0)
        #pragma unroll 2
        for (int j = l; j < 1024; j += 64) {
            float4 c = tile[j];
            float dot = __fadd_rn(__fadd_rn(__fmul_rn(qp.x, c.x), __fmul_rn(qp.y, c.y)), __fmul_rn(qp.z, c.z));
            float d2 = __fsub_rn(__fadd_rn(qp.w, c.w), __fmul_rn(2.f, dot));
            d2 = (t0 + j == q) ? 1e30f : d2;
            unsigned uu = __float_as_uint(d2);
            int bk = (d2 < 0.f) ? 0 : min(255, max(0, (int)(uu >> 21) - 400));
            atomicAdd(&hist[w][sub][bk], 1);
            if (t0 > 0) {
                bool take = (bk <= Bsel);
                unsigned long long mask = __ballot(take);
                if (take) {
                    unsigned du = __float_as_uint(d2);
                    unsigned mu = du ^ (unsigned)(((int)du >> 31) | 0x80000000);
                    int pos = cntw + __popcll(mask & ((1ull << l) - 1ull));
                    if (pos < 256) buf[w][pos] = ((unsigned long long)mu << 32) | (unsigned)(t0 + j);
                }
                cntw += __popcll(mask);
            }
        }

        // rescan own hist -> tightened Bsel (partial-cum bound is safe: >= true B)
        {
            int h0 = hw[4 * l] + hw[256 + 4 * l];
            int h1 = hw[4 * l + 1] + hw[256 + 4 * l + 1];
            int h2 = hw[4 * l + 2] + hw[256 + 4 * l + 2];
            int h3 = hw[4 * l + 3] + hw[256 + 4 * l + 3];
            int c0 = h0, c1 = c0 + h1, c2 = c1 + h2, c3 = c2 + h3;
            int tot = c3;
            int inc = tot;
            for (int off = 1; off < 64; off <<= 1) {
                int vv = __shfl_up(inc, off);
                if (l >= off) inc += vv;
            }
            int excl = inc - tot;
            int Bc = 255;
            if      (excl + c0 >= 16) Bc = 4 * l;
            else if (excl + c1 >= 16) Bc = 4 * l + 1;
            else if (excl + c2 >= 16) Bc = 4 * l + 2;
            else if (excl + c3 >= 16) Bc = 4 * l + 3;
            for (int m = 1; m < 64; m <<= 1) Bc = min(Bc, __shfl_xor(Bc, m));
            Bsel = min(Bsel, Bc);
        }

        // round 0: replay the (still-resident) tile, inserting with B0
        if (t0 == 0) {
            for (int j = l; j < 1024; j += 64) {
                float4 c = tile[j];
                float dot = __fadd_rn(__fadd_rn(__fmul_rn(qp.x, c.x), __fmul_rn(qp.y, c.y)), __fmul_rn(qp.z, c.z));
                float d2 = __fsub_rn(__fadd_rn(qp.w, c.w), __fmul_rn(2.f, dot));
                d2 = (j == q) ? 1e30f : d2;
                unsigned uu = __float_as_uint(d2);
                int bk = (d2 < 0.f) ? 0 : min(255, max(0, (int)(uu >> 21) - 400));
                bool take = (bk <= Bsel);
                unsigned long long mask = __ballot(take);
                if (take) {
                    unsigned du = __float_as_uint(d2);
                    unsigned mu = du ^ (unsigned)(((int)du >> 31) | 0x80000000);
                    int pos = cntw + __popcll(mask & ((1ull << l) - 1ull));
                    if (pos < 256) buf[w][pos] = ((unsigned long long)mu << 32) | (unsigned)j;
                }
                cntw += __popcll(mask);
            }
        }
    }
    int m_ = min(cntw, 256);

    unsigned long long key[4];
    #pragma unroll
    for (int r = 0; r < 4; ++r) {
        int e = l + 64 * r;
        key[r] = (e < m_) ? buf[w][e] : ~0ull;
    }
    for (int r16 = 0; r16 < 16; ++r16) {
        unsigned long long mn = key[0];
        #pragma unroll
        for (int r = 1; r < 4; ++r) mn = (key[r] < mn) ? key[r] : mn;
        unsigned long long wv = mn;
        for (int m = 1; m < 64; m <<= 1) {
            unsigned long long o = __shfl_xor(wv, m);
            wv = (o < wv) ? o : wv;
        }
        if (l == 0) knn[((size_t)b * N_ + q) * 16 + r16] = b * N_ + (int)(wv & 0xffffffffu);
        #pragma unroll
        for (int r = 0; r < 4; ++r) if (key[r] == wv) key[r] = ~0ull;
    }
}

// ---------------- Kernel U: uv = pf @ Wuvcat + bias_cat (no relu) ----------
__global__ __launch_bounds__(256) void k_uv(
    const float* __restrict__ pf, const float* __restrict__ Wuvcat,
    const float* __restrict__ bias_cat,
    float* __restrict__ u, float* __restrict__ v) {
    __shared__ __align__(16) char smem[20480];
    unsigned short* As = (unsigned short*)smem;            // [128][40]
    unsigned short* Bs = (unsigned short*)(smem + 10240);  // [128][40]
    int t = threadIdx.x;
    int l = t & 63, w = t >> 6;
    int wr = w >> 1, wcn = w & 1;
    int rowbase = blockIdx.x * 128;
    int ncol0 = blockIdx.y * 128;

    f32x4 acc[4][4];
    #pragma unroll
    for (int i = 0; i < 4; ++i)
        #pragma unroll
        for (int j = 0; j < 4; ++j) acc[i][j] = (f32x4){0.f, 0.f, 0.f, 0.f};

    for (int kb = 0; kb < 4; ++kb) {
        #pragma unroll
        for (int ii = 0; ii < 16; ++ii) {
            int i = t + ii * 256;
            int r = i >> 5, c = i & 31;
            As[r * 40 + c] = f2b(pf[(rowbase + r) * 128 + kb * 32 + c]);
        }
        #pragma unroll
        for (int ii = 0; ii < 16; ++ii) {
            int i = t + ii * 256;
            int c = i >> 7, n = i & 127;
            Bs[n * 40 + c] = f2b(Wuvcat[(kb * 32 + c) * 256 + ncol0 + n]);
        }
        __syncthreads();
        bf16x8 af[4], bfr[4];
        #pragma unroll
        for (int mi = 0; mi < 4; ++mi)
            af[mi] = ldb8(&As[(wr * 64 + mi * 16 + (l & 15)) * 40 + (l >> 4) * 8]);
        #pragma unroll
        for (int nj = 0; nj < 4; ++nj)
            bfr[nj] = ldb8(&Bs[(wcn * 64 + nj * 16 + (l & 15)) * 40 + (l >> 4) * 8]);
        #pragma unroll
        for (int mi = 0; mi < 4; ++mi)
            #pragma unroll
            for (int nj = 0; nj < 4; ++nj)
                acc[mi][nj] = __builtin_amdgcn_mfma_f32_16x16x32_bf16(af[mi], bfr[nj], acc[mi][nj], 0, 0, 0);
        __syncthreads();
    }
    float* outp = (ncol0 == 0) ? u : v;
    #pragma unroll
    for (int mi = 0; mi < 4; ++mi)
        #pragma unroll
        for (int nj = 0; nj < 4; ++nj) {
            int col = wcn * 64 + nj * 16 + (l & 15);
            float bias = bias_cat[ncol0 + col];
            #pragma unroll
            for (int rg = 0; rg < 4; ++rg) {
                int row = wr * 64 + mi * 16 + (l >> 4) * 4 + rg;
                outp[(size_t)(rowbase + row) * 128 + col] = acc[mi][nj][rg] + bias;
            }
        }
}

// ---------------- Kernel C: edge layer2 GEMM + max over K ------------------
__global__ __launch_bounds__(256) void k_edge(
    const float* __restrict__ u, const float* __restrict__ v,
    const int* __restrict__ knn, const unsigned short* __restrict__ Wl2T,
    const float* __restrict__ bl2, float* __restrict__ lf) {
    __shared__ __align__(16) unsigned short h1s[128 * 136];  // 34816 B
    int t = threadIdx.x;
    int l = t & 63, w = t >> 6;
    int wr = w >> 1, wcn = w & 1;
    int rowbase = blockIdx.x * 128;
    int p0 = blockIdx.x * 8;

    #pragma unroll 2
    for (int i = 0; i < 8; ++i) {
        int ci = t + 256 * i;
        int r = ci >> 4, c8 = (ci & 15) * 8;
        int nb = knn[rowbase + r];
        int pt = p0 + (r >> 4);
        const float4* vp = (const float4*)(v + (size_t)nb * 128 + c8);
        const float4* up = (const float4*)(u + (size_t)pt * 128 + c8);
        float4 va = vp[0], vb = vp[1];
        float4 ua = up[0], ub = up[1];
        unsigned d0 = (unsigned)f2b(fmaxf(ua.x + va.x, 0.f)) | ((unsigned)f2b(fmaxf(ua.y + va.y, 0.f)) << 16);
        unsigned d1 = (unsigned)f2b(fmaxf(ua.z + va.z, 0.f)) | ((unsigned)f2b(fmaxf(ua.w + va.w, 0.f)) << 16);
        unsigned d2 = (unsigned)f2b(fmaxf(ub.x + vb.x, 0.f)) | ((unsigned)f2b(fmaxf(ub.y + vb.y, 0.f)) << 16);
        unsigned d3 = (unsigned)f2b(fmaxf(ub.z + vb.z, 0.f)) | ((unsigned)f2b(fmaxf(ub.w + vb.w, 0.f)) << 16);
        uint4 pk; pk.x = d0; pk.y = d1; pk.z = d2; pk.w = d3;
        *(uint4*)&h1s[r * 136 + c8] = pk;
    }
    __syncthreads();

    f32x4 acc[4][4];
    #pragma unroll
    for (int i = 0; i < 4; ++i)
        #pragma unroll
        for (int j = 0; j < 4; ++j) acc[i][j] = (f32x4){0.f, 0.f, 0.f, 0.f};

    #pragma unroll
    for (int ks = 0; ks < 4; ++ks) {
        bf16x8 bfr[4], afr[4];
        #pragma unroll
        for (int nj = 0; nj < 4; ++nj)
            bfr[nj] = ldb8(&Wl2T[(size_t)(wcn * 64 + nj * 16 + (l & 15)) * 128 + ks * 32 + (l >> 4) * 8]);
        #pragma unroll
        for (int mi = 0; mi < 4; ++mi)
            afr[mi] = ldb8(&h1s[(wr * 64 + mi * 16 + (l & 15)) * 136 + ks * 32 + (l >> 4) * 8]);
        #pragma unroll
        for (int mi = 0; mi < 4; ++mi)
            #pragma unroll
            for (int nj = 0; nj < 4; ++nj)
                acc[mi][nj] = __builtin_amdgcn_mfma_f32_16x16x32_bf16(afr[mi], bfr[nj], acc[mi][nj], 0, 0, 0);
    }

    #pragma unroll
    for (int mi = 0; mi < 4; ++mi)
        #pragma unroll
        for (int nj = 0; nj < 4; ++nj) {
            int col = wcn * 64 + nj * 16 + (l & 15);
            float bias = bl2[col];
            float m = fmaxf(acc[mi][nj][0] + bias, 0.f);
            m = fmaxf(m, fmaxf(acc[mi][nj][1] + bias, 0.f));
            m = fmaxf(m, fmaxf(acc[mi][nj][2] + bias, 0.f));
            m = fmaxf(m, fmaxf(acc[mi][nj][3] + bias, 0.f));
            m = fmaxf(m, __shfl_xor(m, 16));
            m = fmaxf(m, __shfl_xor(m, 32));
            if (l < 16) lf[(size_t)(p0 + wr * 4 + mi) * 128 + col] = m;
        }
}

// ---------------- Kernel D: ctx = relu([pf,lf]@Wc+bc); gf = max over N -----
__global__ __launch_bounds__(256) void k_ctx(
    const float* __restrict__ pf, const float* __restrict__ lf,
    const float* __restrict__ Wc, const float* __restrict__ bc,
    float* __restrict__ gf) {
    __shared__ __align__(16) char smem[67584];
    unsigned short* As = (unsigned short*)smem;            // [128][40]
    unsigned short* Bs = (unsigned short*)(smem + 10240);  // [128][40]
    float* cs = (float*)smem;                              // [128][132]
    int t = threadIdx.x;
    int l = t & 63, w = t >> 6;
    int wr = w >> 1, wcn = w & 1;
    int rowbase = blockIdx.x * 128;
    int ncol0 = blockIdx.y * 128;
    int b = rowbase >> 13;

    f32x4 acc[4][4];
    #pragma unroll
    for (int i = 0; i < 4; ++i)
        #pragma unroll
        for (int j = 0; j < 4; ++j) acc[i][j] = (f32x4){0.f, 0.f, 0.f, 0.f};

    for (int kb = 0; kb < 8; ++kb) {
        #pragma unroll
        for (int ii = 0; ii < 16; ++ii) {
            int i = t + ii * 256;
            int r = i >> 5, c = i & 31;
            int cg = kb * 32 + c;
            int p = rowbase + r;
            float v = (cg < 128) ? pf[p * 128 + cg] : lf[p * 128 + (cg - 128)];
            As[r * 40 + c] = f2b(v);
        }
        #pragma unroll
        for (int ii = 0; ii < 16; ++ii) {
            int i = t + ii * 256;
            int c = i >> 7, n = i & 127;
            Bs[n * 40 + c] = f2b(Wc[(kb * 32 + c) * 256 + ncol0 + n]);
        }
        __syncthreads();
        bf16x8 af[4], bfr[4];
        #pragma unroll
        for (int mi = 0; mi < 4; ++mi)
            af[mi] = ldb8(&As[(wr * 64 + mi * 16 + (l & 15)) * 40 + (l >> 4) * 8]);
        #pragma unroll
        for (int nj = 0; nj < 4; ++nj)
            bfr[nj] = ldb8(&Bs[(wcn * 64 + nj * 16 + (l & 15)) * 40 + (l >> 4) * 8]);
        #pragma unroll
        for (int mi = 0; mi < 4; ++mi)
            #pragma unroll
            for (int nj = 0; nj < 4; ++nj)
                acc[mi][nj] = __builtin_amdgcn_mfma_f32_16x16x32_bf16(af[mi], bfr[nj], acc[mi][nj], 0, 0, 0);
        __syncthreads();
    }
    #pragma unroll
    for (int mi = 0; mi < 4; ++mi)
        #pragma unroll
        for (int nj = 0; nj < 4; ++nj)
            #pragma unroll
            for (int rg = 0; rg < 4; ++rg) {
                int row = wr * 64 + mi * 16 + (l >> 4) * 4 + rg;
                int col = wcn * 64 + nj * 16 + (l & 15);
                cs[row * 132 + col] = fmaxf(acc[mi][nj][rg] + bc[ncol0 + col], 0.f);
            }
    __syncthreads();
    if (t < 128) {
        float m = 0.f;
        for (int r = 0; r < 128; ++r) m = fmaxf(m, cs[r * 132 + t]);
        atomicMax((unsigned int*)&gf[b * 256 + ncol0 + t], __float_as_uint(m));
    }
}

// ---------------- Kernel E: heads (Wk / Wp branch via blockIdx.y) ----------
__global__ __launch_bounds__(256) void k_head(
    const float* __restrict__ pf, const float* __restrict__ lf, const float* __restrict__ gf,
    const float* __restrict__ Wk1, const float* __restrict__ bk1,
    const float* __restrict__ Wk2, const float* __restrict__ bk2,
    const float* __restrict__ Wp1, const float* __restrict__ bp1,
    const float* __restrict__ Wp2, const float* __restrict__ bp2,
    float* __restrict__ out) {
    __shared__ __align__(16) char smem[67584];
    unsigned short* As = (unsigned short*)smem;
    unsigned short* Bs = (unsigned short*)(smem + 10240);
    float* hs = (float*)smem;  // [128][132]
    int t = threadIdx.x;
    int l = t & 63, w = t >> 6;
    int wr = w >> 1, wcn = w & 1;
    int rowbase = blockIdx.x * 128;
    int br = blockIdx.y;
    const float* W1 = br ? Wp1 : Wk1;
    const float* b1 = br ? bp1 : bk1;
    const float* W2 = br ? Wp2 : Wk2;
    const float* b2p = br ? bp2 : bk2;
    int OC = br ? 8 : 10;
    float* obase = out + (br ? (size_t)NP * 10 : 0);

    f32x4 acc[4][4];
    #pragma unroll
    for (int i = 0; i < 4; ++i)
        #pragma unroll
        for (int j = 0; j < 4; ++j) acc[i][j] = (f32x4){0.f, 0.f, 0.f, 0.f};

    for (int kb = 0; kb < 16; ++kb) {
        #pragma unroll
        for (int ii = 0; ii < 16; ++ii) {
            int i = t + ii * 256;
            int r = i >> 5, c = i & 31;
            int cg = kb * 32 + c;
            int p = rowbase + r;
            float v;
            if (cg < 128) v = pf[p * 128 + cg];
            else if (cg < 256) v = lf[p * 128 + (cg - 128)];
            else v = gf[(p >> 13) * 256 + (cg - 256)];
            As[r * 40 + c] = f2b(v);
        }
        #pragma unroll
        for (int ii = 0; ii < 16; ++ii) {
            int i = t + ii * 256;
            int c = i >> 7, n = i & 127;
            Bs[n * 40 + c] = f2b(W1[(kb * 32 + c) * 128 + n]);
        }
        __syncthreads();
        bf16x8 af[4], bfr[4];
        #pragma unroll
        for (int mi = 0; mi < 4; ++mi)
            af[mi] = ldb8(&As[(wr * 64 + mi * 16 + (l & 15)) * 40 + (l >> 4) * 8]);
        #pragma unroll
        for (int nj = 0; nj < 4; ++nj)
            bfr[nj] = ldb8(&Bs[(wcn * 64 + nj * 16 + (l & 15)) * 40 + (l >> 4) * 8]);
        #pragma unroll
        for (int mi = 0; mi < 4; ++mi)
            #pragma unroll
            for (int nj = 0; nj < 4; ++nj)
                acc[mi][nj] = __builtin_amdgcn_mfma_f32_16x16x32_bf16(af[mi], bfr[nj], acc[mi][nj], 0, 0, 0);
        __syncthreads();
    }
    #pragma unroll
    for (int mi = 0; mi < 4; ++mi)
        #pragma unroll
        for (int nj = 0; nj < 4; ++nj)
            #pragma unroll
            for (int rg = 0; rg < 4; ++rg) {
                int row = wr * 64 + mi * 16 + (l >> 4) * 4 + rg;
                int col = wcn * 64 + nj * 16 + (l & 15);
                hs[row * 132 + col] = fmaxf(acc[mi][nj][rg] + b1[col], 0.f);
            }
    __syncthreads();
    for (int o = t; o < 128 * OC; o += 256) {
        int r = o / OC, c = o % OC;
        float a = b2p[c];
        for (int k2 = 0; k2 < 128; ++k2) a += hs[r * 132 + k2] * W2[k2 * OC + c];
        obase[(size_t)(rowbase + r) * OC + c] = a;
    }
}

extern "C" void kernel_launch(void* const* d_in, const int* in_sizes, int n_in,
                              void* d_out, int out_size, void* d_ws, size_t ws_size,
                              hipStream_t stream) {
    const float* pts = (const float*)d_in[0];
    const float* nrm = (const float*)d_in[1];
    const float* We1 = (const float*)d_in[2];
    const float* be1 = (const float*)d_in[3];
    const float* We2 = (const float*)d_in[4];
    const float* be2 = (const float*)d_in[5];
    const float* Wl1 = (const float*)d_in[6];
    const float* bl1 = (const float*)d_in[7];
    const float* Wl2 = (const float*)d_in[8];
    const float* bl2 = (const float*)d_in[9];
    const float* Wc  = (const float*)d_in[10];
    const float* bc  = (const float*)d_in[11];
    const float* Wk1 = (const float*)d_in[12];
    const float* bk1 = (const float*)d_in[13];
    const float* Wk2 = (const float*)d_in[14];
    const float* bk2 = (const float*)d_in[15];
    const float* Wp1 = (const float*)d_in[16];
    const float* bp1 = (const float*)d_in[17];
    const float* Wp2 = (const float*)d_in[18];
    const float* bp2 = (const float*)d_in[19];
    float* out = (float*)d_out;

    char* ws = (char*)d_ws;
    size_t off = 0;
    float* pf = (float*)(ws + off);       off += (size_t)NP * 128 * 4;   // 8.39 MB
    float* lf = (float*)(ws + off);       off += (size_t)NP * 128 * 4;   // 8.39 MB
    float* u  = (float*)(ws + off);       off += (size_t)NP * 128 * 4;   // 8.39 MB
    float* v  = (float*)(ws + off);       off += (size_t)NP * 128 * 4;   // 8.39 MB
    int* knn  = (int*)(ws + off);         off += (size_t)NP * 16 * 4;    // 1.05 MB
    float* gf = (float*)(ws + off);       off += 2048;
    float4* pts4 = (float4*)(ws + off);   off += (size_t)NP * 16;        // 256 KB
    float* Wuvcat = (float*)(ws + off);   off += 128 * 256 * 4;          // 128 KB
    float* bias_cat = (float*)(ws + off); off += 1024;
    unsigned short* Wl2T = (unsigned short*)(ws + off); off += 128 * 128 * 2;

    hipLaunchKernelGGL(k_pf, dim3(256), dim3(256), 0, stream,
                       pts, nrm, We1, be1, We2, be2, pf, gf, pts4);
    hipLaunchKernelGGL(k_prep, dim3(64), dim3(256), 0, stream,
                       Wl1, bl1, Wl2, Wuvcat, bias_cat, Wl2T);
    hipLaunchKernelGGL(k_knn, dim3(4096), dim3(256), 0, stream, pts4, knn);
    hipLaunchKernelGGL(k_uv, dim3(128, 2), dim3(256), 0, stream,
                       pf, Wuvcat, bias_cat, u, v);
    hipLaunchKernelGGL(k_edge, dim3(2048), dim3(256), 0, stream,
                       u, v, knn, Wl2T, bl2, lf);
    hipLaunchKernelGGL(k_ctx, dim3(128, 2), dim3(256), 0, stream,
                       pf, lf, Wc, bc, gf);
    hipLaunchKernelGGL(k_head, dim3(128, 2), dim3(256), 0, stream,
                       pf, lf, gf, Wk1, bk1, Wk2, bk2, Wp1, bp1, Wp2, bp2, out);
}

// Round 8
// 449.608 us; speedup vs baseline: 2.8567x; 1.0626x over previous
//
#include <hip/hip_runtime.h>

#define B_ 2
#define N_ 8192
#define NP 16384   // B_*N_
#define K_ 16
#define H_ 128
#define KCAP 512

typedef short bf16x8 __attribute__((ext_vector_type(8)));
typedef float f32x4 __attribute__((ext_vector_type(4)));

__device__ inline unsigned short f2b(float f) {
    unsigned u = __builtin_bit_cast(unsigned, f);
    unsigned r = (u + 0x7fff + ((u >> 16) & 1)) >> 16;
    return (unsigned short)r;
}
__device__ inline bf16x8 ldb8(const unsigned short* p) {
    return *(const bf16x8*)p;
}

// ------- Kernel A: pf = relu(relu(x@We1+be1)@We2+be2); zero gf; pack pts4 --
__global__ __launch_bounds__(256) void k_pf(
    const float* __restrict__ pts, const float* __restrict__ nrm,
    const float* __restrict__ We1, const float* __restrict__ be1,
    const float* __restrict__ We2, const float* __restrict__ be2,
    float* __restrict__ pf, float* __restrict__ gf, float4* __restrict__ pts4) {
    __shared__ float w2s[128 * 128];
    __shared__ float w1s[6 * 128];
    __shared__ float b1s[128], b2s[128];
    __shared__ float xs[2][6];
    __shared__ float h1s[2][128];
    int t = threadIdx.x;
    for (int i = t; i < 128 * 128; i += 256) w2s[i] = We2[i];
    for (int i = t; i < 6 * 128; i += 256) w1s[i] = We1[i];
    if (t < 128) { b1s[t] = be1[t]; b2s[t] = be2[t]; }
    if (blockIdx.x == 0) { gf[t] = 0.f; gf[256 + t] = 0.f; }
    int base = blockIdx.x * 64;
    if (t < 64) {  // fold of k_pack: this block's 64 points
        int p = base + t;
        float x = pts[p * 3], y = pts[p * 3 + 1], z = pts[p * 3 + 2];
        float sq = __fadd_rn(__fadd_rn(__fmul_rn(x, x), __fmul_rn(y, y)), __fmul_rn(z, z));
        pts4[p] = make_float4(x, y, z, sq);
    }
    __syncthreads();
    int g = t >> 7, h = t & 127;
    for (int it = 0; it < 32; ++it) {
        int p = base + it * 2 + g;
        if (h < 3) xs[g][h] = pts[p * 3 + h];
        else if (h < 6) xs[g][h] = nrm[p * 3 + h - 3];
        __syncthreads();
        float a = b1s[h];
        #pragma unroll
        for (int c = 0; c < 6; ++c) a += xs[g][c] * w1s[c * 128 + h];
        h1s[g][h] = fmaxf(a, 0.f);
        __syncthreads();
        float o = b2s[h];
        #pragma unroll 8
        for (int c = 0; c < 128; ++c) o += h1s[g][c] * w2s[c * 128 + h];
        pf[p * 128 + h] = fmaxf(o, 0.f);
        __syncthreads();
    }
}

// ---------------- Kernel P: prep factored weights ---------------------------
__global__ __launch_bounds__(256) void k_prep(
    const float* __restrict__ Wl1, const float* __restrict__ bl1,
    const float* __restrict__ Wl2,
    float* __restrict__ Wuvcat, float* __restrict__ bias_cat,
    unsigned short* __restrict__ Wl2T) {
    int tid = blockIdx.x * 256 + threadIdx.x;
    int stride = gridDim.x * 256;
    for (int i = tid; i < 128 * 256; i += stride) {
        int k = i >> 8, n = i & 255;
        float val;
        if (n < 128) val = Wl1[k * 128 + n] - Wl1[(k + 128) * 128 + n];
        else         val = Wl1[(k + 128) * 128 + (n - 128)];
        Wuvcat[i] = val;
    }
    for (int i = tid; i < 256; i += stride) bias_cat[i] = (i < 128) ? bl1[i] : 0.f;
    for (int i = tid; i < 128 * 128; i += stride) {
        int n = i >> 7, k = i & 127;
        Wl2T[i] = f2b(Wl2[k * 128 + n]);
    }
}

// ------- Kernel B: 16-NN. Tile-0 histogram -> float threshold; then pure
//         filter stream. KCAP=512: overflow needs tile-0 cum@B0 >= ~58
//         (Poisson-impossible), vs 256 which a dense bucket could breach. ----
__global__ __launch_bounds__(256) void k_knn(
    const float4* __restrict__ pts4, int* __restrict__ knn) {
    __shared__ float4 tile[1024];                  // 16 KB
    __shared__ int hist[4][260];                   // 4.06 KB
    __shared__ unsigned long long buf[4][KCAP];    // 16 KB
    int t = threadIdx.x, w = t >> 6, l = t & 63;
    int b = blockIdx.x >> 11;
    int q = (blockIdx.x & 2047) * 4 + w;
    const float4* pb = pts4 + b * N_;
    float4 qp = pb[q];
    for (int i = l; i < 256; i += 64) hist[w][i] = 0;
    int cntw = 0;

    // ---- tile 0: stage, histogram (only histogram of the whole kernel)
    #pragma unroll
    for (int i = 0; i < 4; ++i) tile[t + 256 * i] = pb[t + 256 * i];
    __syncthreads();
    #pragma unroll 2
    for (int j = l; j < 1024; j += 64) {
        float4 c = tile[j];
        float dot = __fadd_rn(__fadd_rn(__fmul_rn(qp.x, c.x), __fmul_rn(qp.y, c.y)), __fmul_rn(qp.z, c.z));
        float d2 = __fsub_rn(__fadd_rn(qp.w, c.w), __fmul_rn(2.f, dot));
        d2 = (j == q) ? 1e30f : d2;
        unsigned uu = __float_as_uint(d2);
        int bk = (d2 < 0.f) ? 0 : min(255, max(0, (int)(uu >> 21) - 400));
        atomicAdd(&hist[w][bk], 1);
    }
    // wave scan -> first bucket B0 with tile-0 cumcount >= 16 (upper bound on true B)
    float Tf;
    {
        int h0 = hist[w][4 * l], h1 = hist[w][4 * l + 1], h2 = hist[w][4 * l + 2], h3 = hist[w][4 * l + 3];
        int c0 = h0, c1 = c0 + h1, c2 = c1 + h2, c3 = c2 + h3;
        int tot = c3;
        int inc = tot;
        for (int off = 1; off < 64; off <<= 1) {
            int vv = __shfl_up(inc, off);
            if (l >= off) inc += vv;
        }
        int excl = inc - tot;
        int Bc = 255;
        if      (excl + c0 >= 16) Bc = 4 * l;
        else if (excl + c1 >= 16) Bc = 4 * l + 1;
        else if (excl + c2 >= 16) Bc = 4 * l + 2;
        else if (excl + c3 >= 16) Bc = 4 * l + 3;
        for (int m = 1; m < 64; m <<= 1) Bc = min(Bc, __shfl_xor(Bc, m));
        // bucket bk <= Bc  <=>  d2 < Tf (float cmp; negatives auto-included)
        Tf = __uint_as_float((unsigned)(Bc + 401) << 21);
    }
    // ---- replay tile 0 with the filter (tile still resident)
    for (int j = l; j < 1024; j += 64) {
        float4 c = tile[j];
        float dot = __fadd_rn(__fadd_rn(__fmul_rn(qp.x, c.x), __fmul_rn(qp.y, c.y)), __fmul_rn(qp.z, c.z));
        float d2 = __fsub_rn(__fadd_rn(qp.w, c.w), __fmul_rn(2.f, dot));
        d2 = (j == q) ? 1e30f : d2;
        bool take = (d2 < Tf);
        unsigned long long mask = __ballot(take);
        if (take) {
            unsigned du = __float_as_uint(d2);
            unsigned mu = du ^ (unsigned)(((int)du >> 31) | 0x80000000);
            int pos = cntw + __popcll(mask & ((1ull << l) - 1ull));
            if (pos < KCAP) buf[w][pos] = ((unsigned long long)mu << 32) | (unsigned)j;
        }
        cntw += __popcll(mask);
    }

    // ---- tiles 1..7: stage + pure filter (no histogram, no atomics)
    for (int t0 = 1024; t0 < N_; t0 += 1024) {
        __syncthreads();   // everyone done reading previous tile
        #pragma unroll
        for (int i = 0; i < 4; ++i) tile[t + 256 * i] = pb[t0 + t + 256 * i];
        __syncthreads();
        #pragma unroll 2
        for (int j = l; j < 1024; j += 64) {
            float4 c = tile[j];
            float dot = __fadd_rn(__fadd_rn(__fmul_rn(qp.x, c.x), __fmul_rn(qp.y, c.y)), __fmul_rn(qp.z, c.z));
            float d2 = __fsub_rn(__fadd_rn(qp.w, c.w), __fmul_rn(2.f, dot));
            d2 = (t0 + j == q) ? 1e30f : d2;
            bool take = (d2 < Tf);
            unsigned long long mask = __ballot(take);
            if (take) {
                unsigned du = __float_as_uint(d2);
                unsigned mu = du ^ (unsigned)(((int)du >> 31) | 0x80000000);
                int pos = cntw + __popcll(mask & ((1ull << l) - 1ull));
                if (pos < KCAP) buf[w][pos] = ((unsigned long long)mu << 32) | (unsigned)(t0 + j);
            }
            cntw += __popcll(mask);
        }
    }
    int m_ = min(cntw, KCAP);

    unsigned long long key[8];
    #pragma unroll
    for (int r = 0; r < 8; ++r) {
        int e = l + 64 * r;
        key[r] = (e < m_) ? buf[w][e] : ~0ull;
    }
    for (int r16 = 0; r16 < 16; ++r16) {
        unsigned long long mn = key[0];
        #pragma unroll
        for (int r = 1; r < 8; ++r) mn = (key[r] < mn) ? key[r] : mn;
        unsigned long long wv = mn;
        for (int m = 1; m < 64; m <<= 1) {
            unsigned long long o = __shfl_xor(wv, m);
            wv = (o < wv) ? o : wv;
        }
        if (l == 0) knn[((size_t)b * N_ + q) * 16 + r16] = b * N_ + (int)(wv & 0xffffffffu);
        #pragma unroll
        for (int r = 0; r < 8; ++r) if (key[r] == wv) key[r] = ~0ull;
    }
}

// ---------------- Kernel U: uv = pf @ Wuvcat + bias_cat (no relu) ----------
__global__ __launch_bounds__(256) void k_uv(
    const float* __restrict__ pf, const float* __restrict__ Wuvcat,
    const float* __restrict__ bias_cat,
    float* __restrict__ u, float* __restrict__ v) {
    __shared__ __align__(16) char smem[20480];
    unsigned short* As = (unsigned short*)smem;            // [128][40]
    unsigned short* Bs = (unsigned short*)(smem + 10240);  // [128][40]
    int t = threadIdx.x;
    int l = t & 63, w = t >> 6;
    int wr = w >> 1, wcn = w & 1;
    int rowbase = blockIdx.x * 128;
    int ncol0 = blockIdx.y * 128;

    f32x4 acc[4][4];
    #pragma unroll
    for (int i = 0; i < 4; ++i)
        #pragma unroll
        for (int j = 0; j < 4; ++j) acc[i][j] = (f32x4){0.f, 0.f, 0.f, 0.f};

    for (int kb = 0; kb < 4; ++kb) {
        #pragma unroll
        for (int ii = 0; ii < 16; ++ii) {
            int i = t + ii * 256;
            int r = i >> 5, c = i & 31;
            As[r * 40 + c] = f2b(pf[(rowbase + r) * 128 + kb * 32 + c]);
        }
        #pragma unroll
        for (int ii = 0; ii < 16; ++ii) {
            int i = t + ii * 256;
            int c = i >> 7, n = i & 127;
            Bs[n * 40 + c] = f2b(Wuvcat[(kb * 32 + c) * 256 + ncol0 + n]);
        }
        __syncthreads();
        bf16x8 af[4], bfr[4];
        #pragma unroll
        for (int mi = 0; mi < 4; ++mi)
            af[mi] = ldb8(&As[(wr * 64 + mi * 16 + (l & 15)) * 40 + (l >> 4) * 8]);
        #pragma unroll
        for (int nj = 0; nj < 4; ++nj)
            bfr[nj] = ldb8(&Bs[(wcn * 64 + nj * 16 + (l & 15)) * 40 + (l >> 4) * 8]);
        #pragma unroll
        for (int mi = 0; mi < 4; ++mi)
            #pragma unroll
            for (int nj = 0; nj < 4; ++nj)
                acc[mi][nj] = __builtin_amdgcn_mfma_f32_16x16x32_bf16(af[mi], bfr[nj], acc[mi][nj], 0, 0, 0);
        __syncthreads();
    }
    float* outp = (ncol0 == 0) ? u : v;
    #pragma unroll
    for (int mi = 0; mi < 4; ++mi)
        #pragma unroll
        for (int nj = 0; nj < 4; ++nj) {
            int col = wcn * 64 + nj * 16 + (l & 15);
            float bias = bias_cat[ncol0 + col];
            #pragma unroll
            for (int rg = 0; rg < 4; ++rg) {
                int row = wr * 64 + mi * 16 + (l >> 4) * 4 + rg;
                outp[(size_t)(rowbase + row) * 128 + col] = acc[mi][nj][rg] + bias;
            }
        }
}

// ---------------- Kernel C: edge layer2 GEMM + max over K ------------------
__global__ __launch_bounds__(256) void k_edge(
    const float* __restrict__ u, const float* __restrict__ v,
    const int* __restrict__ knn, const unsigned short* __restrict__ Wl2T,
    const float* __restrict__ bl2, float* __restrict__ lf) {
    __shared__ __align__(16) unsigned short h1s[128 * 136];  // 34816 B
    int t = threadIdx.x;
    int l = t & 63, w = t >> 6;
    int wr = w >> 1, wcn = w & 1;
    int rowbase = blockIdx.x * 128;
    int p0 = blockIdx.x * 8;

    #pragma unroll 2
    for (int i = 0; i < 8; ++i) {
        int ci = t + 256 * i;
        int r = ci >> 4, c8 = (ci & 15) * 8;
        int nb = knn[rowbase + r];
        int pt = p0 + (r >> 4);
        const float4* vp = (const float4*)(v + (size_t)nb * 128 + c8);
        const float4* up = (const float4*)(u + (size_t)pt * 128 + c8);
        float4 va = vp[0], vb = vp[1];
        float4 ua = up[0], ub = up[1];
        unsigned d0 = (unsigned)f2b(fmaxf(ua.x + va.x, 0.f)) | ((unsigned)f2b(fmaxf(ua.y + va.y, 0.f)) << 16);
        unsigned d1 = (unsigned)f2b(fmaxf(ua.z + va.z, 0.f)) | ((unsigned)f2b(fmaxf(ua.w + va.w, 0.f)) << 16);
        unsigned d2 = (unsigned)f2b(fmaxf(ub.x + vb.x, 0.f)) | ((unsigned)f2b(fmaxf(ub.y + vb.y, 0.f)) << 16);
        unsigned d3 = (unsigned)f2b(fmaxf(ub.z + vb.z, 0.f)) | ((unsigned)f2b(fmaxf(ub.w + vb.w, 0.f)) << 16);
        uint4 pk; pk.x = d0; pk.y = d1; pk.z = d2; pk.w = d3;
        *(uint4*)&h1s[r * 136 + c8] = pk;
    }
    __syncthreads();

    f32x4 acc[4][4];
    #pragma unroll
    for (int i = 0; i < 4; ++i)
        #pragma unroll
        for (int j = 0; j < 4; ++j) acc[i][j] = (f32x4){0.f, 0.f, 0.f, 0.f};

    #pragma unroll
    for (int ks = 0; ks < 4; ++ks) {
        bf16x8 bfr[4], afr[4];
        #pragma unroll
        for (int nj = 0; nj < 4; ++nj)
            bfr[nj] = ldb8(&Wl2T[(size_t)(wcn * 64 + nj * 16 + (l & 15)) * 128 + ks * 32 + (l >> 4) * 8]);
        #pragma unroll
        for (int mi = 0; mi < 4; ++mi)
            afr[mi] = ldb8(&h1s[(wr * 64 + mi * 16 + (l & 15)) * 136 + ks * 32 + (l >> 4) * 8]);
        #pragma unroll
        for (int mi = 0; mi < 4; ++mi)
            #pragma unroll
            for (int nj = 0; nj < 4; ++nj)
                acc[mi][nj] = __builtin_amdgcn_mfma_f32_16x16x32_bf16(afr[mi], bfr[nj], acc[mi][nj], 0, 0, 0);
    }

    #pragma unroll
    for (int mi = 0; mi < 4; ++mi)
        #pragma unroll
        for (int nj = 0; nj < 4; ++nj) {
            int col = wcn * 64 + nj * 16 + (l & 15);
            float bias = bl2[col];
            float m = fmaxf(acc[mi][nj][0] + bias, 0.f);
            m = fmaxf(m, fmaxf(acc[mi][nj][1] + bias, 0.f));
            m = fmaxf(m, fmaxf(acc[mi][nj][2] + bias, 0.f));
            m = fmaxf(m, fmaxf(acc[mi][nj][3] + bias, 0.f));
            m = fmaxf(m, __shfl_xor(m, 16));
            m = fmaxf(m, __shfl_xor(m, 32));
            if (l < 16) lf[(size_t)(p0 + wr * 4 + mi) * 128 + col] = m;
        }
}

// ---------------- Kernel D: ctx = relu([pf,lf]@Wc+bc); gf = max over N -----
__global__ __launch_bounds__(256) void k_ctx(
    const float* __restrict__ pf, const float* __restrict__ lf,
    const float* __restrict__ Wc, const float* __restrict__ bc,
    float* __restrict__ gf) {
    __shared__ __align__(16) char smem[67584];
    unsigned short* As = (unsigned short*)smem;            // [128][40]
    unsigned short* Bs = (unsigned short*)(smem + 10240);  // [128][40]
    float* cs = (float*)smem;                              // [128][132]
    int t = threadIdx.x;
    int l = t & 63, w = t >> 6;
    int wr = w >> 1, wcn = w & 1;
    int rowbase = blockIdx.x * 128;
    int ncol0 = blockIdx.y * 128;
    int b = rowbase >> 13;

    f32x4 acc[4][4];
    #pragma unroll
    for (int i = 0; i < 4; ++i)
        #pragma unroll
        for (int j = 0; j < 4; ++j) acc[i][j] = (f32x4){0.f, 0.f, 0.f, 0.f};

    for (int kb = 0; kb < 8; ++kb) {
        #pragma unroll
        for (int ii = 0; ii < 16; ++ii) {
            int i = t + ii * 256;
            int r = i >> 5, c = i & 31;
            int cg = kb * 32 + c;
            int p = rowbase + r;
            float v = (cg < 128) ? pf[p * 128 + cg] : lf[p * 128 + (cg - 128)];
            As[r * 40 + c] = f2b(v);
        }
        #pragma unroll
        for (int ii = 0; ii < 16; ++ii) {
            int i = t + ii * 256;
            int c = i >> 7, n = i & 127;
            Bs[n * 40 + c] = f2b(Wc[(kb * 32 + c) * 256 + ncol0 + n]);
        }
        __syncthreads();
        bf16x8 af[4], bfr[4];
        #pragma unroll
        for (int mi = 0; mi < 4; ++mi)
            af[mi] = ldb8(&As[(wr * 64 + mi * 16 + (l & 15)) * 40 + (l >> 4) * 8]);
        #pragma unroll
        for (int nj = 0; nj < 4; ++nj)
            bfr[nj] = ldb8(&Bs[(wcn * 64 + nj * 16 + (l & 15)) * 40 + (l >> 4) * 8]);
        #pragma unroll
        for (int mi = 0; mi < 4; ++mi)
            #pragma unroll
            for (int nj = 0; nj < 4; ++nj)
                acc[mi][nj] = __builtin_amdgcn_mfma_f32_16x16x32_bf16(af[mi], bfr[nj], acc[mi][nj], 0, 0, 0);
        __syncthreads();
    }
    #pragma unroll
    for (int mi = 0; mi < 4; ++mi)
        #pragma unroll
        for (int nj = 0; nj < 4; ++nj)
            #pragma unroll
            for (int rg = 0; rg < 4; ++rg) {
                int row = wr * 64 + mi * 16 + (l >> 4) * 4 + rg;
                int col = wcn * 64 + nj * 16 + (l & 15);
                cs[row * 132 + col] = fmaxf(acc[mi][nj][rg] + bc[ncol0 + col], 0.f);
            }
    __syncthreads();
    if (t < 128) {
        float m = 0.f;
        for (int r = 0; r < 128; ++r) m = fmaxf(m, cs[r * 132 + t]);
        atomicMax((unsigned int*)&gf[b * 256 + ncol0 + t], __float_as_uint(m));
    }
}

// ---------------- Kernel E: heads (Wk / Wp branch via blockIdx.y) ----------
__global__ __launch_bounds__(256) void k_head(
    const float* __restrict__ pf, const float* __restrict__ lf, const float* __restrict__ gf,
    const float* __restrict__ Wk1, const float* __restrict__ bk1,
    const float* __restrict__ Wk2, const float* __restrict__ bk2,
    const float* __restrict__ Wp1, const float* __restrict__ bp1,
    const float* __restrict__ Wp2, const float* __restrict__ bp2,
    float* __restrict__ out) {
    __shared__ __align__(16) char smem[67584];
    unsigned short* As = (unsigned short*)smem;
    unsigned short* Bs = (unsigned short*)(smem + 10240);
    float* hs = (float*)smem;  // [128][132]
    int t = threadIdx.x;
    int l = t & 63, w = t >> 6;
    int wr = w >> 1, wcn = w & 1;
    int rowbase = blockIdx.x * 128;
    int br = blockIdx.y;
    const float* W1 = br ? Wp1 : Wk1;
    const float* b1 = br ? bp1 : bk1;
    const float* W2 = br ? Wp2 : Wk2;
    const float* b2p = br ? bp2 : bk2;
    int OC = br ? 8 : 10;
    float* obase = out + (br ? (size_t)NP * 10 : 0);

    f32x4 acc[4][4];
    #pragma unroll
    for (int i = 0; i < 4; ++i)
        #pragma unroll
        for (int j = 0; j < 4; ++j) acc[i][j] = (f32x4){0.f, 0.f, 0.f, 0.f};

    for (int kb = 0; kb < 16; ++kb) {
        #pragma unroll
        for (int ii = 0; ii < 16; ++ii) {
            int i = t + ii * 256;
            int r = i >> 5, c = i & 31;
            int cg = kb * 32 + c;
            int p = rowbase + r;
            float v;
            if (cg < 128) v = pf[p * 128 + cg];
            else if (cg < 256) v = lf[p * 128 + (cg - 128)];
            else v = gf[(p >> 13) * 256 + (cg - 256)];
            As[r * 40 + c] = f2b(v);
        }
        #pragma unroll
        for (int ii = 0; ii < 16; ++ii) {
            int i = t + ii * 256;
            int c = i >> 7, n = i & 127;
            Bs[n * 40 + c] = f2b(W1[(kb * 32 + c) * 128 + n]);
        }
        __syncthreads();
        bf16x8 af[4], bfr[4];
        #pragma unroll
        for (int mi = 0; mi < 4; ++mi)
            af[mi] = ldb8(&As[(wr * 64 + mi * 16 + (l & 15)) * 40 + (l >> 4) * 8]);
        #pragma unroll
        for (int nj = 0; nj < 4; ++nj)
            bfr[nj] = ldb8(&Bs[(wcn * 64 + nj * 16 + (l & 15)) * 40 + (l >> 4) * 8]);
        #pragma unroll
        for (int mi = 0; mi < 4; ++mi)
            #pragma unroll
            for (int nj = 0; nj < 4; ++nj)
                acc[mi][nj] = __builtin_amdgcn_mfma_f32_16x16x32_bf16(af[mi], bfr[nj], acc[mi][nj], 0, 0, 0);
        __syncthreads();
    }
    #pragma unroll
    for (int mi = 0; mi < 4; ++mi)
        #pragma unroll
        for (int nj = 0; nj < 4; ++nj)
            #pragma unroll
            for (int rg = 0; rg < 4; ++rg) {
                int row = wr * 64 + mi * 16 + (l >> 4) * 4 + rg;
                int col = wcn * 64 + nj * 16 + (l & 15);
                hs[row * 132 + col] = fmaxf(acc[mi][nj][rg] + b1[col], 0.f);
            }
    __syncthreads();
    for (int o = t; o < 128 * OC; o += 256) {
        int r = o / OC, c = o % OC;
        float a = b2p[c];
        for (int k2 = 0; k2 < 128; ++k2) a += hs[r * 132 + k2] * W2[k2 * OC + c];
        obase[(size_t)(rowbase + r) * OC + c] = a;
    }
}

extern "C" void kernel_launch(void* const* d_in, const int* in_sizes, int n_in,
                              void* d_out, int out_size, void* d_ws, size_t ws_size,
                              hipStream_t stream) {
    const float* pts = (const float*)d_in[0];
    const float* nrm = (const float*)d_in[1];
    const float* We1 = (const float*)d_in[2];
    const float* be1 = (const float*)d_in[3];
    const float* We2 = (const float*)d_in[4];
    const float* be2 = (const float*)d_in[5];
    const float* Wl1 = (const float*)d_in[6];
    const float* bl1 = (const float*)d_in[7];
    const float* Wl2 = (const float*)d_in[8];
    const float* bl2 = (const float*)d_in[9];
    const float* Wc  = (const float*)d_in[10];
    const float* bc  = (const float*)d_in[11];
    const float* Wk1 = (const float*)d_in[12];
    const float* bk1 = (const float*)d_in[13];
    const float* Wk2 = (const float*)d_in[14];
    const float* bk2 = (const float*)d_in[15];
    const float* Wp1 = (const float*)d_in[16];
    const float* bp1 = (const float*)d_in[17];
    const float* Wp2 = (const float*)d_in[18];
    const float* bp2 = (const float*)d_in[19];
    float* out = (float*)d_out;

    char* ws = (char*)d_ws;
    size_t off = 0;
    float* pf = (float*)(ws + off);       off += (size_t)NP * 128 * 4;   // 8.39 MB
    float* lf = (float*)(ws + off);       off += (size_t)NP * 128 * 4;   // 8.39 MB
    float* u  = (float*)(ws + off);       off += (size_t)NP * 128 * 4;   // 8.39 MB
    float* v  = (float*)(ws + off);       off += (size_t)NP * 128 * 4;   // 8.39 MB
    int* knn  = (int*)(ws + off);         off += (size_t)NP * 16 * 4;    // 1.05 MB
    float* gf = (float*)(ws + off);       off += 2048;
    float4* pts4 = (float4*)(ws + off);   off += (size_t)NP * 16;        // 256 KB
    float* Wuvcat = (float*)(ws + off);   off += 128 * 256 * 4;          // 128 KB
    float* bias_cat = (float*)(ws + off); off += 1024;
    unsigned short* Wl2T = (unsigned short*)(ws + off); off += 128 * 128 * 2;

    hipLaunchKernelGGL(k_pf, dim3(256), dim3(256), 0, stream,
                       pts, nrm, We1, be1, We2, be2, pf, gf, pts4);
    hipLaunchKernelGGL(k_prep, dim3(64), dim3(256), 0, stream,
                       Wl1, bl1, Wl2, Wuvcat, bias_cat, Wl2T);
    hipLaunchKernelGGL(k_knn, dim3(4096), dim3(256), 0, stream, pts4, knn);
    hipLaunchKernelGGL(k_uv, dim3(128, 2), dim3(256), 0, stream,
                       pf, Wuvcat, bias_cat, u, v);
    hipLaunchKernelGGL(k_edge, dim3(2048), dim3(256), 0, stream,
                       u, v, knn, Wl2T, bl2, lf);
    hipLaunchKernelGGL(k_ctx, dim3(128, 2), dim3(256), 0, stream,
                       pf, lf, Wc, bc, gf);
    hipLaunchKernelGGL(k_head, dim3(128, 2), dim3(256), 0, stream,
                       pf, lf, gf, Wk1, bk1, Wk2, bk2, Wp1, bp1, Wp2, bp2, out);
}

// Round 9
// 411.531 us; speedup vs baseline: 3.1211x; 1.0925x over previous
//
#include <hip/hip_runtime.h>

#define B_ 2
#define N_ 8192
#define NP 16384   // B_*N_
#define K_ 16
#define H_ 128
#define KCAP 512

typedef short bf16x8 __attribute__((ext_vector_type(8)));
typedef float f32x4 __attribute__((ext_vector_type(4)));

__device__ inline unsigned short f2b(float f) {
    unsigned u = __builtin_bit_cast(unsigned, f);
    unsigned r = (u + 0x7fff + ((u >> 16) & 1)) >> 16;
    return (unsigned short)r;
}
__device__ inline bf16x8 ldb8(const unsigned short* p) {
    return *(const bf16x8*)p;
}
__device__ inline uint4 pack8(float4 a, float4 b) {
    uint4 pk;
    pk.x = (unsigned)f2b(a.x) | ((unsigned)f2b(a.y) << 16);
    pk.y = (unsigned)f2b(a.z) | ((unsigned)f2b(a.w) << 16);
    pk.z = (unsigned)f2b(b.x) | ((unsigned)f2b(b.y) << 16);
    pk.w = (unsigned)f2b(b.z) | ((unsigned)f2b(b.w) << 16);
    return pk;
}

// ------- Kernel A: pf = relu(relu(x@We1+be1)@We2+be2); zero gf; pack pts4 --
__global__ __launch_bounds__(256) void k_pf(
    const float* __restrict__ pts, const float* __restrict__ nrm,
    const float* __restrict__ We1, const float* __restrict__ be1,
    const float* __restrict__ We2, const float* __restrict__ be2,
    float* __restrict__ pf, float* __restrict__ gf, float4* __restrict__ pts4) {
    __shared__ float w2s[128 * 128];
    __shared__ float w1s[6 * 128];
    __shared__ float b1s[128], b2s[128];
    __shared__ float xs[2][6];
    __shared__ float h1s[2][128];
    int t = threadIdx.x;
    for (int i = t; i < 128 * 128; i += 256) w2s[i] = We2[i];
    for (int i = t; i < 6 * 128; i += 256) w1s[i] = We1[i];
    if (t < 128) { b1s[t] = be1[t]; b2s[t] = be2[t]; }
    if (blockIdx.x == 0) { gf[t] = 0.f; gf[256 + t] = 0.f; }
    int base = blockIdx.x * 64;
    if (t < 64) {  // fold of k_pack: this block's 64 points
        int p = base + t;
        float x = pts[p * 3], y = pts[p * 3 + 1], z = pts[p * 3 + 2];
        float sq = __fadd_rn(__fadd_rn(__fmul_rn(x, x), __fmul_rn(y, y)), __fmul_rn(z, z));
        pts4[p] = make_float4(x, y, z, sq);
    }
    __syncthreads();
    int g = t >> 7, h = t & 127;
    for (int it = 0; it < 32; ++it) {
        int p = base + it * 2 + g;
        if (h < 3) xs[g][h] = pts[p * 3 + h];
        else if (h < 6) xs[g][h] = nrm[p * 3 + h - 3];
        __syncthreads();
        float a = b1s[h];
        #pragma unroll
        for (int c = 0; c < 6; ++c) a += xs[g][c] * w1s[c * 128 + h];
        h1s[g][h] = fmaxf(a, 0.f);
        __syncthreads();
        float o = b2s[h];
        #pragma unroll 8
        for (int c = 0; c < 128; ++c) o += h1s[g][c] * w2s[c * 128 + h];
        pf[p * 128 + h] = fmaxf(o, 0.f);
        __syncthreads();
    }
}

// ---------------- Kernel P: prep factored + transposed bf16 weights --------
__global__ __launch_bounds__(256) void k_prep(
    const float* __restrict__ Wl1, const float* __restrict__ bl1,
    const float* __restrict__ Wl2, const float* __restrict__ Wc,
    const float* __restrict__ Wk1, const float* __restrict__ Wp1,
    unsigned short* __restrict__ WuvT, float* __restrict__ bias_cat,
    unsigned short* __restrict__ Wl2T, unsigned short* __restrict__ WcT,
    unsigned short* __restrict__ Wk1T, unsigned short* __restrict__ Wp1T) {
    int tid = blockIdx.x * 256 + threadIdx.x;
    int stride = gridDim.x * 256;
    for (int i = tid; i < 256 * 128; i += stride) {
        int n = i >> 7, k = i & 127;
        float val = (n < 128) ? Wl1[k * 128 + n] - Wl1[(k + 128) * 128 + n]
                              : Wl1[(k + 128) * 128 + (n - 128)];
        WuvT[i] = f2b(val);
    }
    for (int i = tid; i < 256; i += stride) bias_cat[i] = (i < 128) ? bl1[i] : 0.f;
    for (int i = tid; i < 128 * 128; i += stride) {
        int n = i >> 7, k = i & 127;
        Wl2T[i] = f2b(Wl2[k * 128 + n]);
    }
    for (int i = tid; i < 256 * 256; i += stride) {
        int n = i >> 8, k = i & 255;
        WcT[i] = f2b(Wc[k * 256 + n]);
    }
    for (int i = tid; i < 128 * 512; i += stride) {
        int n = i >> 9, k = i & 511;
        Wk1T[i] = f2b(Wk1[k * 128 + n]);
        Wp1T[i] = f2b(Wp1[k * 128 + n]);
    }
}

// ------- Kernel B: 16-NN. Tile-0 histogram -> float threshold; pure filter -
__global__ __launch_bounds__(256) void k_knn(
    const float4* __restrict__ pts4, int* __restrict__ knn) {
    __shared__ float4 tile[1024];                  // 16 KB
    __shared__ int hist[4][260];                   // 4.06 KB
    __shared__ unsigned long long buf[4][KCAP];    // 16 KB
    int t = threadIdx.x, w = t >> 6, l = t & 63;
    int b = blockIdx.x >> 11;
    int q = (blockIdx.x & 2047) * 4 + w;
    const float4* pb = pts4 + b * N_;
    float4 qp = pb[q];
    for (int i = l; i < 256; i += 64) hist[w][i] = 0;
    int cntw = 0;

    #pragma unroll
    for (int i = 0; i < 4; ++i) tile[t + 256 * i] = pb[t + 256 * i];
    __syncthreads();
    #pragma unroll 2
    for (int j = l; j < 1024; j += 64) {
        float4 c = tile[j];
        float dot = __fadd_rn(__fadd_rn(__fmul_rn(qp.x, c.x), __fmul_rn(qp.y, c.y)), __fmul_rn(qp.z, c.z));
        float d2 = __fsub_rn(__fadd_rn(qp.w, c.w), __fmul_rn(2.f, dot));
        d2 = (j == q) ? 1e30f : d2;
        unsigned uu = __float_as_uint(d2);
        int bk = (d2 < 0.f) ? 0 : min(255, max(0, (int)(uu >> 21) - 400));
        atomicAdd(&hist[w][bk], 1);
    }
    float Tf;
    {
        int h0 = hist[w][4 * l], h1 = hist[w][4 * l + 1], h2 = hist[w][4 * l + 2], h3 = hist[w][4 * l + 3];
        int c0 = h0, c1 = c0 + h1, c2 = c1 + h2, c3 = c2 + h3;
        int tot = c3;
        int inc = tot;
        for (int off = 1; off < 64; off <<= 1) {
            int vv = __shfl_up(inc, off);
            if (l >= off) inc += vv;
        }
        int excl = inc - tot;
        int Bc = 255;
        if      (excl + c0 >= 16) Bc = 4 * l;
        else if (excl + c1 >= 16) Bc = 4 * l + 1;
        else if (excl + c2 >= 16) Bc = 4 * l + 2;
        else if (excl + c3 >= 16) Bc = 4 * l + 3;
        for (int m = 1; m < 64; m <<= 1) Bc = min(Bc, __shfl_xor(Bc, m));
        Tf = __uint_as_float((unsigned)(Bc + 401) << 21);
    }
    for (int j = l; j < 1024; j += 64) {
        float4 c = tile[j];
        float dot = __fadd_rn(__fadd_rn(__fmul_rn(qp.x, c.x), __fmul_rn(qp.y, c.y)), __fmul_rn(qp.z, c.z));
        float d2 = __fsub_rn(__fadd_rn(qp.w, c.w), __fmul_rn(2.f, dot));
        d2 = (j == q) ? 1e30f : d2;
        bool take = (d2 < Tf);
        unsigned long long mask = __ballot(take);
        if (take) {
            unsigned du = __float_as_uint(d2);
            unsigned mu = du ^ (unsigned)(((int)du >> 31) | 0x80000000);
            int pos = cntw + __popcll(mask & ((1ull << l) - 1ull));
            if (pos < KCAP) buf[w][pos] = ((unsigned long long)mu << 32) | (unsigned)j;
        }
        cntw += __popcll(mask);
    }

    for (int t0 = 1024; t0 < N_; t0 += 1024) {
        __syncthreads();
        #pragma unroll
        for (int i = 0; i < 4; ++i) tile[t + 256 * i] = pb[t0 + t + 256 * i];
        __syncthreads();
        #pragma unroll 2
        for (int j = l; j < 1024; j += 64) {
            float4 c = tile[j];
            float dot = __fadd_rn(__fadd_rn(__fmul_rn(qp.x, c.x), __fmul_rn(qp.y, c.y)), __fmul_rn(qp.z, c.z));
            float d2 = __fsub_rn(__fadd_rn(qp.w, c.w), __fmul_rn(2.f, dot));
            d2 = (t0 + j == q) ? 1e30f : d2;
            bool take = (d2 < Tf);
            unsigned long long mask = __ballot(take);
            if (take) {
                unsigned du = __float_as_uint(d2);
                unsigned mu = du ^ (unsigned)(((int)du >> 31) | 0x80000000);
                int pos = cntw + __popcll(mask & ((1ull << l) - 1ull));
                if (pos < KCAP) buf[w][pos] = ((unsigned long long)mu << 32) | (unsigned)(t0 + j);
            }
            cntw += __popcll(mask);
        }
    }
    int m_ = min(cntw, KCAP);

    unsigned long long key[8];
    #pragma unroll
    for (int r = 0; r < 8; ++r) {
        int e = l + 64 * r;
        key[r] = (e < m_) ? buf[w][e] : ~0ull;
    }
    for (int r16 = 0; r16 < 16; ++r16) {
        unsigned long long mn = key[0];
        #pragma unroll
        for (int r = 1; r < 8; ++r) mn = (key[r] < mn) ? key[r] : mn;
        unsigned long long wv = mn;
        for (int m = 1; m < 64; m <<= 1) {
            unsigned long long o = __shfl_xor(wv, m);
            wv = (o < wv) ? o : wv;
        }
        if (l == 0) knn[((size_t)b * N_ + q) * 16 + r16] = b * N_ + (int)(wv & 0xffffffffu);
        #pragma unroll
        for (int r = 0; r < 8; ++r) if (key[r] == wv) key[r] = ~0ull;
    }
}

// ---- Kernel U: uv = pf @ WuvT^T + bias_cat (A in LDS, B direct-global) ----
__global__ __launch_bounds__(256) void k_uv(
    const float* __restrict__ pf, const unsigned short* __restrict__ WuvT,
    const float* __restrict__ bias_cat,
    float* __restrict__ u, float* __restrict__ v) {
    __shared__ __align__(16) unsigned short As[128 * 136];
    int t = threadIdx.x;
    int l = t & 63, w = t >> 6;
    int wr = w >> 1, wcn = w & 1;
    int rowbase = blockIdx.x * 128;
    int ncol0 = blockIdx.y * 128;

    #pragma unroll
    for (int i = 0; i < 8; ++i) {
        int ci = t + 256 * i;
        int r = ci >> 4, c8 = (ci & 15) * 8;
        const float4* sp = (const float4*)(pf + (size_t)(rowbase + r) * 128 + c8);
        *(uint4*)&As[r * 136 + c8] = pack8(sp[0], sp[1]);
    }
    __syncthreads();

    f32x4 acc[4][4];
    #pragma unroll
    for (int i = 0; i < 4; ++i)
        #pragma unroll
        for (int j = 0; j < 4; ++j) acc[i][j] = (f32x4){0.f, 0.f, 0.f, 0.f};

    #pragma unroll
    for (int ks = 0; ks < 4; ++ks) {
        bf16x8 bfr[4], afr[4];
        #pragma unroll
        for (int nj = 0; nj < 4; ++nj)
            bfr[nj] = ldb8(&WuvT[(size_t)(ncol0 + wcn * 64 + nj * 16 + (l & 15)) * 128 + ks * 32 + (l >> 4) * 8]);
        #pragma unroll
        for (int mi = 0; mi < 4; ++mi)
            afr[mi] = ldb8(&As[(wr * 64 + mi * 16 + (l & 15)) * 136 + ks * 32 + (l >> 4) * 8]);
        #pragma unroll
        for (int mi = 0; mi < 4; ++mi)
            #pragma unroll
            for (int nj = 0; nj < 4; ++nj)
                acc[mi][nj] = __builtin_amdgcn_mfma_f32_16x16x32_bf16(afr[mi], bfr[nj], acc[mi][nj], 0, 0, 0);
    }
    float* outp = (ncol0 == 0) ? u : v;
    #pragma unroll
    for (int mi = 0; mi < 4; ++mi)
        #pragma unroll
        for (int nj = 0; nj < 4; ++nj) {
            int col = wcn * 64 + nj * 16 + (l & 15);
            float bias = bias_cat[ncol0 + col];
            #pragma unroll
            for (int rg = 0; rg < 4; ++rg) {
                int row = wr * 64 + mi * 16 + (l >> 4) * 4 + rg;
                outp[(size_t)(rowbase + row) * 128 + col] = acc[mi][nj][rg] + bias;
            }
        }
}

// ---------------- Kernel C: edge layer2 GEMM + max over K ------------------
__global__ __launch_bounds__(256) void k_edge(
    const float* __restrict__ u, const float* __restrict__ v,
    const int* __restrict__ knn, const unsigned short* __restrict__ Wl2T,
    const float* __restrict__ bl2, float* __restrict__ lf) {
    __shared__ __align__(16) unsigned short h1s[128 * 136];  // 34816 B
    int t = threadIdx.x;
    int l = t & 63, w = t >> 6;
    int wr = w >> 1, wcn = w & 1;
    int rowbase = blockIdx.x * 128;
    int p0 = blockIdx.x * 8;

    #pragma unroll 2
    for (int i = 0; i < 8; ++i) {
        int ci = t + 256 * i;
        int r = ci >> 4, c8 = (ci & 15) * 8;
        int nb = knn[rowbase + r];
        int pt = p0 + (r >> 4);
        const float4* vp = (const float4*)(v + (size_t)nb * 128 + c8);
        const float4* up = (const float4*)(u + (size_t)pt * 128 + c8);
        float4 va = vp[0], vb = vp[1];
        float4 ua = up[0], ub = up[1];
        unsigned d0 = (unsigned)f2b(fmaxf(ua.x + va.x, 0.f)) | ((unsigned)f2b(fmaxf(ua.y + va.y, 0.f)) << 16);
        unsigned d1 = (unsigned)f2b(fmaxf(ua.z + va.z, 0.f)) | ((unsigned)f2b(fmaxf(ua.w + va.w, 0.f)) << 16);
        unsigned d2 = (unsigned)f2b(fmaxf(ub.x + vb.x, 0.f)) | ((unsigned)f2b(fmaxf(ub.y + vb.y, 0.f)) << 16);
        unsigned d3 = (unsigned)f2b(fmaxf(ub.z + vb.z, 0.f)) | ((unsigned)f2b(fmaxf(ub.w + vb.w, 0.f)) << 16);
        uint4 pk; pk.x = d0; pk.y = d1; pk.z = d2; pk.w = d3;
        *(uint4*)&h1s[r * 136 + c8] = pk;
    }
    __syncthreads();

    f32x4 acc[4][4];
    #pragma unroll
    for (int i = 0; i < 4; ++i)
        #pragma unroll
        for (int j = 0; j < 4; ++j) acc[i][j] = (f32x4){0.f, 0.f, 0.f, 0.f};

    #pragma unroll
    for (int ks = 0; ks < 4; ++ks) {
        bf16x8 bfr[4], afr[4];
        #pragma unroll
        for (int nj = 0; nj < 4; ++nj)
            bfr[nj] = ldb8(&Wl2T[(size_t)(wcn * 64 + nj * 16 + (l & 15)) * 128 + ks * 32 + (l >> 4) * 8]);
        #pragma unroll
        for (int mi = 0; mi < 4; ++mi)
            afr[mi] = ldb8(&h1s[(wr * 64 + mi * 16 + (l & 15)) * 136 + ks * 32 + (l >> 4) * 8]);
        #pragma unroll
        for (int mi = 0; mi < 4; ++mi)
            #pragma unroll
            for (int nj = 0; nj < 4; ++nj)
                acc[mi][nj] = __builtin_amdgcn_mfma_f32_16x16x32_bf16(afr[mi], bfr[nj], acc[mi][nj], 0, 0, 0);
    }

    #pragma unroll
    for (int mi = 0; mi < 4; ++mi)
        #pragma unroll
        for (int nj = 0; nj < 4; ++nj) {
            int col = wcn * 64 + nj * 16 + (l & 15);
            float bias = bl2[col];
            float m = fmaxf(acc[mi][nj][0] + bias, 0.f);
            m = fmaxf(m, fmaxf(acc[mi][nj][1] + bias, 0.f));
            m = fmaxf(m, fmaxf(acc[mi][nj][2] + bias, 0.f));
            m = fmaxf(m, fmaxf(acc[mi][nj][3] + bias, 0.f));
            m = fmaxf(m, __shfl_xor(m, 16));
            m = fmaxf(m, __shfl_xor(m, 32));
            if (l < 16) lf[(size_t)(p0 + wr * 4 + mi) * 128 + col] = m;
        }
}

// -- Kernel D: ctx col-max fused in-register; gf via atomicMax (no cs LDS) --
__global__ __launch_bounds__(256) void k_ctx(
    const float* __restrict__ pf, const float* __restrict__ lf,
    const unsigned short* __restrict__ WcT, const float* __restrict__ bc,
    float* __restrict__ gf) {
    __shared__ __align__(16) unsigned short As[128 * 136];
    int t = threadIdx.x;
    int l = t & 63, w = t >> 6;
    int wr = w >> 1, wcn = w & 1;
    int rowbase = blockIdx.x * 128;
    int ncol0 = blockIdx.y * 128;
    int b = rowbase >> 13;

    f32x4 acc[4][4];
    #pragma unroll
    for (int i = 0; i < 4; ++i)
        #pragma unroll
        for (int j = 0; j < 4; ++j) acc[i][j] = (f32x4){0.f, 0.f, 0.f, 0.f};

    for (int kb = 0; kb < 2; ++kb) {
        const float* src = kb ? lf : pf;
        #pragma unroll
        for (int i = 0; i < 8; ++i) {
            int ci = t + 256 * i;
            int r = ci >> 4, c8 = (ci & 15) * 8;
            const float4* sp = (const float4*)(src + (size_t)(rowbase + r) * 128 + c8);
            *(uint4*)&As[r * 136 + c8] = pack8(sp[0], sp[1]);
        }
        __syncthreads();
        #pragma unroll
        for (int ks = 0; ks < 4; ++ks) {
            bf16x8 bfr[4], afr[4];
            #pragma unroll
            for (int nj = 0; nj < 4; ++nj)
                bfr[nj] = ldb8(&WcT[(size_t)(ncol0 + wcn * 64 + nj * 16 + (l & 15)) * 256 + kb * 128 + ks * 32 + (l >> 4) * 8]);
            #pragma unroll
            for (int mi = 0; mi < 4; ++mi)
                afr[mi] = ldb8(&As[(wr * 64 + mi * 16 + (l & 15)) * 136 + ks * 32 + (l >> 4) * 8]);
            #pragma unroll
            for (int mi = 0; mi < 4; ++mi)
                #pragma unroll
                for (int nj = 0; nj < 4; ++nj)
                    acc[mi][nj] = __builtin_amdgcn_mfma_f32_16x16x32_bf16(afr[mi], bfr[nj], acc[mi][nj], 0, 0, 0);
        }
        __syncthreads();
    }
    #pragma unroll
    for (int nj = 0; nj < 4; ++nj) {
        int col = ncol0 + wcn * 64 + nj * 16 + (l & 15);
        float m = acc[0][nj][0];
        #pragma unroll
        for (int mi = 0; mi < 4; ++mi)
            #pragma unroll
            for (int rg = 0; rg < 4; ++rg) m = fmaxf(m, acc[mi][nj][rg]);
        m = fmaxf(m + bc[col], 0.f);
        m = fmaxf(m, __shfl_xor(m, 16));
        m = fmaxf(m, __shfl_xor(m, 32));
        if (l < 16) atomicMax((unsigned int*)&gf[b * 256 + col], __float_as_uint(m));
    }
}

// ---------------- Kernel E: heads (vectorized staging, global-B) -----------
__global__ __launch_bounds__(256) void k_head(
    const float* __restrict__ pf, const float* __restrict__ lf, const float* __restrict__ gf,
    const unsigned short* __restrict__ Wk1T, const float* __restrict__ bk1,
    const float* __restrict__ Wk2, const float* __restrict__ bk2,
    const unsigned short* __restrict__ Wp1T, const float* __restrict__ bp1,
    const float* __restrict__ Wp2, const float* __restrict__ bp2,
    float* __restrict__ out) {
    __shared__ __align__(16) char smem[67584];
    unsigned short* As = (unsigned short*)smem;  // [128][136] bf16
    float* hs = (float*)smem;                    // [128][132] f32 (reuse)
    int t = threadIdx.x;
    int l = t & 63, w = t >> 6;
    int wr = w >> 1, wcn = w & 1;
    int rowbase = blockIdx.x * 128;
    int b = rowbase >> 13;
    int br = blockIdx.y;
    const unsigned short* W1T = br ? Wp1T : Wk1T;
    const float* b1 = br ? bp1 : bk1;
    const float* W2 = br ? Wp2 : Wk2;
    const float* b2p = br ? bp2 : bk2;
    int OC = br ? 8 : 10;
    float* obase = out + (br ? (size_t)NP * 10 : 0);

    f32x4 acc[4][4];
    #pragma unroll
    for (int i = 0; i < 4; ++i)
        #pragma unroll
        for (int j = 0; j < 4; ++j) acc[i][j] = (f32x4){0.f, 0.f, 0.f, 0.f};

    for (int kb = 0; kb < 4; ++kb) {
        #pragma unroll
        for (int i = 0; i < 8; ++i) {
            int ci = t + 256 * i;
            int r = ci >> 4, c8 = (ci & 15) * 8;
            const float4* sp;
            if (kb == 0)      sp = (const float4*)(pf + (size_t)(rowbase + r) * 128 + c8);
            else if (kb == 1) sp = (const float4*)(lf + (size_t)(rowbase + r) * 128 + c8);
            else              sp = (const float4*)(gf + b * 256 + (kb - 2) * 128 + c8);
            *(uint4*)&As[r * 136 + c8] = pack8(sp[0], sp[1]);
        }
        __syncthreads();
        #pragma unroll
        for (int ks = 0; ks < 4; ++ks) {
            bf16x8 bfr[4], afr[4];
            #pragma unroll
            for (int nj = 0; nj < 4; ++nj)
                bfr[nj] = ldb8(&W1T[(size_t)(wcn * 64 + nj * 16 + (l & 15)) * 512 + kb * 128 + ks * 32 + (l >> 4) * 8]);
            #pragma unroll
            for (int mi = 0; mi < 4; ++mi)
                afr[mi] = ldb8(&As[(wr * 64 + mi * 16 + (l & 15)) * 136 + ks * 32 + (l >> 4) * 8]);
            #pragma unroll
            for (int mi = 0; mi < 4; ++mi)
                #pragma unroll
                for (int nj = 0; nj < 4; ++nj)
                    acc[mi][nj] = __builtin_amdgcn_mfma_f32_16x16x32_bf16(afr[mi], bfr[nj], acc[mi][nj], 0, 0, 0);
        }
        __syncthreads();
    }
    #pragma unroll
    for (int mi = 0; mi < 4; ++mi)
        #pragma unroll
        for (int nj = 0; nj < 4; ++nj)
            #pragma unroll
            for (int rg = 0; rg < 4; ++rg) {
                int row = wr * 64 + mi * 16 + (l >> 4) * 4 + rg;
                int col = wcn * 64 + nj * 16 + (l & 15);
                hs[row * 132 + col] = fmaxf(acc[mi][nj][rg] + b1[col], 0.f);
            }
    __syncthreads();
    for (int o = t; o < 128 * OC; o += 256) {
        int r = o / OC, c = o % OC;
        float a = b2p[c];
        for (int k2 = 0; k2 < 128; ++k2) a += hs[r * 132 + k2] * W2[k2 * OC + c];
        obase[(size_t)(rowbase + r) * OC + c] = a;
    }
}

extern "C" void kernel_launch(void* const* d_in, const int* in_sizes, int n_in,
                              void* d_out, int out_size, void* d_ws, size_t ws_size,
                              hipStream_t stream) {
    const float* pts = (const float*)d_in[0];
    const float* nrm = (const float*)d_in[1];
    const float* We1 = (const float*)d_in[2];
    const float* be1 = (const float*)d_in[3];
    const float* We2 = (const float*)d_in[4];
    const float* be2 = (const float*)d_in[5];
    const float* Wl1 = (const float*)d_in[6];
    const float* bl1 = (const float*)d_in[7];
    const float* Wl2 = (const float*)d_in[8];
    const float* bl2 = (const float*)d_in[9];
    const float* Wc  = (const float*)d_in[10];
    const float* bc  = (const float*)d_in[11];
    const float* Wk1 = (const float*)d_in[12];
    const float* bk1 = (const float*)d_in[13];
    const float* Wk2 = (const float*)d_in[14];
    const float* bk2 = (const float*)d_in[15];
    const float* Wp1 = (const float*)d_in[16];
    const float* bp1 = (const float*)d_in[17];
    const float* Wp2 = (const float*)d_in[18];
    const float* bp2 = (const float*)d_in[19];
    float* out = (float*)d_out;

    char* ws = (char*)d_ws;
    size_t off = 0;
    float* pf = (float*)(ws + off);       off += (size_t)NP * 128 * 4;   // 8.39 MB
    float* lf = (float*)(ws + off);       off += (size_t)NP * 128 * 4;   // 8.39 MB
    float* u  = (float*)(ws + off);       off += (size_t)NP * 128 * 4;   // 8.39 MB
    float* v  = (float*)(ws + off);       off += (size_t)NP * 128 * 4;   // 8.39 MB
    int* knn  = (int*)(ws + off);         off += (size_t)NP * 16 * 4;    // 1.05 MB
    float* gf = (float*)(ws + off);       off += 2048;
    float4* pts4 = (float4*)(ws + off);   off += (size_t)NP * 16;        // 256 KB
    float* bias_cat = (float*)(ws + off); off += 1024;
    unsigned short* WuvT = (unsigned short*)(ws + off); off += 256 * 128 * 2;
    unsigned short* Wl2T = (unsigned short*)(ws + off); off += 128 * 128 * 2;
    unsigned short* WcT  = (unsigned short*)(ws + off); off += 256 * 256 * 2;
    unsigned short* Wk1T = (unsigned short*)(ws + off); off += 128 * 512 * 2;
    unsigned short* Wp1T = (unsigned short*)(ws + off); off += 128 * 512 * 2;

    hipLaunchKernelGGL(k_pf, dim3(256), dim3(256), 0, stream,
                       pts, nrm, We1, be1, We2, be2, pf, gf, pts4);
    hipLaunchKernelGGL(k_prep, dim3(64), dim3(256), 0, stream,
                       Wl1, bl1, Wl2, Wc, Wk1, Wp1,
                       WuvT, bias_cat, Wl2T, WcT, Wk1T, Wp1T);
    hipLaunchKernelGGL(k_knn, dim3(4096), dim3(256), 0, stream, pts4, knn);
    hipLaunchKernelGGL(k_uv, dim3(128, 2), dim3(256), 0, stream,
                       pf, WuvT, bias_cat, u, v);
    hipLaunchKernelGGL(k_edge, dim3(2048), dim3(256), 0, stream,
                       u, v, knn, Wl2T, bl2, lf);
    hipLaunchKernelGGL(k_ctx, dim3(128, 2), dim3(256), 0, stream,
                       pf, lf, WcT, bc, gf);
    hipLaunchKernelGGL(k_head, dim3(128, 2), dim3(256), 0, stream,
                       pf, lf, gf, Wk1T, bk1, Wk2, bk2, Wp1T, bp1, Wp2, bp2, out);
}

// Round 10
// 391.071 us; speedup vs baseline: 3.2844x; 1.0523x over previous
//
#include <hip/hip_runtime.h>

#define B_ 2
#define N_ 8192
#define NP 16384   // B_*N_
#define K_ 16
#define H_ 128
#define KCAP 512

typedef short bf16x8 __attribute__((ext_vector_type(8)));
typedef float f32x4 __attribute__((ext_vector_type(4)));

__device__ inline unsigned short f2b(float f) {
    unsigned u = __builtin_bit_cast(unsigned, f);
    unsigned r = (u + 0x7fff + ((u >> 16) & 1)) >> 16;
    return (unsigned short)r;
}
__device__ inline bf16x8 ldb8(const unsigned short* p) {
    return *(const bf16x8*)p;
}
__device__ inline uint4 pack8(float4 a, float4 b) {
    uint4 pk;
    pk.x = (unsigned)f2b(a.x) | ((unsigned)f2b(a.y) << 16);
    pk.y = (unsigned)f2b(a.z) | ((unsigned)f2b(a.w) << 16);
    pk.z = (unsigned)f2b(b.x) | ((unsigned)f2b(b.y) << 16);
    pk.w = (unsigned)f2b(b.z) | ((unsigned)f2b(b.w) << 16);
    return pk;
}

// ------- Kernel A: pf = relu(relu(x@We1+be1)@We2+be2); zero gf; pack pts4 --
__global__ __launch_bounds__(256) void k_pf(
    const float* __restrict__ pts, const float* __restrict__ nrm,
    const float* __restrict__ We1, const float* __restrict__ be1,
    const float* __restrict__ We2, const float* __restrict__ be2,
    float* __restrict__ pf, float* __restrict__ gf, float4* __restrict__ pts4) {
    __shared__ float w2s[128 * 128];
    __shared__ float w1s[6 * 128];
    __shared__ float b1s[128], b2s[128];
    __shared__ float xs[2][6];
    __shared__ float h1s[2][128];
    int t = threadIdx.x;
    for (int i = t; i < 128 * 128; i += 256) w2s[i] = We2[i];
    for (int i = t; i < 6 * 128; i += 256) w1s[i] = We1[i];
    if (t < 128) { b1s[t] = be1[t]; b2s[t] = be2[t]; }
    if (blockIdx.x == 0) { gf[t] = 0.f; gf[256 + t] = 0.f; }
    int base = blockIdx.x * 64;
    if (t < 64) {  // fold of k_pack: this block's 64 points
        int p = base + t;
        float x = pts[p * 3], y = pts[p * 3 + 1], z = pts[p * 3 + 2];
        float sq = __fadd_rn(__fadd_rn(__fmul_rn(x, x), __fmul_rn(y, y)), __fmul_rn(z, z));
        pts4[p] = make_float4(x, y, z, sq);
    }
    __syncthreads();
    int g = t >> 7, h = t & 127;
    for (int it = 0; it < 32; ++it) {
        int p = base + it * 2 + g;
        if (h < 3) xs[g][h] = pts[p * 3 + h];
        else if (h < 6) xs[g][h] = nrm[p * 3 + h - 3];
        __syncthreads();
        float a = b1s[h];
        #pragma unroll
        for (int c = 0; c < 6; ++c) a += xs[g][c] * w1s[c * 128 + h];
        h1s[g][h] = fmaxf(a, 0.f);
        __syncthreads();
        float o = b2s[h];
        #pragma unroll 8
        for (int c = 0; c < 128; ++c) o += h1s[g][c] * w2s[c * 128 + h];
        pf[p * 128 + h] = fmaxf(o, 0.f);
        __syncthreads();
    }
}

// ---------------- Kernel P: prep factored + transposed bf16 weights --------
__global__ __launch_bounds__(256) void k_prep(
    const float* __restrict__ Wl1, const float* __restrict__ bl1,
    const float* __restrict__ Wl2, const float* __restrict__ Wc,
    const float* __restrict__ Wk1, const float* __restrict__ Wp1,
    unsigned short* __restrict__ WuvT, float* __restrict__ bias_cat,
    unsigned short* __restrict__ Wl2T, unsigned short* __restrict__ WcT,
    unsigned short* __restrict__ Wk1T, unsigned short* __restrict__ Wp1T) {
    int tid = blockIdx.x * 256 + threadIdx.x;
    int stride = gridDim.x * 256;
    for (int i = tid; i < 256 * 128; i += stride) {
        int n = i >> 7, k = i & 127;
        float val = (n < 128) ? Wl1[k * 128 + n] - Wl1[(k + 128) * 128 + n]
                              : Wl1[(k + 128) * 128 + (n - 128)];
        WuvT[i] = f2b(val);
    }
    for (int i = tid; i < 256; i += stride) bias_cat[i] = (i < 128) ? bl1[i] : 0.f;
    for (int i = tid; i < 128 * 128; i += stride) {
        int n = i >> 7, k = i & 127;
        Wl2T[i] = f2b(Wl2[k * 128 + n]);
    }
    for (int i = tid; i < 256 * 256; i += stride) {
        int n = i >> 8, k = i & 255;
        WcT[i] = f2b(Wc[k * 256 + n]);
    }
    for (int i = tid; i < 128 * 512; i += stride) {
        int n = i >> 9, k = i & 511;
        Wk1T[i] = f2b(Wk1[k * 128 + n]);
        Wp1T[i] = f2b(Wp1[k * 128 + n]);
    }
}

// ------- Kernel B: 16-NN. Barrier-free: direct-global candidate stream,
//         tile-0 histogram -> float threshold, per-wave private state.
//         Self excluded in hist; enters buf (d2=0, global min); skipped
//         at extraction (17 rounds, emit 16 non-self). ----------------------
__global__ __launch_bounds__(256) void k_knn(
    const float4* __restrict__ pts4, int* __restrict__ knn) {
    __shared__ int hist[4][260];                   // 4.16 KB
    __shared__ unsigned long long buf[4][KCAP];    // 16 KB
    int t = threadIdx.x, w = t >> 6, l = t & 63;
    int b = blockIdx.x >> 11;
    int q = (blockIdx.x & 2047) * 4 + w;
    const float4* pb = pts4 + b * N_;
    float4 qp = pb[q];
    for (int i = l; i < 256; i += 64) hist[w][i] = 0;
    int cntw = 0;

    // ---- histogram over first 1024 candidates (self -> bucket 255)
    #pragma unroll 2
    for (int i = 0; i < 16; ++i) {
        int j = l + 64 * i;
        float4 c = pb[j];
        float dot = __fadd_rn(__fadd_rn(__fmul_rn(qp.x, c.x), __fmul_rn(qp.y, c.y)), __fmul_rn(qp.z, c.z));
        float d2 = __fsub_rn(__fadd_rn(qp.w, c.w), __fmul_rn(2.f, dot));
        d2 = (j == q) ? 1e30f : d2;
        unsigned uu = __float_as_uint(d2);
        int bk = (d2 < 0.f) ? 0 : min(255, max(0, (int)(uu >> 21) - 400));
        atomicAdd(&hist[w][bk], 1);
    }
    // wave scan -> first bucket B0 with tile-0 cumcount >= 16 -> float Tf
    float Tf;
    {
        int h0 = hist[w][4 * l], h1 = hist[w][4 * l + 1], h2 = hist[w][4 * l + 2], h3 = hist[w][4 * l + 3];
        int c0 = h0, c1 = c0 + h1, c2 = c1 + h2, c3 = c2 + h3;
        int tot = c3;
        int inc = tot;
        for (int off = 1; off < 64; off <<= 1) {
            int vv = __shfl_up(inc, off);
            if (l >= off) inc += vv;
        }
        int excl = inc - tot;
        int Bc = 255;
        if      (excl + c0 >= 16) Bc = 4 * l;
        else if (excl + c1 >= 16) Bc = 4 * l + 1;
        else if (excl + c2 >= 16) Bc = 4 * l + 2;
        else if (excl + c3 >= 16) Bc = 4 * l + 3;
        for (int m = 1; m < 64; m <<= 1) Bc = min(Bc, __shfl_xor(Bc, m));
        Tf = __uint_as_float((unsigned)(Bc + 401) << 21);
    }

    // ---- single filter pass over ALL 8192 candidates (incl. self, d2=0)
    #pragma unroll 4
    for (int i = 0; i < 128; ++i) {
        int j = l + 64 * i;
        float4 c = pb[j];
        float dot = __fadd_rn(__fadd_rn(__fmul_rn(qp.x, c.x), __fmul_rn(qp.y, c.y)), __fmul_rn(qp.z, c.z));
        float d2 = __fsub_rn(__fadd_rn(qp.w, c.w), __fmul_rn(2.f, dot));
        bool take = (d2 < Tf);
        unsigned long long mask = __ballot(take);
        if (take) {
            unsigned du = __float_as_uint(d2);
            unsigned mu = du ^ (unsigned)(((int)du >> 31) | 0x80000000);
            int pos = cntw + __popcll(mask & ((1ull << l) - 1ull));
            if (pos < KCAP) buf[w][pos] = ((unsigned long long)mu << 32) | (unsigned)j;
        }
        cntw += __popcll(mask);
    }
    int m_ = min(cntw, KCAP);

    unsigned long long key[8];
    #pragma unroll
    for (int r = 0; r < 8; ++r) {
        int e = l + 64 * r;
        key[r] = (e < m_) ? buf[w][e] : ~0ull;
    }
    // 17 rounds of wave-min extraction; skip the self entry (idx == q)
    int emitted = 0;
    for (int r17 = 0; r17 < 17 && emitted < 16; ++r17) {
        unsigned long long mn = key[0];
        #pragma unroll
        for (int r = 1; r < 8; ++r) mn = (key[r] < mn) ? key[r] : mn;
        unsigned long long wv = mn;
        for (int m = 1; m < 64; m <<= 1) {
            unsigned long long o = __shfl_xor(wv, m);
            wv = (o < wv) ? o : wv;
        }
        int idx = (int)(wv & 0xffffffffu);
        if (idx != q) {
            if (l == 0) knn[((size_t)b * N_ + q) * 16 + emitted] = b * N_ + idx;
            ++emitted;
        }
        #pragma unroll
        for (int r = 0; r < 8; ++r) if (key[r] == wv) key[r] = ~0ull;
    }
}

// ---- Kernel U: uv = pf @ WuvT^T + bias_cat (A in LDS, B direct-global) ----
__global__ __launch_bounds__(256) void k_uv(
    const float* __restrict__ pf, const unsigned short* __restrict__ WuvT,
    const float* __restrict__ bias_cat,
    float* __restrict__ u, float* __restrict__ v) {
    __shared__ __align__(16) unsigned short As[128 * 136];
    int t = threadIdx.x;
    int l = t & 63, w = t >> 6;
    int wr = w >> 1, wcn = w & 1;
    int rowbase = blockIdx.x * 128;
    int ncol0 = blockIdx.y * 128;

    #pragma unroll
    for (int i = 0; i < 8; ++i) {
        int ci = t + 256 * i;
        int r = ci >> 4, c8 = (ci & 15) * 8;
        const float4* sp = (const float4*)(pf + (size_t)(rowbase + r) * 128 + c8);
        *(uint4*)&As[r * 136 + c8] = pack8(sp[0], sp[1]);
    }
    __syncthreads();

    f32x4 acc[4][4];
    #pragma unroll
    for (int i = 0; i < 4; ++i)
        #pragma unroll
        for (int j = 0; j < 4; ++j) acc[i][j] = (f32x4){0.f, 0.f, 0.f, 0.f};

    #pragma unroll
    for (int ks = 0; ks < 4; ++ks) {
        bf16x8 bfr[4], afr[4];
        #pragma unroll
        for (int nj = 0; nj < 4; ++nj)
            bfr[nj] = ldb8(&WuvT[(size_t)(ncol0 + wcn * 64 + nj * 16 + (l & 15)) * 128 + ks * 32 + (l >> 4) * 8]);
        #pragma unroll
        for (int mi = 0; mi < 4; ++mi)
            afr[mi] = ldb8(&As[(wr * 64 + mi * 16 + (l & 15)) * 136 + ks * 32 + (l >> 4) * 8]);
        #pragma unroll
        for (int mi = 0; mi < 4; ++mi)
            #pragma unroll
            for (int nj = 0; nj < 4; ++nj)
                acc[mi][nj] = __builtin_amdgcn_mfma_f32_16x16x32_bf16(afr[mi], bfr[nj], acc[mi][nj], 0, 0, 0);
    }
    float* outp = (ncol0 == 0) ? u : v;
    #pragma unroll
    for (int mi = 0; mi < 4; ++mi)
        #pragma unroll
        for (int nj = 0; nj < 4; ++nj) {
            int col = wcn * 64 + nj * 16 + (l & 15);
            float bias = bias_cat[ncol0 + col];
            #pragma unroll
            for (int rg = 0; rg < 4; ++rg) {
                int row = wr * 64 + mi * 16 + (l >> 4) * 4 + rg;
                outp[(size_t)(rowbase + row) * 128 + col] = acc[mi][nj][rg] + bias;
            }
        }
}

// ---------------- Kernel C: edge layer2 GEMM + max over K ------------------
__global__ __launch_bounds__(256) void k_edge(
    const float* __restrict__ u, const float* __restrict__ v,
    const int* __restrict__ knn, const unsigned short* __restrict__ Wl2T,
    const float* __restrict__ bl2, float* __restrict__ lf) {
    __shared__ __align__(16) unsigned short h1s[128 * 136];  // 34816 B
    int t = threadIdx.x;
    int l = t & 63, w = t >> 6;
    int wr = w >> 1, wcn = w & 1;
    int rowbase = blockIdx.x * 128;
    int p0 = blockIdx.x * 8;

    #pragma unroll 2
    for (int i = 0; i < 8; ++i) {
        int ci = t + 256 * i;
        int r = ci >> 4, c8 = (ci & 15) * 8;
        int nb = knn[rowbase + r];
        int pt = p0 + (r >> 4);
        const float4* vp = (const float4*)(v + (size_t)nb * 128 + c8);
        const float4* up = (const float4*)(u + (size_t)pt * 128 + c8);
        float4 va = vp[0], vb = vp[1];
        float4 ua = up[0], ub = up[1];
        unsigned d0 = (unsigned)f2b(fmaxf(ua.x + va.x, 0.f)) | ((unsigned)f2b(fmaxf(ua.y + va.y, 0.f)) << 16);
        unsigned d1 = (unsigned)f2b(fmaxf(ua.z + va.z, 0.f)) | ((unsigned)f2b(fmaxf(ua.w + va.w, 0.f)) << 16);
        unsigned d2 = (unsigned)f2b(fmaxf(ub.x + vb.x, 0.f)) | ((unsigned)f2b(fmaxf(ub.y + vb.y, 0.f)) << 16);
        unsigned d3 = (unsigned)f2b(fmaxf(ub.z + vb.z, 0.f)) | ((unsigned)f2b(fmaxf(ub.w + vb.w, 0.f)) << 16);
        uint4 pk; pk.x = d0; pk.y = d1; pk.z = d2; pk.w = d3;
        *(uint4*)&h1s[r * 136 + c8] = pk;
    }
    __syncthreads();

    f32x4 acc[4][4];
    #pragma unroll
    for (int i = 0; i < 4; ++i)
        #pragma unroll
        for (int j = 0; j < 4; ++j) acc[i][j] = (f32x4){0.f, 0.f, 0.f, 0.f};

    #pragma unroll
    for (int ks = 0; ks < 4; ++ks) {
        bf16x8 bfr[4], afr[4];
        #pragma unroll
        for (int nj = 0; nj < 4; ++nj)
            bfr[nj] = ldb8(&Wl2T[(size_t)(wcn * 64 + nj * 16 + (l & 15)) * 128 + ks * 32 + (l >> 4) * 8]);
        #pragma unroll
        for (int mi = 0; mi < 4; ++mi)
            afr[mi] = ldb8(&h1s[(wr * 64 + mi * 16 + (l & 15)) * 136 + ks * 32 + (l >> 4) * 8]);
        #pragma unroll
        for (int mi = 0; mi < 4; ++mi)
            #pragma unroll
            for (int nj = 0; nj < 4; ++nj)
                acc[mi][nj] = __builtin_amdgcn_mfma_f32_16x16x32_bf16(afr[mi], bfr[nj], acc[mi][nj], 0, 0, 0);
    }

    #pragma unroll
    for (int mi = 0; mi < 4; ++mi)
        #pragma unroll
        for (int nj = 0; nj < 4; ++nj) {
            int col = wcn * 64 + nj * 16 + (l & 15);
            float bias = bl2[col];
            float m = fmaxf(acc[mi][nj][0] + bias, 0.f);
            m = fmaxf(m, fmaxf(acc[mi][nj][1] + bias, 0.f));
            m = fmaxf(m, fmaxf(acc[mi][nj][2] + bias, 0.f));
            m = fmaxf(m, fmaxf(acc[mi][nj][3] + bias, 0.f));
            m = fmaxf(m, __shfl_xor(m, 16));
            m = fmaxf(m, __shfl_xor(m, 32));
            if (l < 16) lf[(size_t)(p0 + wr * 4 + mi) * 128 + col] = m;
        }
}

// -- Kernel D: ctx col-max fused in-register; gf via atomicMax (no cs LDS) --
__global__ __launch_bounds__(256) void k_ctx(
    const float* __restrict__ pf, const float* __restrict__ lf,
    const unsigned short* __restrict__ WcT, const float* __restrict__ bc,
    float* __restrict__ gf) {
    __shared__ __align__(16) unsigned short As[128 * 136];
    int t = threadIdx.x;
    int l = t & 63, w = t >> 6;
    int wr = w >> 1, wcn = w & 1;
    int rowbase = blockIdx.x * 128;
    int ncol0 = blockIdx.y * 128;
    int b = rowbase >> 13;

    f32x4 acc[4][4];
    #pragma unroll
    for (int i = 0; i < 4; ++i)
        #pragma unroll
        for (int j = 0; j < 4; ++j) acc[i][j] = (f32x4){0.f, 0.f, 0.f, 0.f};

    for (int kb = 0; kb < 2; ++kb) {
        const float* src = kb ? lf : pf;
        #pragma unroll
        for (int i = 0; i < 8; ++i) {
            int ci = t + 256 * i;
            int r = ci >> 4, c8 = (ci & 15) * 8;
            const float4* sp = (const float4*)(src + (size_t)(rowbase + r) * 128 + c8);
            *(uint4*)&As[r * 136 + c8] = pack8(sp[0], sp[1]);
        }
        __syncthreads();
        #pragma unroll
        for (int ks = 0; ks < 4; ++ks) {
            bf16x8 bfr[4], afr[4];
            #pragma unroll
            for (int nj = 0; nj < 4; ++nj)
                bfr[nj] = ldb8(&WcT[(size_t)(ncol0 + wcn * 64 + nj * 16 + (l & 15)) * 256 + kb * 128 + ks * 32 + (l >> 4) * 8]);
            #pragma unroll
            for (int mi = 0; mi < 4; ++mi)
                afr[mi] = ldb8(&As[(wr * 64 + mi * 16 + (l & 15)) * 136 + ks * 32 + (l >> 4) * 8]);
            #pragma unroll
            for (int mi = 0; mi < 4; ++mi)
                #pragma unroll
                for (int nj = 0; nj < 4; ++nj)
                    acc[mi][nj] = __builtin_amdgcn_mfma_f32_16x16x32_bf16(afr[mi], bfr[nj], acc[mi][nj], 0, 0, 0);
        }
        __syncthreads();
    }
    #pragma unroll
    for (int nj = 0; nj < 4; ++nj) {
        int col = ncol0 + wcn * 64 + nj * 16 + (l & 15);
        float m = acc[0][nj][0];
        #pragma unroll
        for (int mi = 0; mi < 4; ++mi)
            #pragma unroll
            for (int rg = 0; rg < 4; ++rg) m = fmaxf(m, acc[mi][nj][rg]);
        m = fmaxf(m + bc[col], 0.f);
        m = fmaxf(m, __shfl_xor(m, 16));
        m = fmaxf(m, __shfl_xor(m, 32));
        if (l < 16) atomicMax((unsigned int*)&gf[b * 256 + col], __float_as_uint(m));
    }
}

// ---------------- Kernel E: heads (vectorized staging, global-B) -----------
__global__ __launch_bounds__(256) void k_head(
    const float* __restrict__ pf, const float* __restrict__ lf, const float* __restrict__ gf,
    const unsigned short* __restrict__ Wk1T, const float* __restrict__ bk1,
    const float* __restrict__ Wk2, const float* __restrict__ bk2,
    const unsigned short* __restrict__ Wp1T, const float* __restrict__ bp1,
    const float* __restrict__ Wp2, const float* __restrict__ bp2,
    float* __restrict__ out) {
    __shared__ __align__(16) char smem[67584];
    unsigned short* As = (unsigned short*)smem;  // [128][136] bf16
    float* hs = (float*)smem;                    // [128][132] f32 (reuse)
    int t = threadIdx.x;
    int l = t & 63, w = t >> 6;
    int wr = w >> 1, wcn = w & 1;
    int rowbase = blockIdx.x * 128;
    int b = rowbase >> 13;
    int br = blockIdx.y;
    const unsigned short* W1T = br ? Wp1T : Wk1T;
    const float* b1 = br ? bp1 : bk1;
    const float* W2 = br ? Wp2 : Wk2;
    const float* b2p = br ? bp2 : bk2;
    int OC = br ? 8 : 10;
    float* obase = out + (br ? (size_t)NP * 10 : 0);

    f32x4 acc[4][4];
    #pragma unroll
    for (int i = 0; i < 4; ++i)
        #pragma unroll
        for (int j = 0; j < 4; ++j) acc[i][j] = (f32x4){0.f, 0.f, 0.f, 0.f};

    for (int kb = 0; kb < 4; ++kb) {
        #pragma unroll
        for (int i = 0; i < 8; ++i) {
            int ci = t + 256 * i;
            int r = ci >> 4, c8 = (ci & 15) * 8;
            const float4* sp;
            if (kb == 0)      sp = (const float4*)(pf + (size_t)(rowbase + r) * 128 + c8);
            else if (kb == 1) sp = (const float4*)(lf + (size_t)(rowbase + r) * 128 + c8);
            else              sp = (const float4*)(gf + b * 256 + (kb - 2) * 128 + c8);
            *(uint4*)&As[r * 136 + c8] = pack8(sp[0], sp[1]);
        }
        __syncthreads();
        #pragma unroll
        for (int ks = 0; ks < 4; ++ks) {
            bf16x8 bfr[4], afr[4];
            #pragma unroll
            for (int nj = 0; nj < 4; ++nj)
                bfr[nj] = ldb8(&W1T[(size_t)(wcn * 64 + nj * 16 + (l & 15)) * 512 + kb * 128 + ks * 32 + (l >> 4) * 8]);
            #pragma unroll
            for (int mi = 0; mi < 4; ++mi)
                afr[mi] = ldb8(&As[(wr * 64 + mi * 16 + (l & 15)) * 136 + ks * 32 + (l >> 4) * 8]);
            #pragma unroll
            for (int mi = 0; mi < 4; ++mi)
                #pragma unroll
                for (int nj = 0; nj < 4; ++nj)
                    acc[mi][nj] = __builtin_amdgcn_mfma_f32_16x16x32_bf16(afr[mi], bfr[nj], acc[mi][nj], 0, 0, 0);
        }
        __syncthreads();
    }
    #pragma unroll
    for (int mi = 0; mi < 4; ++mi)
        #pragma unroll
        for (int nj = 0; nj < 4; ++nj)
            #pragma unroll
            for (int rg = 0; rg < 4; ++rg) {
                int row = wr * 64 + mi * 16 + (l >> 4) * 4 + rg;
                int col = wcn * 64 + nj * 16 + (l & 15);
                hs[row * 132 + col] = fmaxf(acc[mi][nj][rg] + b1[col], 0.f);
            }
    __syncthreads();
    for (int o = t; o < 128 * OC; o += 256) {
        int r = o / OC, c = o % OC;
        float a = b2p[c];
        for (int k2 = 0; k2 < 128; ++k2) a += hs[r * 132 + k2] * W2[k2 * OC + c];
        obase[(size_t)(rowbase + r) * OC + c] = a;
    }
}

extern "C" void kernel_launch(void* const* d_in, const int* in_sizes, int n_in,
                              void* d_out, int out_size, void* d_ws, size_t ws_size,
                              hipStream_t stream) {
    const float* pts = (const float*)d_in[0];
    const float* nrm = (const float*)d_in[1];
    const float* We1 = (const float*)d_in[2];
    const float* be1 = (const float*)d_in[3];
    const float* We2 = (const float*)d_in[4];
    const float* be2 = (const float*)d_in[5];
    const float* Wl1 = (const float*)d_in[6];
    const float* bl1 = (const float*)d_in[7];
    const float* Wl2 = (const float*)d_in[8];
    const float* bl2 = (const float*)d_in[9];
    const float* Wc  = (const float*)d_in[10];
    const float* bc  = (const float*)d_in[11];
    const float* Wk1 = (const float*)d_in[12];
    const float* bk1 = (const float*)d_in[13];
    const float* Wk2 = (const float*)d_in[14];
    const float* bk2 = (const float*)d_in[15];
    const float* Wp1 = (const float*)d_in[16];
    const float* bp1 = (const float*)d_in[17];
    const float* Wp2 = (const float*)d_in[18];
    const float* bp2 = (const float*)d_in[19];
    float* out = (float*)d_out;

    char* ws = (char*)d_ws;
    size_t off = 0;
    float* pf = (float*)(ws + off);       off += (size_t)NP * 128 * 4;   // 8.39 MB
    float* lf = (float*)(ws + off);       off += (size_t)NP * 128 * 4;   // 8.39 MB
    float* u  = (float*)(ws + off);       off += (size_t)NP * 128 * 4;   // 8.39 MB
    float* v  = (float*)(ws + off);       off += (size_t)NP * 128 * 4;   // 8.39 MB
    int* knn  = (int*)(ws + off);         off += (size_t)NP * 16 * 4;    // 1.05 MB
    float* gf = (float*)(ws + off);       off += 2048;
    float4* pts4 = (float4*)(ws + off);   off += (size_t)NP * 16;        // 256 KB
    float* bias_cat = (float*)(ws + off); off += 1024;
    unsigned short* WuvT = (unsigned short*)(ws + off); off += 256 * 128 * 2;
    unsigned short* Wl2T = (unsigned short*)(ws + off); off += 128 * 128 * 2;
    unsigned short* WcT  = (unsigned short*)(ws + off); off += 256 * 256 * 2;
    unsigned short* Wk1T = (unsigned short*)(ws + off); off += 128 * 512 * 2;
    unsigned short* Wp1T = (unsigned short*)(ws + off); off += 128 * 512 * 2;

    hipLaunchKernelGGL(k_pf, dim3(256), dim3(256), 0, stream,
                       pts, nrm, We1, be1, We2, be2, pf, gf, pts4);
    hipLaunchKernelGGL(k_prep, dim3(64), dim3(256), 0, stream,
                       Wl1, bl1, Wl2, Wc, Wk1, Wp1,
                       WuvT, bias_cat, Wl2T, WcT, Wk1T, Wp1T);
    hipLaunchKernelGGL(k_knn, dim3(4096), dim3(256), 0, stream, pts4, knn);
    hipLaunchKernelGGL(k_uv, dim3(128, 2), dim3(256), 0, stream,
                       pf, WuvT, bias_cat, u, v);
    hipLaunchKernelGGL(k_edge, dim3(2048), dim3(256), 0, stream,
                       u, v, knn, Wl2T, bl2, lf);
    hipLaunchKernelGGL(k_ctx, dim3(128, 2), dim3(256), 0, stream,
                       pf, lf, WcT, bc, gf);
    hipLaunchKernelGGL(k_head, dim3(128, 2), dim3(256), 0, stream,
                       pf, lf, gf, Wk1T, bk1, Wk2, bk2, Wp1T, bp1, Wp2, bp2, out);
}

// Round 11
// 358.034 us; speedup vs baseline: 3.5874x; 1.0923x over previous
//
#include <hip/hip_runtime.h>

#define B_ 2
#define N_ 8192
#define NP 16384   // B_*N_
#define K_ 16
#define H_ 128
#define KCAP 512

typedef short bf16x8 __attribute__((ext_vector_type(8)));
typedef float f32x4 __attribute__((ext_vector_type(4)));

__device__ inline unsigned short f2b(float f) {
    unsigned u = __builtin_bit_cast(unsigned, f);
    unsigned r = (u + 0x7fff + ((u >> 16) & 1)) >> 16;
    return (unsigned short)r;
}
__device__ inline bf16x8 ldb8(const unsigned short* p) {
    return *(const bf16x8*)p;
}
__device__ inline uint4 pack8(float4 a, float4 b) {
    uint4 pk;
    pk.x = (unsigned)f2b(a.x) | ((unsigned)f2b(a.y) << 16);
    pk.y = (unsigned)f2b(a.z) | ((unsigned)f2b(a.w) << 16);
    pk.z = (unsigned)f2b(b.x) | ((unsigned)f2b(b.y) << 16);
    pk.w = (unsigned)f2b(b.z) | ((unsigned)f2b(b.w) << 16);
    return pk;
}

// ---- Kernel H: h1 = relu(x@We1+be1) bf16; pack pts4; zero gf --------------
__global__ __launch_bounds__(256) void k_h1(
    const float* __restrict__ pts, const float* __restrict__ nrm,
    const float* __restrict__ We1, const float* __restrict__ be1,
    unsigned short* __restrict__ h1, float* __restrict__ gf,
    float4* __restrict__ pts4) {
    int tid = blockIdx.x * 256 + threadIdx.x;
    if (blockIdx.x == 0) { gf[threadIdx.x] = 0.f; gf[256 + threadIdx.x] = 0.f; }
    if (tid < NP) {
        int p = tid;
        float x = pts[p * 3], y = pts[p * 3 + 1], z = pts[p * 3 + 2];
        float sq = __fadd_rn(__fadd_rn(__fmul_rn(x, x), __fmul_rn(y, y)), __fmul_rn(z, z));
        pts4[p] = make_float4(x, y, z, sq);
    }
    for (int o = tid; o < NP * 128; o += gridDim.x * 256) {
        int p = o >> 7, h = o & 127;
        float a = be1[h];
        a += pts[p * 3]     * We1[0 * 128 + h];
        a += pts[p * 3 + 1] * We1[1 * 128 + h];
        a += pts[p * 3 + 2] * We1[2 * 128 + h];
        a += nrm[p * 3]     * We1[3 * 128 + h];
        a += nrm[p * 3 + 1] * We1[4 * 128 + h];
        a += nrm[p * 3 + 2] * We1[5 * 128 + h];
        h1[o] = f2b(fmaxf(a, 0.f));
    }
}

// ---------------- Kernel P: prep factored + transposed bf16 weights --------
__global__ __launch_bounds__(256) void k_prep(
    const float* __restrict__ Wl1, const float* __restrict__ bl1,
    const float* __restrict__ Wl2, const float* __restrict__ Wc,
    const float* __restrict__ Wk1, const float* __restrict__ Wp1,
    const float* __restrict__ We2,
    unsigned short* __restrict__ WuvT, float* __restrict__ bias_cat,
    unsigned short* __restrict__ Wl2T, unsigned short* __restrict__ WcT,
    unsigned short* __restrict__ Wk1T, unsigned short* __restrict__ Wp1T,
    unsigned short* __restrict__ We2T) {
    int tid = blockIdx.x * 256 + threadIdx.x;
    int stride = gridDim.x * 256;
    for (int i = tid; i < 256 * 128; i += stride) {
        int n = i >> 7, k = i & 127;
        float val = (n < 128) ? Wl1[k * 128 + n] - Wl1[(k + 128) * 128 + n]
                              : Wl1[(k + 128) * 128 + (n - 128)];
        WuvT[i] = f2b(val);
    }
    for (int i = tid; i < 256; i += stride) bias_cat[i] = (i < 128) ? bl1[i] : 0.f;
    for (int i = tid; i < 128 * 128; i += stride) {
        int n = i >> 7, k = i & 127;
        Wl2T[i] = f2b(Wl2[k * 128 + n]);
        We2T[i] = f2b(We2[k * 128 + n]);
    }
    for (int i = tid; i < 256 * 256; i += stride) {
        int n = i >> 8, k = i & 255;
        WcT[i] = f2b(Wc[k * 256 + n]);
    }
    for (int i = tid; i < 128 * 512; i += stride) {
        int n = i >> 9, k = i & 511;
        Wk1T[i] = f2b(Wk1[k * 128 + n]);
        Wp1T[i] = f2b(Wp1[k * 128 + n]);
    }
}

// ---- Kernel PF2: pf = relu(h1 @ We2T^T + be2), A/B direct-global, no LDS --
__global__ __launch_bounds__(256) void k_pf2(
    const unsigned short* __restrict__ h1, const unsigned short* __restrict__ We2T,
    const float* __restrict__ be2, float* __restrict__ pf) {
    int t = threadIdx.x, l = t & 63, w = t >> 6;
    int row0 = blockIdx.x * 64 + w * 16;
    f32x4 acc[8];
    #pragma unroll
    for (int nj = 0; nj < 8; ++nj) acc[nj] = (f32x4){0.f, 0.f, 0.f, 0.f};
    #pragma unroll
    for (int ks = 0; ks < 4; ++ks) {
        bf16x8 a = ldb8(&h1[(size_t)(row0 + (l & 15)) * 128 + ks * 32 + (l >> 4) * 8]);
        #pragma unroll
        for (int nj = 0; nj < 8; ++nj) {
            bf16x8 bfr = ldb8(&We2T[(size_t)(nj * 16 + (l & 15)) * 128 + ks * 32 + (l >> 4) * 8]);
            acc[nj] = __builtin_amdgcn_mfma_f32_16x16x32_bf16(a, bfr, acc[nj], 0, 0, 0);
        }
    }
    #pragma unroll
    for (int nj = 0; nj < 8; ++nj) {
        int col = nj * 16 + (l & 15);
        float bias = be2[col];
        #pragma unroll
        for (int rg = 0; rg < 4; ++rg) {
            int row = row0 + (l >> 4) * 4 + rg;
            pf[(size_t)row * 128 + col] = fmaxf(acc[nj][rg] + bias, 0.f);
        }
    }
}

// ---- scan helper: first bucket with cumcount >= 16 -> float threshold -----
__device__ inline float knn_thresh(const int* __restrict__ hh, int l) {
    int h0 = hh[4 * l], h1 = hh[4 * l + 1], h2 = hh[4 * l + 2], h3 = hh[4 * l + 3];
    int c0 = h0, c1 = c0 + h1, c2 = c1 + h2, c3 = c2 + h3;
    int tot = c3;
    int inc = tot;
    for (int off = 1; off < 64; off <<= 1) {
        int vv = __shfl_up(inc, off);
        if (l >= off) inc += vv;
    }
    int excl = inc - tot;
    int Bc = 255;
    if      (excl + c0 >= 16) Bc = 4 * l;
    else if (excl + c1 >= 16) Bc = 4 * l + 1;
    else if (excl + c2 >= 16) Bc = 4 * l + 2;
    else if (excl + c3 >= 16) Bc = 4 * l + 3;
    for (int m = 1; m < 64; m <<= 1) Bc = min(Bc, __shfl_xor(Bc, m));
    return __uint_as_float((unsigned)(Bc + 401) << 21);
}

// ------- Kernel B: 16-NN, 2 queries/wave (shared candidate loads),
//         u32 index-only survivor buffers, exact d2 recompute at extraction -
__global__ __launch_bounds__(256) void k_knn(
    const float4* __restrict__ pts4, int* __restrict__ knn) {
    __shared__ int hist[4][2][260];            // 8320 B
    __shared__ unsigned buf[4][2][KCAP];       // 16384 B
    int t = threadIdx.x, w = t >> 6, l = t & 63;
    int b = blockIdx.x >> 10;                  // 1024 blocks per batch
    int qbase = (blockIdx.x & 1023) * 8 + w * 2;
    const float4* pb = pts4 + b * N_;
    float4 qp0 = pb[qbase];
    float4 qp1 = pb[qbase + 1];
    for (int i = l; i < 520; i += 64) (&hist[w][0][0])[i] = 0;
    int cnt0 = 0, cnt1 = 0;

    // phase 1: tile-0 histogram for both queries; cache raw d2 in regs
    float d2c0[16], d2c1[16];
    #pragma unroll
    for (int i = 0; i < 16; ++i) {
        int j = l + 64 * i;
        float4 c = pb[j];
        float dot0 = __fadd_rn(__fadd_rn(__fmul_rn(qp0.x, c.x), __fmul_rn(qp0.y, c.y)), __fmul_rn(qp0.z, c.z));
        float d20 = __fsub_rn(__fadd_rn(qp0.w, c.w), __fmul_rn(2.f, dot0));
        float dot1 = __fadd_rn(__fadd_rn(__fmul_rn(qp1.x, c.x), __fmul_rn(qp1.y, c.y)), __fmul_rn(qp1.z, c.z));
        float d21 = __fsub_rn(__fadd_rn(qp1.w, c.w), __fmul_rn(2.f, dot1));
        d2c0[i] = d20; d2c1[i] = d21;
        float hv0 = (j == qbase) ? 1e30f : d20;
        float hv1 = (j == qbase + 1) ? 1e30f : d21;
        unsigned u0 = __float_as_uint(hv0);
        int bk0 = (hv0 < 0.f) ? 0 : min(255, max(0, (int)(u0 >> 21) - 400));
        atomicAdd(&hist[w][0][bk0], 1);
        unsigned u1 = __float_as_uint(hv1);
        int bk1 = (hv1 < 0.f) ? 0 : min(255, max(0, (int)(u1 >> 21) - 400));
        atomicAdd(&hist[w][1][bk1], 1);
    }
    float Tf0 = knn_thresh(&hist[w][0][0], l);
    float Tf1 = knn_thresh(&hist[w][1][0], l);

    // phase 3a: filter tile-0 from cached regs (no reload)
    #pragma unroll
    for (int i = 0; i < 16; ++i) {
        int j = l + 64 * i;
        bool t0 = d2c0[i] < Tf0;
        unsigned long long m0 = __ballot(t0);
        if (t0) {
            int pos = cnt0 + __popcll(m0 & ((1ull << l) - 1ull));
            if (pos < KCAP) buf[w][0][pos] = (unsigned)j;
        }
        cnt0 += __popcll(m0);
        bool t1 = d2c1[i] < Tf1;
        unsigned long long m1 = __ballot(t1);
        if (t1) {
            int pos = cnt1 + __popcll(m1 & ((1ull << l) - 1ull));
            if (pos < KCAP) buf[w][1][pos] = (unsigned)j;
        }
        cnt1 += __popcll(m1);
    }

    // phase 3b: tiles 1..7 — one load serves both queries
    #pragma unroll 2
    for (int i = 16; i < 128; ++i) {
        int j = l + 64 * i;
        float4 c = pb[j];
        float dot0 = __fadd_rn(__fadd_rn(__fmul_rn(qp0.x, c.x), __fmul_rn(qp0.y, c.y)), __fmul_rn(qp0.z, c.z));
        float d20 = __fsub_rn(__fadd_rn(qp0.w, c.w), __fmul_rn(2.f, dot0));
        float dot1 = __fadd_rn(__fadd_rn(__fmul_rn(qp1.x, c.x), __fmul_rn(qp1.y, c.y)), __fmul_rn(qp1.z, c.z));
        float d21 = __fsub_rn(__fadd_rn(qp1.w, c.w), __fmul_rn(2.f, dot1));
        bool t0 = d20 < Tf0;
        unsigned long long m0 = __ballot(t0);
        if (t0) {
            int pos = cnt0 + __popcll(m0 & ((1ull << l) - 1ull));
            if (pos < KCAP) buf[w][0][pos] = (unsigned)j;
        }
        cnt0 += __popcll(m0);
        bool t1 = d21 < Tf1;
        unsigned long long m1 = __ballot(t1);
        if (t1) {
            int pos = cnt1 + __popcll(m1 & ((1ull << l) - 1ull));
            if (pos < KCAP) buf[w][1][pos] = (unsigned)j;
        }
        cnt1 += __popcll(m1);
    }

    // extraction per query: rebuild u64 keys (exact d2 recompute), 17 rounds
    for (int qq = 0; qq < 2; ++qq) {
        int q = qbase + qq;
        float4 qp = qq ? qp1 : qp0;
        int m_ = min(qq ? cnt1 : cnt0, KCAP);
        unsigned long long key[8];
        #pragma unroll
        for (int r = 0; r < 8; ++r) {
            int e = l + 64 * r;
            if (e < m_) {
                int idx = (int)buf[w][qq][e];
                float4 c = pb[idx];
                float dot = __fadd_rn(__fadd_rn(__fmul_rn(qp.x, c.x), __fmul_rn(qp.y, c.y)), __fmul_rn(qp.z, c.z));
                float d2 = __fsub_rn(__fadd_rn(qp.w, c.w), __fmul_rn(2.f, dot));
                unsigned du = __float_as_uint(d2);
                unsigned mu = du ^ (unsigned)(((int)du >> 31) | 0x80000000);
                key[r] = ((unsigned long long)mu << 32) | (unsigned)idx;
            } else key[r] = ~0ull;
        }
        unsigned long long lmin = key[0];
        #pragma unroll
        for (int r = 1; r < 8; ++r) lmin = (key[r] < lmin) ? key[r] : lmin;
        int emitted = 0;
        for (int r17 = 0; r17 < 17 && emitted < 16; ++r17) {
            unsigned long long wv = lmin;
            for (int m = 1; m < 64; m <<= 1) {
                unsigned long long o = __shfl_xor(wv, m);
                wv = (o < wv) ? o : wv;
            }
            int idx = (int)(wv & 0xffffffffu);
            if (idx != q) {
                if (l == 0) knn[((size_t)b * N_ + q) * 16 + emitted] = b * N_ + idx;
                ++emitted;
            }
            if (lmin == wv) {
                #pragma unroll
                for (int r = 0; r < 8; ++r) if (key[r] == wv) key[r] = ~0ull;
                lmin = key[0];
                #pragma unroll
                for (int r = 1; r < 8; ++r) lmin = (key[r] < lmin) ? key[r] : lmin;
            }
        }
    }
}

// ---- Kernel U: uv = pf @ WuvT^T + bias_cat (A in LDS, B direct-global) ----
__global__ __launch_bounds__(256) void k_uv(
    const float* __restrict__ pf, const unsigned short* __restrict__ WuvT,
    const float* __restrict__ bias_cat,
    float* __restrict__ u, float* __restrict__ v) {
    __shared__ __align__(16) unsigned short As[128 * 136];
    int t = threadIdx.x;
    int l = t & 63, w = t >> 6;
    int wr = w >> 1, wcn = w & 1;
    int rowbase = blockIdx.x * 128;
    int ncol0 = blockIdx.y * 128;

    #pragma unroll
    for (int i = 0; i < 8; ++i) {
        int ci = t + 256 * i;
        int r = ci >> 4, c8 = (ci & 15) * 8;
        const float4* sp = (const float4*)(pf + (size_t)(rowbase + r) * 128 + c8);
        *(uint4*)&As[r * 136 + c8] = pack8(sp[0], sp[1]);
    }
    __syncthreads();

    f32x4 acc[4][4];
    #pragma unroll
    for (int i = 0; i < 4; ++i)
        #pragma unroll
        for (int j = 0; j < 4; ++j) acc[i][j] = (f32x4){0.f, 0.f, 0.f, 0.f};

    #pragma unroll
    for (int ks = 0; ks < 4; ++ks) {
        bf16x8 bfr[4], afr[4];
        #pragma unroll
        for (int nj = 0; nj < 4; ++nj)
            bfr[nj] = ldb8(&WuvT[(size_t)(ncol0 + wcn * 64 + nj * 16 + (l & 15)) * 128 + ks * 32 + (l >> 4) * 8]);
        #pragma unroll
        for (int mi = 0; mi < 4; ++mi)
            afr[mi] = ldb8(&As[(wr * 64 + mi * 16 + (l & 15)) * 136 + ks * 32 + (l >> 4) * 8]);
        #pragma unroll
        for (int mi = 0; mi < 4; ++mi)
            #pragma unroll
            for (int nj = 0; nj < 4; ++nj)
                acc[mi][nj] = __builtin_amdgcn_mfma_f32_16x16x32_bf16(afr[mi], bfr[nj], acc[mi][nj], 0, 0, 0);
    }
    float* outp = (ncol0 == 0) ? u : v;
    #pragma unroll
    for (int mi = 0; mi < 4; ++mi)
        #pragma unroll
        for (int nj = 0; nj < 4; ++nj) {
            int col = wcn * 64 + nj * 16 + (l & 15);
            float bias = bias_cat[ncol0 + col];
            #pragma unroll
            for (int rg = 0; rg < 4; ++rg) {
                int row = wr * 64 + mi * 16 + (l >> 4) * 4 + rg;
                outp[(size_t)(rowbase + row) * 128 + col] = acc[mi][nj][rg] + bias;
            }
        }
}

// ---------------- Kernel C: edge layer2 GEMM + max over K ------------------
__global__ __launch_bounds__(256) void k_edge(
    const float* __restrict__ u, const float* __restrict__ v,
    const int* __restrict__ knn, const unsigned short* __restrict__ Wl2T,
    const float* __restrict__ bl2, float* __restrict__ lf) {
    __shared__ __align__(16) unsigned short h1s[128 * 136];  // 34816 B
    int t = threadIdx.x;
    int l = t & 63, w = t >> 6;
    int wr = w >> 1, wcn = w & 1;
    int rowbase = blockIdx.x * 128;
    int p0 = blockIdx.x * 8;

    #pragma unroll 2
    for (int i = 0; i < 8; ++i) {
        int ci = t + 256 * i;
        int r = ci >> 4, c8 = (ci & 15) * 8;
        int nb = knn[rowbase + r];
        int pt = p0 + (r >> 4);
        const float4* vp = (const float4*)(v + (size_t)nb * 128 + c8);
        const float4* up = (const float4*)(u + (size_t)pt * 128 + c8);
        float4 va = vp[0], vb = vp[1];
        float4 ua = up[0], ub = up[1];
        unsigned d0 = (unsigned)f2b(fmaxf(ua.x + va.x, 0.f)) | ((unsigned)f2b(fmaxf(ua.y + va.y, 0.f)) << 16);
        unsigned d1 = (unsigned)f2b(fmaxf(ua.z + va.z, 0.f)) | ((unsigned)f2b(fmaxf(ua.w + va.w, 0.f)) << 16);
        unsigned d2 = (unsigned)f2b(fmaxf(ub.x + vb.x, 0.f)) | ((unsigned)f2b(fmaxf(ub.y + vb.y, 0.f)) << 16);
        unsigned d3 = (unsigned)f2b(fmaxf(ub.z + vb.z, 0.f)) | ((unsigned)f2b(fmaxf(ub.w + vb.w, 0.f)) << 16);
        uint4 pk; pk.x = d0; pk.y = d1; pk.z = d2; pk.w = d3;
        *(uint4*)&h1s[r * 136 + c8] = pk;
    }
    __syncthreads();

    f32x4 acc[4][4];
    #pragma unroll
    for (int i = 0; i < 4; ++i)
        #pragma unroll
        for (int j = 0; j < 4; ++j) acc[i][j] = (f32x4){0.f, 0.f, 0.f, 0.f};

    #pragma unroll
    for (int ks = 0; ks < 4; ++ks) {
        bf16x8 bfr[4], afr[4];
        #pragma unroll
        for (int nj = 0; nj < 4; ++nj)
            bfr[nj] = ldb8(&Wl2T[(size_t)(wcn * 64 + nj * 16 + (l & 15)) * 128 + ks * 32 + (l >> 4) * 8]);
        #pragma unroll
        for (int mi = 0; mi < 4; ++mi)
            afr[mi] = ldb8(&h1s[(wr * 64 + mi * 16 + (l & 15)) * 136 + ks * 32 + (l >> 4) * 8]);
        #pragma unroll
        for (int mi = 0; mi < 4; ++mi)
            #pragma unroll
            for (int nj = 0; nj < 4; ++nj)
                acc[mi][nj] = __builtin_amdgcn_mfma_f32_16x16x32_bf16(afr[mi], bfr[nj], acc[mi][nj], 0, 0, 0);
    }

    #pragma unroll
    for (int mi = 0; mi < 4; ++mi)
        #pragma unroll
        for (int nj = 0; nj < 4; ++nj) {
            int col = wcn * 64 + nj * 16 + (l & 15);
            float bias = bl2[col];
            float m = fmaxf(acc[mi][nj][0] + bias, 0.f);
            m = fmaxf(m, fmaxf(acc[mi][nj][1] + bias, 0.f));
            m = fmaxf(m, fmaxf(acc[mi][nj][2] + bias, 0.f));
            m = fmaxf(m, fmaxf(acc[mi][nj][3] + bias, 0.f));
            m = fmaxf(m, __shfl_xor(m, 16));
            m = fmaxf(m, __shfl_xor(m, 32));
            if (l < 16) lf[(size_t)(p0 + wr * 4 + mi) * 128 + col] = m;
        }
}

// -- Kernel D: ctx col-max fused in-register; gf via atomicMax (no cs LDS) --
__global__ __launch_bounds__(256) void k_ctx(
    const float* __restrict__ pf, const float* __restrict__ lf,
    const unsigned short* __restrict__ WcT, const float* __restrict__ bc,
    float* __restrict__ gf) {
    __shared__ __align__(16) unsigned short As[128 * 136];
    int t = threadIdx.x;
    int l = t & 63, w = t >> 6;
    int wr = w >> 1, wcn = w & 1;
    int rowbase = blockIdx.x * 128;
    int ncol0 = blockIdx.y * 128;
    int b = rowbase >> 13;

    f32x4 acc[4][4];
    #pragma unroll
    for (int i = 0; i < 4; ++i)
        #pragma unroll
        for (int j = 0; j < 4; ++j) acc[i][j] = (f32x4){0.f, 0.f, 0.f, 0.f};

    for (int kb = 0; kb < 2; ++kb) {
        const float* src = kb ? lf : pf;
        #pragma unroll
        for (int i = 0; i < 8; ++i) {
            int ci = t + 256 * i;
            int r = ci >> 4, c8 = (ci & 15) * 8;
            const float4* sp = (const float4*)(src + (size_t)(rowbase + r) * 128 + c8);
            *(uint4*)&As[r * 136 + c8] = pack8(sp[0], sp[1]);
        }
        __syncthreads();
        #pragma unroll
        for (int ks = 0; ks < 4; ++ks) {
            bf16x8 bfr[4], afr[4];
            #pragma unroll
            for (int nj = 0; nj < 4; ++nj)
                bfr[nj] = ldb8(&WcT[(size_t)(ncol0 + wcn * 64 + nj * 16 + (l & 15)) * 256 + kb * 128 + ks * 32 + (l >> 4) * 8]);
            #pragma unroll
            for (int mi = 0; mi < 4; ++mi)
                afr[mi] = ldb8(&As[(wr * 64 + mi * 16 + (l & 15)) * 136 + ks * 32 + (l >> 4) * 8]);
            #pragma unroll
            for (int mi = 0; mi < 4; ++mi)
                #pragma unroll
                for (int nj = 0; nj < 4; ++nj)
                    acc[mi][nj] = __builtin_amdgcn_mfma_f32_16x16x32_bf16(afr[mi], bfr[nj], acc[mi][nj], 0, 0, 0);
        }
        __syncthreads();
    }
    #pragma unroll
    for (int nj = 0; nj < 4; ++nj) {
        int col = ncol0 + wcn * 64 + nj * 16 + (l & 15);
        float m = acc[0][nj][0];
        #pragma unroll
        for (int mi = 0; mi < 4; ++mi)
            #pragma unroll
            for (int rg = 0; rg < 4; ++rg) m = fmaxf(m, acc[mi][nj][rg]);
        m = fmaxf(m + bc[col], 0.f);
        m = fmaxf(m, __shfl_xor(m, 16));
        m = fmaxf(m, __shfl_xor(m, 32));
        if (l < 16) atomicMax((unsigned int*)&gf[b * 256 + col], __float_as_uint(m));
    }
}

// ---------------- Kernel E: heads (vectorized staging, global-B) -----------
__global__ __launch_bounds__(256) void k_head(
    const float* __restrict__ pf, const float* __restrict__ lf, const float* __restrict__ gf,
    const unsigned short* __restrict__ Wk1T, const float* __restrict__ bk1,
    const float* __restrict__ Wk2, const float* __restrict__ bk2,
    const unsigned short* __restrict__ Wp1T, const float* __restrict__ bp1,
    const float* __restrict__ Wp2, const float* __restrict__ bp2,
    float* __restrict__ out) {
    __shared__ __align__(16) char smem[67584];
    unsigned short* As = (unsigned short*)smem;  // [128][136] bf16
    float* hs = (float*)smem;                    // [128][132] f32 (reuse)
    int t = threadIdx.x;
    int l = t & 63, w = t >> 6;
    int wr = w >> 1, wcn = w & 1;
    int rowbase = blockIdx.x * 128;
    int b = rowbase >> 13;
    int br = blockIdx.y;
    const unsigned short* W1T = br ? Wp1T : Wk1T;
    const float* b1 = br ? bp1 : bk1;
    const float* W2 = br ? Wp2 : Wk2;
    const float* b2p = br ? bp2 : bk2;
    int OC = br ? 8 : 10;
    float* obase = out + (br ? (size_t)NP * 10 : 0);

    f32x4 acc[4][4];
    #pragma unroll
    for (int i = 0; i < 4; ++i)
        #pragma unroll
        for (int j = 0; j < 4; ++j) acc[i][j] = (f32x4){0.f, 0.f, 0.f, 0.f};

    for (int kb = 0; kb < 4; ++kb) {
        #pragma unroll
        for (int i = 0; i < 8; ++i) {
            int ci = t + 256 * i;
            int r = ci >> 4, c8 = (ci & 15) * 8;
            const float4* sp;
            if (kb == 0)      sp = (const float4*)(pf + (size_t)(rowbase + r) * 128 + c8);
            else if (kb == 1) sp = (const float4*)(lf + (size_t)(rowbase + r) * 128 + c8);
            else              sp = (const float4*)(gf + b * 256 + (kb - 2) * 128 + c8);
            *(uint4*)&As[r * 136 + c8] = pack8(sp[0], sp[1]);
        }
        __syncthreads();
        #pragma unroll
        for (int ks = 0; ks < 4; ++ks) {
            bf16x8 bfr[4], afr[4];
            #pragma unroll
            for (int nj = 0; nj < 4; ++nj)
                bfr[nj] = ldb8(&W1T[(size_t)(wcn * 64 + nj * 16 + (l & 15)) * 512 + kb * 128 + ks * 32 + (l >> 4) * 8]);
            #pragma unroll
            for (int mi = 0; mi < 4; ++mi)
                afr[mi] = ldb8(&As[(wr * 64 + mi * 16 + (l & 15)) * 136 + ks * 32 + (l >> 4) * 8]);
            #pragma unroll
            for (int mi = 0; mi < 4; ++mi)
                #pragma unroll
                for (int nj = 0; nj < 4; ++nj)
                    acc[mi][nj] = __builtin_amdgcn_mfma_f32_16x16x32_bf16(afr[mi], bfr[nj], acc[mi][nj], 0, 0, 0);
        }
        __syncthreads();
    }
    #pragma unroll
    for (int mi = 0; mi < 4; ++mi)
        #pragma unroll
        for (int nj = 0; nj < 4; ++nj)
            #pragma unroll
            for (int rg = 0; rg < 4; ++rg) {
                int row = wr * 64 + mi * 16 + (l >> 4) * 4 + rg;
                int col = wcn * 64 + nj * 16 + (l & 15);
                hs[row * 132 + col] = fmaxf(acc[mi][nj][rg] + b1[col], 0.f);
            }
    __syncthreads();
    for (int o = t; o < 128 * OC; o += 256) {
        int r = o / OC, c = o % OC;
        float a = b2p[c];
        for (int k2 = 0; k2 < 128; ++k2) a += hs[r * 132 + k2] * W2[k2 * OC + c];
        obase[(size_t)(rowbase + r) * OC + c] = a;
    }
}

extern "C" void kernel_launch(void* const* d_in, const int* in_sizes, int n_in,
                              void* d_out, int out_size, void* d_ws, size_t ws_size,
                              hipStream_t stream) {
    const float* pts = (const float*)d_in[0];
    const float* nrm = (const float*)d_in[1];
    const float* We1 = (const float*)d_in[2];
    const float* be1 = (const float*)d_in[3];
    const float* We2 = (const float*)d_in[4];
    const float* be2 = (const float*)d_in[5];
    const float* Wl1 = (const float*)d_in[6];
    const float* bl1 = (const float*)d_in[7];
    const float* Wl2 = (const float*)d_in[8];
    const float* bl2 = (const float*)d_in[9];
    const float* Wc  = (const float*)d_in[10];
    const float* bc  = (const float*)d_in[11];
    const float* Wk1 = (const float*)d_in[12];
    const float* bk1 = (const float*)d_in[13];
    const float* Wk2 = (const float*)d_in[14];
    const float* bk2 = (const float*)d_in[15];
    const float* Wp1 = (const float*)d_in[16];
    const float* bp1 = (const float*)d_in[17];
    const float* Wp2 = (const float*)d_in[18];
    const float* bp2 = (const float*)d_in[19];
    float* out = (float*)d_out;

    char* ws = (char*)d_ws;
    size_t off = 0;
    float* pf = (float*)(ws + off);       off += (size_t)NP * 128 * 4;   // 8.39 MB
    float* lf = (float*)(ws + off);       off += (size_t)NP * 128 * 4;   // 8.39 MB
    float* u  = (float*)(ws + off);       off += (size_t)NP * 128 * 4;   // 8.39 MB
    float* v  = (float*)(ws + off);       off += (size_t)NP * 128 * 4;   // 8.39 MB
    int* knn  = (int*)(ws + off);         off += (size_t)NP * 16 * 4;    // 1.05 MB
    float* gf = (float*)(ws + off);       off += 2048;
    float4* pts4 = (float4*)(ws + off);   off += (size_t)NP * 16;        // 256 KB
    float* bias_cat = (float*)(ws + off); off += 1024;
    unsigned short* WuvT = (unsigned short*)(ws + off); off += 256 * 128 * 2;
    unsigned short* Wl2T = (unsigned short*)(ws + off); off += 128 * 128 * 2;
    unsigned short* WcT  = (unsigned short*)(ws + off); off += 256 * 256 * 2;
    unsigned short* Wk1T = (unsigned short*)(ws + off); off += 128 * 512 * 2;
    unsigned short* Wp1T = (unsigned short*)(ws + off); off += 128 * 512 * 2;
    unsigned short* We2T = (unsigned short*)(ws + off); off += 128 * 128 * 2;
    unsigned short* h1   = (unsigned short*)(ws + off); off += (size_t)NP * 128 * 2;  // 4.19 MB

    hipLaunchKernelGGL(k_h1, dim3(2048), dim3(256), 0, stream,
                       pts, nrm, We1, be1, h1, gf, pts4);
    hipLaunchKernelGGL(k_prep, dim3(64), dim3(256), 0, stream,
                       Wl1, bl1, Wl2, Wc, Wk1, Wp1, We2,
                       WuvT, bias_cat, Wl2T, WcT, Wk1T, Wp1T, We2T);
    hipLaunchKernelGGL(k_knn, dim3(2048), dim3(256), 0, stream, pts4, knn);
    hipLaunchKernelGGL(k_pf2, dim3(256), dim3(256), 0, stream,
                       h1, We2T, be2, pf);
    hipLaunchKernelGGL(k_uv, dim3(128, 2), dim3(256), 0, stream,
                       pf, WuvT, bias_cat, u, v);
    hipLaunchKernelGGL(k_edge, dim3(2048), dim3(256), 0, stream,
                       u, v, knn, Wl2T, bl2, lf);
    hipLaunchKernelGGL(k_ctx, dim3(128, 2), dim3(256), 0, stream,
                       pf, lf, WcT, bc, gf);
    hipLaunchKernelGGL(k_head, dim3(128, 2), dim3(256), 0, stream,
                       pf, lf, gf, Wk1T, bk1, Wk2, bk2, Wp1T, bp1, Wp2, bp2, out);
}

// Round 12
// 349.072 us; speedup vs baseline: 3.6795x; 1.0257x over previous
//
#include <hip/hip_runtime.h>

#define B_ 2
#define N_ 8192
#define NP 16384   // B_*N_
#define K_ 16
#define H_ 128
#define KCAP 512

typedef short bf16x8 __attribute__((ext_vector_type(8)));
typedef float f32x4 __attribute__((ext_vector_type(4)));

__device__ inline unsigned short f2b(float f) {
    unsigned u = __builtin_bit_cast(unsigned, f);
    unsigned r = (u + 0x7fff + ((u >> 16) & 1)) >> 16;
    return (unsigned short)r;
}
__device__ inline bf16x8 ldb8(const unsigned short* p) {
    return *(const bf16x8*)p;
}
__device__ inline uint4 pack8(float4 a, float4 b) {
    uint4 pk;
    pk.x = (unsigned)f2b(a.x) | ((unsigned)f2b(a.y) << 16);
    pk.y = (unsigned)f2b(a.z) | ((unsigned)f2b(a.w) << 16);
    pk.z = (unsigned)f2b(b.x) | ((unsigned)f2b(b.y) << 16);
    pk.w = (unsigned)f2b(b.z) | ((unsigned)f2b(b.w) << 16);
    return pk;
}

// ---- Kernel H: h1 = relu(x@We1+be1) bf16; pack pts4; zero gf --------------
__global__ __launch_bounds__(256) void k_h1(
    const float* __restrict__ pts, const float* __restrict__ nrm,
    const float* __restrict__ We1, const float* __restrict__ be1,
    unsigned short* __restrict__ h1, float* __restrict__ gf,
    float4* __restrict__ pts4) {
    int tid = blockIdx.x * 256 + threadIdx.x;
    if (blockIdx.x == 0) { gf[threadIdx.x] = 0.f; gf[256 + threadIdx.x] = 0.f; }
    if (tid < NP) {
        int p = tid;
        float x = pts[p * 3], y = pts[p * 3 + 1], z = pts[p * 3 + 2];
        float sq = __fadd_rn(__fadd_rn(__fmul_rn(x, x), __fmul_rn(y, y)), __fmul_rn(z, z));
        pts4[p] = make_float4(x, y, z, sq);
    }
    for (int o = tid; o < NP * 128; o += gridDim.x * 256) {
        int p = o >> 7, h = o & 127;
        float a = be1[h];
        a += pts[p * 3]     * We1[0 * 128 + h];
        a += pts[p * 3 + 1] * We1[1 * 128 + h];
        a += pts[p * 3 + 2] * We1[2 * 128 + h];
        a += nrm[p * 3]     * We1[3 * 128 + h];
        a += nrm[p * 3 + 1] * We1[4 * 128 + h];
        a += nrm[p * 3 + 2] * We1[5 * 128 + h];
        h1[o] = f2b(fmaxf(a, 0.f));
    }
}

// ---------------- Kernel P: prep factored + transposed bf16 weights --------
__global__ __launch_bounds__(256) void k_prep(
    const float* __restrict__ Wl1, const float* __restrict__ bl1,
    const float* __restrict__ Wl2, const float* __restrict__ Wc,
    const float* __restrict__ Wk1, const float* __restrict__ Wp1,
    const float* __restrict__ We2,
    unsigned short* __restrict__ WuvT, float* __restrict__ bias_cat,
    unsigned short* __restrict__ Wl2T, unsigned short* __restrict__ WcT,
    unsigned short* __restrict__ Wk1T, unsigned short* __restrict__ Wp1T,
    unsigned short* __restrict__ We2T) {
    int tid = blockIdx.x * 256 + threadIdx.x;
    int stride = gridDim.x * 256;
    for (int i = tid; i < 256 * 128; i += stride) {
        int n = i >> 7, k = i & 127;
        float val = (n < 128) ? Wl1[k * 128 + n] - Wl1[(k + 128) * 128 + n]
                              : Wl1[(k + 128) * 128 + (n - 128)];
        WuvT[i] = f2b(val);
    }
    for (int i = tid; i < 256; i += stride) bias_cat[i] = (i < 128) ? bl1[i] : 0.f;
    for (int i = tid; i < 128 * 128; i += stride) {
        int n = i >> 7, k = i & 127;
        Wl2T[i] = f2b(Wl2[k * 128 + n]);
        We2T[i] = f2b(We2[k * 128 + n]);
    }
    for (int i = tid; i < 256 * 256; i += stride) {
        int n = i >> 8, k = i & 255;
        WcT[i] = f2b(Wc[k * 256 + n]);
    }
    for (int i = tid; i < 128 * 512; i += stride) {
        int n = i >> 9, k = i & 511;
        Wk1T[i] = f2b(Wk1[k * 128 + n]);
        Wp1T[i] = f2b(Wp1[k * 128 + n]);
    }
}

// ---- Kernel PF2: pf = relu(h1 @ We2T^T + be2), A/B direct-global, no LDS --
__global__ __launch_bounds__(256) void k_pf2(
    const unsigned short* __restrict__ h1, const unsigned short* __restrict__ We2T,
    const float* __restrict__ be2, float* __restrict__ pf) {
    int t = threadIdx.x, l = t & 63, w = t >> 6;
    int row0 = blockIdx.x * 64 + w * 16;
    f32x4 acc[8];
    #pragma unroll
    for (int nj = 0; nj < 8; ++nj) acc[nj] = (f32x4){0.f, 0.f, 0.f, 0.f};
    #pragma unroll
    for (int ks = 0; ks < 4; ++ks) {
        bf16x8 a = ldb8(&h1[(size_t)(row0 + (l & 15)) * 128 + ks * 32 + (l >> 4) * 8]);
        #pragma unroll
        for (int nj = 0; nj < 8; ++nj) {
            bf16x8 bfr = ldb8(&We2T[(size_t)(nj * 16 + (l & 15)) * 128 + ks * 32 + (l >> 4) * 8]);
            acc[nj] = __builtin_amdgcn_mfma_f32_16x16x32_bf16(a, bfr, acc[nj], 0, 0, 0);
        }
    }
    #pragma unroll
    for (int nj = 0; nj < 8; ++nj) {
        int col = nj * 16 + (l & 15);
        float bias = be2[col];
        #pragma unroll
        for (int rg = 0; rg < 4; ++rg) {
            int row = row0 + (l >> 4) * 4 + rg;
            pf[(size_t)row * 128 + col] = fmaxf(acc[nj][rg] + bias, 0.f);
        }
    }
}

// ---- scan helper: first bucket with cumcount >= 16 -> float threshold -----
__device__ inline float knn_thresh(const int* __restrict__ hh, int l) {
    int h0 = hh[4 * l], h1 = hh[4 * l + 1], h2 = hh[4 * l + 2], h3 = hh[4 * l + 3];
    int c0 = h0, c1 = c0 + h1, c2 = c1 + h2, c3 = c2 + h3;
    int tot = c3;
    int inc = tot;
    for (int off = 1; off < 64; off <<= 1) {
        int vv = __shfl_up(inc, off);
        if (l >= off) inc += vv;
    }
    int excl = inc - tot;
    int Bc = 255;
    if      (excl + c0 >= 16) Bc = 4 * l;
    else if (excl + c1 >= 16) Bc = 4 * l + 1;
    else if (excl + c2 >= 16) Bc = 4 * l + 2;
    else if (excl + c3 >= 16) Bc = 4 * l + 3;
    for (int m = 1; m < 64; m <<= 1) Bc = min(Bc, __shfl_xor(Bc, m));
    return __uint_as_float((unsigned)(Bc + 401) << 21);
}

// ------- Kernel B: 16-NN (R10 structure: 1 query/wave, barrier-free,
//         direct-global stream) + cached-lmin extraction from R11. ----------
__global__ __launch_bounds__(256) void k_knn(
    const float4* __restrict__ pts4, int* __restrict__ knn) {
    __shared__ int hist[4][260];                   // 4.16 KB
    __shared__ unsigned long long buf[4][KCAP];    // 16 KB
    int t = threadIdx.x, w = t >> 6, l = t & 63;
    int b = blockIdx.x >> 11;
    int q = (blockIdx.x & 2047) * 4 + w;
    const float4* pb = pts4 + b * N_;
    float4 qp = pb[q];
    for (int i = l; i < 256; i += 64) hist[w][i] = 0;
    int cntw = 0;

    // ---- histogram over first 1024 candidates (self -> bucket 255)
    #pragma unroll 2
    for (int i = 0; i < 16; ++i) {
        int j = l + 64 * i;
        float4 c = pb[j];
        float dot = __fadd_rn(__fadd_rn(__fmul_rn(qp.x, c.x), __fmul_rn(qp.y, c.y)), __fmul_rn(qp.z, c.z));
        float d2 = __fsub_rn(__fadd_rn(qp.w, c.w), __fmul_rn(2.f, dot));
        d2 = (j == q) ? 1e30f : d2;
        unsigned uu = __float_as_uint(d2);
        int bk = (d2 < 0.f) ? 0 : min(255, max(0, (int)(uu >> 21) - 400));
        atomicAdd(&hist[w][bk], 1);
    }
    float Tf = knn_thresh(&hist[w][0], l);

    // ---- single filter pass over ALL 8192 candidates (incl. self, d2=0)
    #pragma unroll 4
    for (int i = 0; i < 128; ++i) {
        int j = l + 64 * i;
        float4 c = pb[j];
        float dot = __fadd_rn(__fadd_rn(__fmul_rn(qp.x, c.x), __fmul_rn(qp.y, c.y)), __fmul_rn(qp.z, c.z));
        float d2 = __fsub_rn(__fadd_rn(qp.w, c.w), __fmul_rn(2.f, dot));
        bool take = (d2 < Tf);
        unsigned long long mask = __ballot(take);
        if (take) {
            unsigned du = __float_as_uint(d2);
            unsigned mu = du ^ (unsigned)(((int)du >> 31) | 0x80000000);
            int pos = cntw + __popcll(mask & ((1ull << l) - 1ull));
            if (pos < KCAP) buf[w][pos] = ((unsigned long long)mu << 32) | (unsigned)j;
        }
        cntw += __popcll(mask);
    }
    int m_ = min(cntw, KCAP);

    unsigned long long key[8];
    #pragma unroll
    for (int r = 0; r < 8; ++r) {
        int e = l + 64 * r;
        key[r] = (e < m_) ? buf[w][e] : ~0ull;
    }
    // 17 rounds of wave-min extraction with cached local min; skip self
    unsigned long long lmin = key[0];
    #pragma unroll
    for (int r = 1; r < 8; ++r) lmin = (key[r] < lmin) ? key[r] : lmin;
    int emitted = 0;
    for (int r17 = 0; r17 < 17 && emitted < 16; ++r17) {
        unsigned long long wv = lmin;
        for (int m = 1; m < 64; m <<= 1) {
            unsigned long long o = __shfl_xor(wv, m);
            wv = (o < wv) ? o : wv;
        }
        int idx = (int)(wv & 0xffffffffu);
        if (idx != q) {
            if (l == 0) knn[((size_t)b * N_ + q) * 16 + emitted] = b * N_ + idx;
            ++emitted;
        }
        if (lmin == wv) {
            #pragma unroll
            for (int r = 0; r < 8; ++r) if (key[r] == wv) key[r] = ~0ull;
            lmin = key[0];
            #pragma unroll
            for (int r = 1; r < 8; ++r) lmin = (key[r] < lmin) ? key[r] : lmin;
        }
    }
}

// ---- Kernel U: uv = pf @ WuvT^T + bias_cat (A in LDS, B direct-global) ----
__global__ __launch_bounds__(256) void k_uv(
    const float* __restrict__ pf, const unsigned short* __restrict__ WuvT,
    const float* __restrict__ bias_cat,
    float* __restrict__ u, float* __restrict__ v) {
    __shared__ __align__(16) unsigned short As[128 * 136];
    int t = threadIdx.x;
    int l = t & 63, w = t >> 6;
    int wr = w >> 1, wcn = w & 1;
    int rowbase = blockIdx.x * 128;
    int ncol0 = blockIdx.y * 128;

    #pragma unroll
    for (int i = 0; i < 8; ++i) {
        int ci = t + 256 * i;
        int r = ci >> 4, c8 = (ci & 15) * 8;
        const float4* sp = (const float4*)(pf + (size_t)(rowbase + r) * 128 + c8);
        *(uint4*)&As[r * 136 + c8] = pack8(sp[0], sp[1]);
    }
    __syncthreads();

    f32x4 acc[4][4];
    #pragma unroll
    for (int i = 0; i < 4; ++i)
        #pragma unroll
        for (int j = 0; j < 4; ++j) acc[i][j] = (f32x4){0.f, 0.f, 0.f, 0.f};

    #pragma unroll
    for (int ks = 0; ks < 4; ++ks) {
        bf16x8 bfr[4], afr[4];
        #pragma unroll
        for (int nj = 0; nj < 4; ++nj)
            bfr[nj] = ldb8(&WuvT[(size_t)(ncol0 + wcn * 64 + nj * 16 + (l & 15)) * 128 + ks * 32 + (l >> 4) * 8]);
        #pragma unroll
        for (int mi = 0; mi < 4; ++mi)
            afr[mi] = ldb8(&As[(wr * 64 + mi * 16 + (l & 15)) * 136 + ks * 32 + (l >> 4) * 8]);
        #pragma unroll
        for (int mi = 0; mi < 4; ++mi)
            #pragma unroll
            for (int nj = 0; nj < 4; ++nj)
                acc[mi][nj] = __builtin_amdgcn_mfma_f32_16x16x32_bf16(afr[mi], bfr[nj], acc[mi][nj], 0, 0, 0);
    }
    float* outp = (ncol0 == 0) ? u : v;
    #pragma unroll
    for (int mi = 0; mi < 4; ++mi)
        #pragma unroll
        for (int nj = 0; nj < 4; ++nj) {
            int col = wcn * 64 + nj * 16 + (l & 15);
            float bias = bias_cat[ncol0 + col];
            #pragma unroll
            for (int rg = 0; rg < 4; ++rg) {
                int row = wr * 64 + mi * 16 + (l >> 4) * 4 + rg;
                outp[(size_t)(rowbase + row) * 128 + col] = acc[mi][nj][rg] + bias;
            }
        }
}

// ---------------- Kernel C: edge layer2 GEMM + max over K ------------------
__global__ __launch_bounds__(256) void k_edge(
    const float* __restrict__ u, const float* __restrict__ v,
    const int* __restrict__ knn, const unsigned short* __restrict__ Wl2T,
    const float* __restrict__ bl2, float* __restrict__ lf) {
    __shared__ __align__(16) unsigned short h1s[128 * 136];  // 34816 B
    int t = threadIdx.x;
    int l = t & 63, w = t >> 6;
    int wr = w >> 1, wcn = w & 1;
    int rowbase = blockIdx.x * 128;
    int p0 = blockIdx.x * 8;

    #pragma unroll 2
    for (int i = 0; i < 8; ++i) {
        int ci = t + 256 * i;
        int r = ci >> 4, c8 = (ci & 15) * 8;
        int nb = knn[rowbase + r];
        int pt = p0 + (r >> 4);
        const float4* vp = (const float4*)(v + (size_t)nb * 128 + c8);
        const float4* up = (const float4*)(u + (size_t)pt * 128 + c8);
        float4 va = vp[0], vb = vp[1];
        float4 ua = up[0], ub = up[1];
        unsigned d0 = (unsigned)f2b(fmaxf(ua.x + va.x, 0.f)) | ((unsigned)f2b(fmaxf(ua.y + va.y, 0.f)) << 16);
        unsigned d1 = (unsigned)f2b(fmaxf(ua.z + va.z, 0.f)) | ((unsigned)f2b(fmaxf(ua.w + va.w, 0.f)) << 16);
        unsigned d2 = (unsigned)f2b(fmaxf(ub.x + vb.x, 0.f)) | ((unsigned)f2b(fmaxf(ub.y + vb.y, 0.f)) << 16);
        unsigned d3 = (unsigned)f2b(fmaxf(ub.z + vb.z, 0.f)) | ((unsigned)f2b(fmaxf(ub.w + vb.w, 0.f)) << 16);
        uint4 pk; pk.x = d0; pk.y = d1; pk.z = d2; pk.w = d3;
        *(uint4*)&h1s[r * 136 + c8] = pk;
    }
    __syncthreads();

    f32x4 acc[4][4];
    #pragma unroll
    for (int i = 0; i < 4; ++i)
        #pragma unroll
        for (int j = 0; j < 4; ++j) acc[i][j] = (f32x4){0.f, 0.f, 0.f, 0.f};

    #pragma unroll
    for (int ks = 0; ks < 4; ++ks) {
        bf16x8 bfr[4], afr[4];
        #pragma unroll
        for (int nj = 0; nj < 4; ++nj)
            bfr[nj] = ldb8(&Wl2T[(size_t)(wcn * 64 + nj * 16 + (l & 15)) * 128 + ks * 32 + (l >> 4) * 8]);
        #pragma unroll
        for (int mi = 0; mi < 4; ++mi)
            afr[mi] = ldb8(&h1s[(wr * 64 + mi * 16 + (l & 15)) * 136 + ks * 32 + (l >> 4) * 8]);
        #pragma unroll
        for (int mi = 0; mi < 4; ++mi)
            #pragma unroll
            for (int nj = 0; nj < 4; ++nj)
                acc[mi][nj] = __builtin_amdgcn_mfma_f32_16x16x32_bf16(afr[mi], bfr[nj], acc[mi][nj], 0, 0, 0);
    }

    #pragma unroll
    for (int mi = 0; mi < 4; ++mi)
        #pragma unroll
        for (int nj = 0; nj < 4; ++nj) {
            int col = wcn * 64 + nj * 16 + (l & 15);
            float bias = bl2[col];
            float m = fmaxf(acc[mi][nj][0] + bias, 0.f);
            m = fmaxf(m, fmaxf(acc[mi][nj][1] + bias, 0.f));
            m = fmaxf(m, fmaxf(acc[mi][nj][2] + bias, 0.f));
            m = fmaxf(m, fmaxf(acc[mi][nj][3] + bias, 0.f));
            m = fmaxf(m, __shfl_xor(m, 16));
            m = fmaxf(m, __shfl_xor(m, 32));
            if (l < 16) lf[(size_t)(p0 + wr * 4 + mi) * 128 + col] = m;
        }
}

// -- Kernel D: ctx col-max fused in-register; gf via atomicMax (no cs LDS) --
__global__ __launch_bounds__(256) void k_ctx(
    const float* __restrict__ pf, const float* __restrict__ lf,
    const unsigned short* __restrict__ WcT, const float* __restrict__ bc,
    float* __restrict__ gf) {
    __shared__ __align__(16) unsigned short As[128 * 136];
    int t = threadIdx.x;
    int l = t & 63, w = t >> 6;
    int wr = w >> 1, wcn = w & 1;
    int rowbase = blockIdx.x * 128;
    int ncol0 = blockIdx.y * 128;
    int b = rowbase >> 13;

    f32x4 acc[4][4];
    #pragma unroll
    for (int i = 0; i < 4; ++i)
        #pragma unroll
        for (int j = 0; j < 4; ++j) acc[i][j] = (f32x4){0.f, 0.f, 0.f, 0.f};

    for (int kb = 0; kb < 2; ++kb) {
        const float* src = kb ? lf : pf;
        #pragma unroll
        for (int i = 0; i < 8; ++i) {
            int ci = t + 256 * i;
            int r = ci >> 4, c8 = (ci & 15) * 8;
            const float4* sp = (const float4*)(src + (size_t)(rowbase + r) * 128 + c8);
            *(uint4*)&As[r * 136 + c8] = pack8(sp[0], sp[1]);
        }
        __syncthreads();
        #pragma unroll
        for (int ks = 0; ks < 4; ++ks) {
            bf16x8 bfr[4], afr[4];
            #pragma unroll
            for (int nj = 0; nj < 4; ++nj)
                bfr[nj] = ldb8(&WcT[(size_t)(ncol0 + wcn * 64 + nj * 16 + (l & 15)) * 256 + kb * 128 + ks * 32 + (l >> 4) * 8]);
            #pragma unroll
            for (int mi = 0; mi < 4; ++mi)
                afr[mi] = ldb8(&As[(wr * 64 + mi * 16 + (l & 15)) * 136 + ks * 32 + (l >> 4) * 8]);
            #pragma unroll
            for (int mi = 0; mi < 4; ++mi)
                #pragma unroll
                for (int nj = 0; nj < 4; ++nj)
                    acc[mi][nj] = __builtin_amdgcn_mfma_f32_16x16x32_bf16(afr[mi], bfr[nj], acc[mi][nj], 0, 0, 0);
        }
        __syncthreads();
    }
    #pragma unroll
    for (int nj = 0; nj < 4; ++nj) {
        int col = ncol0 + wcn * 64 + nj * 16 + (l & 15);
        float m = acc[0][nj][0];
        #pragma unroll
        for (int mi = 0; mi < 4; ++mi)
            #pragma unroll
            for (int rg = 0; rg < 4; ++rg) m = fmaxf(m, acc[mi][nj][rg]);
        m = fmaxf(m + bc[col], 0.f);
        m = fmaxf(m, __shfl_xor(m, 16));
        m = fmaxf(m, __shfl_xor(m, 32));
        if (l < 16) atomicMax((unsigned int*)&gf[b * 256 + col], __float_as_uint(m));
    }
}

// ---------------- Kernel E: heads (vectorized staging, global-B) -----------
__global__ __launch_bounds__(256) void k_head(
    const float* __restrict__ pf, const float* __restrict__ lf, const float* __restrict__ gf,
    const unsigned short* __restrict__ Wk1T, const float* __restrict__ bk1,
    const float* __restrict__ Wk2, const float* __restrict__ bk2,
    const unsigned short* __restrict__ Wp1T, const float* __restrict__ bp1,
    const float* __restrict__ Wp2, const float* __restrict__ bp2,
    float* __restrict__ out) {
    __shared__ __align__(16) char smem[67584];
    unsigned short* As = (unsigned short*)smem;  // [128][136] bf16
    float* hs = (float*)smem;                    // [128][132] f32 (reuse)
    int t = threadIdx.x;
    int l = t & 63, w = t >> 6;
    int wr = w >> 1, wcn = w & 1;
    int rowbase = blockIdx.x * 128;
    int b = rowbase >> 13;
    int br = blockIdx.y;
    const unsigned short* W1T = br ? Wp1T : Wk1T;
    const float* b1 = br ? bp1 : bk1;
    const float* W2 = br ? Wp2 : Wk2;
    const float* b2p = br ? bp2 : bk2;
    int OC = br ? 8 : 10;
    float* obase = out + (br ? (size_t)NP * 10 : 0);

    f32x4 acc[4][4];
    #pragma unroll
    for (int i = 0; i < 4; ++i)
        #pragma unroll
        for (int j = 0; j < 4; ++j) acc[i][j] = (f32x4){0.f, 0.f, 0.f, 0.f};

    for (int kb = 0; kb < 4; ++kb) {
        #pragma unroll
        for (int i = 0; i < 8; ++i) {
            int ci = t + 256 * i;
            int r = ci >> 4, c8 = (ci & 15) * 8;
            const float4* sp;
            if (kb == 0)      sp = (const float4*)(pf + (size_t)(rowbase + r) * 128 + c8);
            else if (kb == 1) sp = (const float4*)(lf + (size_t)(rowbase + r) * 128 + c8);
            else              sp = (const float4*)(gf + b * 256 + (kb - 2) * 128 + c8);
            *(uint4*)&As[r * 136 + c8] = pack8(sp[0], sp[1]);
        }
        __syncthreads();
        #pragma unroll
        for (int ks = 0; ks < 4; ++ks) {
            bf16x8 bfr[4], afr[4];
            #pragma unroll
            for (int nj = 0; nj < 4; ++nj)
                bfr[nj] = ldb8(&W1T[(size_t)(wcn * 64 + nj * 16 + (l & 15)) * 512 + kb * 128 + ks * 32 + (l >> 4) * 8]);
            #pragma unroll
            for (int mi = 0; mi < 4; ++mi)
                afr[mi] = ldb8(&As[(wr * 64 + mi * 16 + (l & 15)) * 136 + ks * 32 + (l >> 4) * 8]);
            #pragma unroll
            for (int mi = 0; mi < 4; ++mi)
                #pragma unroll
                for (int nj = 0; nj < 4; ++nj)
                    acc[mi][nj] = __builtin_amdgcn_mfma_f32_16x16x32_bf16(afr[mi], bfr[nj], acc[mi][nj], 0, 0, 0);
        }
        __syncthreads();
    }
    #pragma unroll
    for (int mi = 0; mi < 4; ++mi)
        #pragma unroll
        for (int nj = 0; nj < 4; ++nj)
            #pragma unroll
            for (int rg = 0; rg < 4; ++rg) {
                int row = wr * 64 + mi * 16 + (l >> 4) * 4 + rg;
                int col = wcn * 64 + nj * 16 + (l & 15);
                hs[row * 132 + col] = fmaxf(acc[mi][nj][rg] + b1[col], 0.f);
            }
    __syncthreads();
    for (int o = t; o < 128 * OC; o += 256) {
        int r = o / OC, c = o % OC;
        float a = b2p[c];
        for (int k2 = 0; k2 < 128; ++k2) a += hs[r * 132 + k2] * W2[k2 * OC + c];
        obase[(size_t)(rowbase + r) * OC + c] = a;
    }
}

extern "C" void kernel_launch(void* const* d_in, const int* in_sizes, int n_in,
                              void* d_out, int out_size, void* d_ws, size_t ws_size,
                              hipStream_t stream) {
    const float* pts = (const float*)d_in[0];
    const float* nrm = (const float*)d_in[1];
    const float* We1 = (const float*)d_in[2];
    const float* be1 = (const float*)d_in[3];
    const float* We2 = (const float*)d_in[4];
    const float* be2 = (const float*)d_in[5];
    const float* Wl1 = (const float*)d_in[6];
    const float* bl1 = (const float*)d_in[7];
    const float* Wl2 = (const float*)d_in[8];
    const float* bl2 = (const float*)d_in[9];
    const float* Wc  = (const float*)d_in[10];
    const float* bc  = (const float*)d_in[11];
    const float* Wk1 = (const float*)d_in[12];
    const float* bk1 = (const float*)d_in[13];
    const float* Wk2 = (const float*)d_in[14];
    const float* bk2 = (const float*)d_in[15];
    const float* Wp1 = (const float*)d_in[16];
    const float* bp1 = (const float*)d_in[17];
    const float* Wp2 = (const float*)d_in[18];
    const float* bp2 = (const float*)d_in[19];
    float* out = (float*)d_out;

    char* ws = (char*)d_ws;
    size_t off = 0;
    float* pf = (float*)(ws + off);       off += (size_t)NP * 128 * 4;   // 8.39 MB
    float* lf = (float*)(ws + off);       off += (size_t)NP * 128 * 4;   // 8.39 MB
    float* u  = (float*)(ws + off);       off += (size_t)NP * 128 * 4;   // 8.39 MB
    float* v  = (float*)(ws + off);       off += (size_t)NP * 128 * 4;   // 8.39 MB
    int* knn  = (int*)(ws + off);         off += (size_t)NP * 16 * 4;    // 1.05 MB
    float* gf = (float*)(ws + off);       off += 2048;
    float4* pts4 = (float4*)(ws + off);   off += (size_t)NP * 16;        // 256 KB
    float* bias_cat = (float*)(ws + off); off += 1024;
    unsigned short* WuvT = (unsigned short*)(ws + off); off += 256 * 128 * 2;
    unsigned short* Wl2T = (unsigned short*)(ws + off); off += 128 * 128 * 2;
    unsigned short* WcT  = (unsigned short*)(ws + off); off += 256 * 256 * 2;
    unsigned short* Wk1T = (unsigned short*)(ws + off); off += 128 * 512 * 2;
    unsigned short* Wp1T = (unsigned short*)(ws + off); off += 128 * 512 * 2;
    unsigned short* We2T = (unsigned short*)(ws + off); off += 128 * 128 * 2;
    unsigned short* h1   = (unsigned short*)(ws + off); off += (size_t)NP * 128 * 2;  // 4.19 MB

    hipLaunchKernelGGL(k_h1, dim3(2048), dim3(256), 0, stream,
                       pts, nrm, We1, be1, h1, gf, pts4);
    hipLaunchKernelGGL(k_prep, dim3(64), dim3(256), 0, stream,
                       Wl1, bl1, Wl2, Wc, Wk1, Wp1, We2,
                       WuvT, bias_cat, Wl2T, WcT, Wk1T, Wp1T, We2T);
    hipLaunchKernelGGL(k_knn, dim3(4096), dim3(256), 0, stream, pts4, knn);
    hipLaunchKernelGGL(k_pf2, dim3(256), dim3(256), 0, stream,
                       h1, We2T, be2, pf);
    hipLaunchKernelGGL(k_uv, dim3(128, 2), dim3(256), 0, stream,
                       pf, WuvT, bias_cat, u, v);
    hipLaunchKernelGGL(k_edge, dim3(2048), dim3(256), 0, stream,
                       u, v, knn, Wl2T, bl2, lf);
    hipLaunchKernelGGL(k_ctx, dim3(128, 2), dim3(256), 0, stream,
                       pf, lf, WcT, bc, gf);
    hipLaunchKernelGGL(k_head, dim3(128, 2), dim3(256), 0, stream,
                       pf, lf, gf, Wk1T, bk1, Wk2, bk2, Wp1T, bp1, Wp2, bp2, out);
}

// Round 14
// 340.835 us; speedup vs baseline: 3.7685x; 1.0242x over previous
//
#include <hip/hip_runtime.h>

#define B_ 2
#define N_ 8192
#define NP 16384   // B_*N_
#define K_ 16
#define H_ 128
#define KCAP 512

typedef short bf16x8 __attribute__((ext_vector_type(8)));
typedef float f32x4 __attribute__((ext_vector_type(4)));

__device__ inline unsigned short f2b(float f) {
    unsigned u = __builtin_bit_cast(unsigned, f);
    unsigned r = (u + 0x7fff + ((u >> 16) & 1)) >> 16;
    return (unsigned short)r;
}
__device__ inline bf16x8 ldb8(const unsigned short* p) {
    return *(const bf16x8*)p;
}
__device__ inline uint4 pack8(float4 a, float4 b) {
    uint4 pk;
    pk.x = (unsigned)f2b(a.x) | ((unsigned)f2b(a.y) << 16);
    pk.y = (unsigned)f2b(a.z) | ((unsigned)f2b(a.w) << 16);
    pk.z = (unsigned)f2b(b.x) | ((unsigned)f2b(b.y) << 16);
    pk.w = (unsigned)f2b(b.z) | ((unsigned)f2b(b.w) << 16);
    return pk;
}

// ---- Kernel H: h1 = relu(x@We1+be1) bf16; pack pts4; zero gf --------------
__global__ __launch_bounds__(256) void k_h1(
    const float* __restrict__ pts, const float* __restrict__ nrm,
    const float* __restrict__ We1, const float* __restrict__ be1,
    unsigned short* __restrict__ h1, float* __restrict__ gf,
    float4* __restrict__ pts4) {
    int tid = blockIdx.x * 256 + threadIdx.x;
    if (blockIdx.x == 0) { gf[threadIdx.x] = 0.f; gf[256 + threadIdx.x] = 0.f; }
    if (tid < NP) {
        int p = tid;
        float x = pts[p * 3], y = pts[p * 3 + 1], z = pts[p * 3 + 2];
        float sq = __fadd_rn(__fadd_rn(__fmul_rn(x, x), __fmul_rn(y, y)), __fmul_rn(z, z));
        pts4[p] = make_float4(x, y, z, sq);
    }
    for (int o = tid; o < NP * 128; o += gridDim.x * 256) {
        int p = o >> 7, h = o & 127;
        float a = be1[h];
        a += pts[p * 3]     * We1[0 * 128 + h];
        a += pts[p * 3 + 1] * We1[1 * 128 + h];
        a += pts[p * 3 + 2] * We1[2 * 128 + h];
        a += nrm[p * 3]     * We1[3 * 128 + h];
        a += nrm[p * 3 + 1] * We1[4 * 128 + h];
        a += nrm[p * 3 + 2] * We1[5 * 128 + h];
        h1[o] = f2b(fmaxf(a, 0.f));
    }
}

// ---------------- Kernel P: prep factored + transposed bf16 weights --------
__global__ __launch_bounds__(256) void k_prep(
    const float* __restrict__ Wl1, const float* __restrict__ bl1,
    const float* __restrict__ Wl2, const float* __restrict__ Wc,
    const float* __restrict__ Wk1, const float* __restrict__ Wp1,
    const float* __restrict__ We2,
    unsigned short* __restrict__ WuvT, float* __restrict__ bias_cat,
    unsigned short* __restrict__ Wl2T, unsigned short* __restrict__ WcT,
    unsigned short* __restrict__ Wk1T, unsigned short* __restrict__ Wp1T,
    unsigned short* __restrict__ We2T) {
    int tid = blockIdx.x * 256 + threadIdx.x;
    int stride = gridDim.x * 256;
    for (int i = tid; i < 256 * 128; i += stride) {
        int n = i >> 7, k = i & 127;
        float val = (n < 128) ? Wl1[k * 128 + n] - Wl1[(k + 128) * 128 + n]
                              : Wl1[(k + 128) * 128 + (n - 128)];
        WuvT[i] = f2b(val);
    }
    for (int i = tid; i < 256; i += stride) bias_cat[i] = (i < 128) ? bl1[i] : 0.f;
    for (int i = tid; i < 128 * 128; i += stride) {
        int n = i >> 7, k = i & 127;
        Wl2T[i] = f2b(Wl2[k * 128 + n]);
        We2T[i] = f2b(We2[k * 128 + n]);
    }
    for (int i = tid; i < 256 * 256; i += stride) {
        int n = i >> 8, k = i & 255;
        WcT[i] = f2b(Wc[k * 256 + n]);
    }
    for (int i = tid; i < 128 * 512; i += stride) {
        int n = i >> 9, k = i & 511;
        Wk1T[i] = f2b(Wk1[k * 128 + n]);
        Wp1T[i] = f2b(Wp1[k * 128 + n]);
    }
}

// ---- Kernel PF2: pfb(bf16) = relu(h1 @ We2T^T + be2), direct-global -------
__global__ __launch_bounds__(256) void k_pf2(
    const unsigned short* __restrict__ h1, const unsigned short* __restrict__ We2T,
    const float* __restrict__ be2, unsigned short* __restrict__ pfb) {
    int t = threadIdx.x, l = t & 63, w = t >> 6;
    int row0 = blockIdx.x * 64 + w * 16;
    f32x4 acc[8];
    #pragma unroll
    for (int nj = 0; nj < 8; ++nj) acc[nj] = (f32x4){0.f, 0.f, 0.f, 0.f};
    #pragma unroll
    for (int ks = 0; ks < 4; ++ks) {
        bf16x8 a = ldb8(&h1[(size_t)(row0 + (l & 15)) * 128 + ks * 32 + (l >> 4) * 8]);
        #pragma unroll
        for (int nj = 0; nj < 8; ++nj) {
            bf16x8 bfr = ldb8(&We2T[(size_t)(nj * 16 + (l & 15)) * 128 + ks * 32 + (l >> 4) * 8]);
            acc[nj] = __builtin_amdgcn_mfma_f32_16x16x32_bf16(a, bfr, acc[nj], 0, 0, 0);
        }
    }
    #pragma unroll
    for (int nj = 0; nj < 8; ++nj) {
        int col = nj * 16 + (l & 15);
        float bias = be2[col];
        #pragma unroll
        for (int rg = 0; rg < 4; ++rg) {
            int row = row0 + (l >> 4) * 4 + rg;
            pfb[(size_t)row * 128 + col] = f2b(fmaxf(acc[nj][rg] + bias, 0.f));
        }
    }
}

// ---- scan helper: first bucket with cumcount >= 16 -> float threshold -----
__device__ inline float knn_thresh(const int* __restrict__ hh, int l) {
    int h0 = hh[4 * l], h1 = hh[4 * l + 1], h2 = hh[4 * l + 2], h3 = hh[4 * l + 3];
    int c0 = h0, c1 = c0 + h1, c2 = c1 + h2, c3 = c2 + h3;
    int tot = c3;
    int inc = tot;
    for (int off = 1; off < 64; off <<= 1) {
        int vv = __shfl_up(inc, off);
        if (l >= off) inc += vv;
    }
    int excl = inc - tot;
    int Bc = 255;
    if      (excl + c0 >= 16) Bc = 4 * l;
    else if (excl + c1 >= 16) Bc = 4 * l + 1;
    else if (excl + c2 >= 16) Bc = 4 * l + 2;
    else if (excl + c3 >= 16) Bc = 4 * l + 3;
    for (int m = 1; m < 64; m <<= 1) Bc = min(Bc, __shfl_xor(Bc, m));
    return __uint_as_float((unsigned)(Bc + 401) << 21);
}

// ------- Kernel B: 16-NN (1 query/wave, barrier-free, direct-global) -------
__global__ __launch_bounds__(256) void k_knn(
    const float4* __restrict__ pts4, int* __restrict__ knn) {
    __shared__ int hist[4][260];                   // 4.16 KB
    __shared__ unsigned long long buf[4][KCAP];    // 16 KB
    int t = threadIdx.x, w = t >> 6, l = t & 63;
    int b = blockIdx.x >> 11;
    int q = (blockIdx.x & 2047) * 4 + w;
    const float4* pb = pts4 + b * N_;
    float4 qp = pb[q];
    for (int i = l; i < 256; i += 64) hist[w][i] = 0;
    int cntw = 0;

    #pragma unroll 2
    for (int i = 0; i < 16; ++i) {
        int j = l + 64 * i;
        float4 c = pb[j];
        float dot = __fadd_rn(__fadd_rn(__fmul_rn(qp.x, c.x), __fmul_rn(qp.y, c.y)), __fmul_rn(qp.z, c.z));
        float d2 = __fsub_rn(__fadd_rn(qp.w, c.w), __fmul_rn(2.f, dot));
        d2 = (j == q) ? 1e30f : d2;
        unsigned uu = __float_as_uint(d2);
        int bk = (d2 < 0.f) ? 0 : min(255, max(0, (int)(uu >> 21) - 400));
        atomicAdd(&hist[w][bk], 1);
    }
    float Tf = knn_thresh(&hist[w][0], l);

    #pragma unroll 4
    for (int i = 0; i < 128; ++i) {
        int j = l + 64 * i;
        float4 c = pb[j];
        float dot = __fadd_rn(__fadd_rn(__fmul_rn(qp.x, c.x), __fmul_rn(qp.y, c.y)), __fmul_rn(qp.z, c.z));
        float d2 = __fsub_rn(__fadd_rn(qp.w, c.w), __fmul_rn(2.f, dot));
        bool take = (d2 < Tf);
        unsigned long long mask = __ballot(take);
        if (take) {
            unsigned du = __float_as_uint(d2);
            unsigned mu = du ^ (unsigned)(((int)du >> 31) | 0x80000000);
            int pos = cntw + __popcll(mask & ((1ull << l) - 1ull));
            if (pos < KCAP) buf[w][pos] = ((unsigned long long)mu << 32) | (unsigned)j;
        }
        cntw += __popcll(mask);
    }
    int m_ = min(cntw, KCAP);

    unsigned long long key[8];
    #pragma unroll
    for (int r = 0; r < 8; ++r) {
        int e = l + 64 * r;
        key[r] = (e < m_) ? buf[w][e] : ~0ull;
    }
    unsigned long long lmin = key[0];
    #pragma unroll
    for (int r = 1; r < 8; ++r) lmin = (key[r] < lmin) ? key[r] : lmin;
    int emitted = 0;
    for (int r17 = 0; r17 < 17 && emitted < 16; ++r17) {
        unsigned long long wv = lmin;
        for (int m = 1; m < 64; m <<= 1) {
            unsigned long long o = __shfl_xor(wv, m);
            wv = (o < wv) ? o : wv;
        }
        int idx = (int)(wv & 0xffffffffu);
        if (idx != q) {
            if (l == 0) knn[((size_t)b * N_ + q) * 16 + emitted] = b * N_ + idx;
            ++emitted;
        }
        if (lmin == wv) {
            #pragma unroll
            for (int r = 0; r < 8; ++r) if (key[r] == wv) key[r] = ~0ull;
            lmin = key[0];
            #pragma unroll
            for (int r = 1; r < 8; ++r) lmin = (key[r] < lmin) ? key[r] : lmin;
        }
    }
}

// ---- Kernel U: uv = pfb @ WuvT^T + bias_cat (A and B direct-global) -------
__global__ __launch_bounds__(256) void k_uv(
    const unsigned short* __restrict__ pfb, const unsigned short* __restrict__ WuvT,
    const float* __restrict__ bias_cat,
    float* __restrict__ u, float* __restrict__ v) {
    int t = threadIdx.x;
    int l = t & 63, w = t >> 6;
    int wr = w >> 1, wcn = w & 1;
    int rowbase = blockIdx.x * 128;
    int ncol0 = blockIdx.y * 128;

    f32x4 acc[4][4];
    #pragma unroll
    for (int i = 0; i < 4; ++i)
        #pragma unroll
        for (int j = 0; j < 4; ++j) acc[i][j] = (f32x4){0.f, 0.f, 0.f, 0.f};

    #pragma unroll
    for (int ks = 0; ks < 4; ++ks) {
        bf16x8 bfr[4], afr[4];
        #pragma unroll
        for (int nj = 0; nj < 4; ++nj)
            bfr[nj] = ldb8(&WuvT[(size_t)(ncol0 + wcn * 64 + nj * 16 + (l & 15)) * 128 + ks * 32 + (l >> 4) * 8]);
        #pragma unroll
        for (int mi = 0; mi < 4; ++mi)
            afr[mi] = ldb8(&pfb[(size_t)(rowbase + wr * 64 + mi * 16 + (l & 15)) * 128 + ks * 32 + (l >> 4) * 8]);
        #pragma unroll
        for (int mi = 0; mi < 4; ++mi)
            #pragma unroll
            for (int nj = 0; nj < 4; ++nj)
                acc[mi][nj] = __builtin_amdgcn_mfma_f32_16x16x32_bf16(afr[mi], bfr[nj], acc[mi][nj], 0, 0, 0);
    }
    float* outp = (ncol0 == 0) ? u : v;
    #pragma unroll
    for (int mi = 0; mi < 4; ++mi)
        #pragma unroll
        for (int nj = 0; nj < 4; ++nj) {
            int col = wcn * 64 + nj * 16 + (l & 15);
            float bias = bias_cat[ncol0 + col];
            #pragma unroll
            for (int rg = 0; rg < 4; ++rg) {
                int row = wr * 64 + mi * 16 + (l >> 4) * 4 + rg;
                outp[(size_t)(rowbase + row) * 128 + col] = acc[mi][nj][rg] + bias;
            }
        }
}

// ---------------- Kernel C: edge layer2 GEMM + max over K -> lfb bf16 ------
__global__ __launch_bounds__(256) void k_edge(
    const float* __restrict__ u, const float* __restrict__ v,
    const int* __restrict__ knn, const unsigned short* __restrict__ Wl2T,
    const float* __restrict__ bl2, unsigned short* __restrict__ lfb) {
    __shared__ __align__(16) unsigned short h1s[128 * 136];  // 34816 B
    int t = threadIdx.x;
    int l = t & 63, w = t >> 6;
    int wr = w >> 1, wcn = w & 1;
    int rowbase = blockIdx.x * 128;
    int p0 = blockIdx.x * 8;

    #pragma unroll 2
    for (int i = 0; i < 8; ++i) {
        int ci = t + 256 * i;
        int r = ci >> 4, c8 = (ci & 15) * 8;
        int nb = knn[rowbase + r];
        int pt = p0 + (r >> 4);
        const float4* vp = (const float4*)(v + (size_t)nb * 128 + c8);
        const float4* up = (const float4*)(u + (size_t)pt * 128 + c8);
        float4 va = vp[0], vb = vp[1];
        float4 ua = up[0], ub = up[1];
        unsigned d0 = (unsigned)f2b(fmaxf(ua.x + va.x, 0.f)) | ((unsigned)f2b(fmaxf(ua.y + va.y, 0.f)) << 16);
        unsigned d1 = (unsigned)f2b(fmaxf(ua.z + va.z, 0.f)) | ((unsigned)f2b(fmaxf(ua.w + va.w, 0.f)) << 16);
        unsigned d2 = (unsigned)f2b(fmaxf(ub.x + vb.x, 0.f)) | ((unsigned)f2b(fmaxf(ub.y + vb.y, 0.f)) << 16);
        unsigned d3 = (unsigned)f2b(fmaxf(ub.z + vb.z, 0.f)) | ((unsigned)f2b(fmaxf(ub.w + vb.w, 0.f)) << 16);
        uint4 pk; pk.x = d0; pk.y = d1; pk.z = d2; pk.w = d3;
        *(uint4*)&h1s[r * 136 + c8] = pk;
    }
    __syncthreads();

    f32x4 acc[4][4];
    #pragma unroll
    for (int i = 0; i < 4; ++i)
        #pragma unroll
        for (int j = 0; j < 4; ++j) acc[i][j] = (f32x4){0.f, 0.f, 0.f, 0.f};

    #pragma unroll
    for (int ks = 0; ks < 4; ++ks) {
        bf16x8 bfr[4], afr[4];
        #pragma unroll
        for (int nj = 0; nj < 4; ++nj)
            bfr[nj] = ldb8(&Wl2T[(size_t)(wcn * 64 + nj * 16 + (l & 15)) * 128 + ks * 32 + (l >> 4) * 8]);
        #pragma unroll
        for (int mi = 0; mi < 4; ++mi)
            afr[mi] = ldb8(&h1s[(wr * 64 + mi * 16 + (l & 15)) * 136 + ks * 32 + (l >> 4) * 8]);
        #pragma unroll
        for (int mi = 0; mi < 4; ++mi)
            #pragma unroll
            for (int nj = 0; nj < 4; ++nj)
                acc[mi][nj] = __builtin_amdgcn_mfma_f32_16x16x32_bf16(afr[mi], bfr[nj], acc[mi][nj], 0, 0, 0);
    }

    #pragma unroll
    for (int mi = 0; mi < 4; ++mi)
        #pragma unroll
        for (int nj = 0; nj < 4; ++nj) {
            int col = wcn * 64 + nj * 16 + (l & 15);
            float bias = bl2[col];
            float m = fmaxf(acc[mi][nj][0] + bias, 0.f);
            m = fmaxf(m, fmaxf(acc[mi][nj][1] + bias, 0.f));
            m = fmaxf(m, fmaxf(acc[mi][nj][2] + bias, 0.f));
            m = fmaxf(m, fmaxf(acc[mi][nj][3] + bias, 0.f));
            m = fmaxf(m, __shfl_xor(m, 16));
            m = fmaxf(m, __shfl_xor(m, 32));
            if (l < 16) lfb[(size_t)(p0 + wr * 4 + mi) * 128 + col] = f2b(m);
        }
}

// -- Kernel D: ctx col-max fused in-register; LDS-free (A direct-global) ----
__global__ __launch_bounds__(256) void k_ctx(
    const unsigned short* __restrict__ pfb, const unsigned short* __restrict__ lfb,
    const unsigned short* __restrict__ WcT, const float* __restrict__ bc,
    float* __restrict__ gf) {
    int t = threadIdx.x;
    int l = t & 63, w = t >> 6;
    int wr = w >> 1, wcn = w & 1;
    int rowbase = blockIdx.x * 128;
    int ncol0 = blockIdx.y * 128;
    int b = rowbase >> 13;

    f32x4 acc[4][4];
    #pragma unroll
    for (int i = 0; i < 4; ++i)
        #pragma unroll
        for (int j = 0; j < 4; ++j) acc[i][j] = (f32x4){0.f, 0.f, 0.f, 0.f};

    #pragma unroll
    for (int kb = 0; kb < 2; ++kb) {
        const unsigned short* srcb = kb ? lfb : pfb;
        #pragma unroll
        for (int ks = 0; ks < 4; ++ks) {
            bf16x8 bfr[4], afr[4];
            #pragma unroll
            for (int nj = 0; nj < 4; ++nj)
                bfr[nj] = ldb8(&WcT[(size_t)(ncol0 + wcn * 64 + nj * 16 + (l & 15)) * 256 + kb * 128 + ks * 32 + (l >> 4) * 8]);
            #pragma unroll
            for (int mi = 0; mi < 4; ++mi)
                afr[mi] = ldb8(&srcb[(size_t)(rowbase + wr * 64 + mi * 16 + (l & 15)) * 128 + ks * 32 + (l >> 4) * 8]);
            #pragma unroll
            for (int mi = 0; mi < 4; ++mi)
                #pragma unroll
                for (int nj = 0; nj < 4; ++nj)
                    acc[mi][nj] = __builtin_amdgcn_mfma_f32_16x16x32_bf16(afr[mi], bfr[nj], acc[mi][nj], 0, 0, 0);
        }
    }
    #pragma unroll
    for (int nj = 0; nj < 4; ++nj) {
        int col = ncol0 + wcn * 64 + nj * 16 + (l & 15);
        float m = acc[0][nj][0];
        #pragma unroll
        for (int mi = 0; mi < 4; ++mi)
            #pragma unroll
            for (int rg = 0; rg < 4; ++rg) m = fmaxf(m, acc[mi][nj][rg]);
        m = fmaxf(m + bc[col], 0.f);
        m = fmaxf(m, __shfl_xor(m, 16));
        m = fmaxf(m, __shfl_xor(m, 32));
        if (l < 16) atomicMax((unsigned int*)&gf[b * 256 + col], __float_as_uint(m));
    }
}

// ---------------- Kernel E: heads (pf/lf direct-global, gf tiny LDS) -------
__global__ __launch_bounds__(256) void k_head(
    const unsigned short* __restrict__ pfb, const unsigned short* __restrict__ lfb,
    const float* __restrict__ gf,
    const unsigned short* __restrict__ Wk1T, const float* __restrict__ bk1,
    const float* __restrict__ Wk2, const float* __restrict__ bk2,
    const unsigned short* __restrict__ Wp1T, const float* __restrict__ bp1,
    const float* __restrict__ Wp2, const float* __restrict__ bp2,
    float* __restrict__ out) {
    __shared__ float hs[128 * 132];          // 67584 B
    __shared__ unsigned short gfs[256];      // 512 B
    int t = threadIdx.x;
    int l = t & 63, w = t >> 6;
    int wr = w >> 1, wcn = w & 1;
    int rowbase = blockIdx.x * 128;
    int b = rowbase >> 13;
    int br = blockIdx.y;
    const unsigned short* W1T = br ? Wp1T : Wk1T;
    const float* b1 = br ? bp1 : bk1;
    const float* W2 = br ? Wp2 : Wk2;
    const float* b2p = br ? bp2 : bk2;
    int OC = br ? 8 : 10;
    float* obase = out + (br ? (size_t)NP * 10 : 0);

    gfs[t] = f2b(gf[b * 256 + t]);
    __syncthreads();

    f32x4 acc[4][4];
    #pragma unroll
    for (int i = 0; i < 4; ++i)
        #pragma unroll
        for (int j = 0; j < 4; ++j) acc[i][j] = (f32x4){0.f, 0.f, 0.f, 0.f};

    #pragma unroll
    for (int kb = 0; kb < 4; ++kb) {
        #pragma unroll
        for (int ks = 0; ks < 4; ++ks) {
            bf16x8 bfr[4], afr[4];
            #pragma unroll
            for (int nj = 0; nj < 4; ++nj)
                bfr[nj] = ldb8(&W1T[(size_t)(wcn * 64 + nj * 16 + (l & 15)) * 512 + kb * 128 + ks * 32 + (l >> 4) * 8]);
            #pragma unroll
            for (int mi = 0; mi < 4; ++mi) {
                if (kb == 0)
                    afr[mi] = ldb8(&pfb[(size_t)(rowbase + wr * 64 + mi * 16 + (l & 15)) * 128 + ks * 32 + (l >> 4) * 8]);
                else if (kb == 1)
                    afr[mi] = ldb8(&lfb[(size_t)(rowbase + wr * 64 + mi * 16 + (l & 15)) * 128 + ks * 32 + (l >> 4) * 8]);
                else
                    afr[mi] = ldb8(&gfs[(kb - 2) * 128 + ks * 32 + (l >> 4) * 8]);  // row-broadcast
            }
            #pragma unroll
            for (int mi = 0; mi < 4; ++mi)
                #pragma unroll
                for (int nj = 0; nj < 4; ++nj)
                    acc[mi][nj] = __builtin_amdgcn_mfma_f32_16x16x32_bf16(afr[mi], bfr[nj], acc[mi][nj], 0, 0, 0);
        }
    }
    #pragma unroll
    for (int mi = 0; mi < 4; ++mi)
        #pragma unroll
        for (int nj = 0; nj < 4; ++nj)
            #pragma unroll
            for (int rg = 0; rg < 4; ++rg) {
                int row = wr * 64 + mi * 16 + (l >> 4) * 4 + rg;
                int col = wcn * 64 + nj * 16 + (l & 15);
                hs[row * 132 + col] = fmaxf(acc[mi][nj][rg] + b1[col], 0.f);
            }
    __syncthreads();
    for (int o = t; o < 128 * OC; o += 256) {
        int r = o / OC, c = o % OC;
        float a = b2p[c];
        for (int k2 = 0; k2 < 128; ++k2) a += hs[r * 132 + k2] * W2[k2 * OC + c];
        obase[(size_t)(rowbase + r) * OC + c] = a;
    }
}

extern "C" void kernel_launch(void* const* d_in, const int* in_sizes, int n_in,
                              void* d_out, int out_size, void* d_ws, size_t ws_size,
                              hipStream_t stream) {
    const float* pts = (const float*)d_in[0];
    const float* nrm = (const float*)d_in[1];
    const float* We1 = (const float*)d_in[2];
    const float* be1 = (const float*)d_in[3];
    const float* We2 = (const float*)d_in[4];
    const float* be2 = (const float*)d_in[5];
    const float* Wl1 = (const float*)d_in[6];
    const float* bl1 = (const float*)d_in[7];
    const float* Wl2 = (const float*)d_in[8];
    const float* bl2 = (const float*)d_in[9];
    const float* Wc  = (const float*)d_in[10];
    const float* bc  = (const float*)d_in[11];
    const float* Wk1 = (const float*)d_in[12];
    const float* bk1 = (const float*)d_in[13];
    const float* Wk2 = (const float*)d_in[14];
    const float* bk2 = (const float*)d_in[15];
    const float* Wp1 = (const float*)d_in[16];
    const float* bp1 = (const float*)d_in[17];
    const float* Wp2 = (const float*)d_in[18];
    const float* bp2 = (const float*)d_in[19];
    float* out = (float*)d_out;

    char* ws = (char*)d_ws;
    size_t off = 0;
    unsigned short* pfb = (unsigned short*)(ws + off); off += (size_t)NP * 128 * 2;  // 4.19 MB
    unsigned short* lfb = (unsigned short*)(ws + off); off += (size_t)NP * 128 * 2;  // 4.19 MB
    float* u  = (float*)(ws + off);       off += (size_t)NP * 128 * 4;   // 8.39 MB
    float* v  = (float*)(ws + off);       off += (size_t)NP * 128 * 4;   // 8.39 MB
    int* knn  = (int*)(ws + off);         off += (size_t)NP * 16 * 4;    // 1.05 MB
    float* gf = (float*)(ws + off);       off += 2048;
    float4* pts4 = (float4*)(ws + off);   off += (size_t)NP * 16;        // 256 KB
    float* bias_cat = (float*)(ws + off); off += 1024;
    unsigned short* WuvT = (unsigned short*)(ws + off); off += 256 * 128 * 2;
    unsigned short* Wl2T = (unsigned short*)(ws + off); off += 128 * 128 * 2;
    unsigned short* WcT  = (unsigned short*)(ws + off); off += 256 * 256 * 2;
    unsigned short* Wk1T = (unsigned short*)(ws + off); off += 128 * 512 * 2;
    unsigned short* Wp1T = (unsigned short*)(ws + off); off += 128 * 512 * 2;
    unsigned short* We2T = (unsigned short*)(ws + off); off += 128 * 128 * 2;
    unsigned short* h1   = (unsigned short*)(ws + off); off += (size_t)NP * 128 * 2;  // 4.19 MB

    hipLaunchKernelGGL(k_h1, dim3(2048), dim3(256), 0, stream,
                       pts, nrm, We1, be1, h1, gf, pts4);
    hipLaunchKernelGGL(k_prep, dim3(64), dim3(256), 0, stream,
                       Wl1, bl1, Wl2, Wc, Wk1, Wp1, We2,
                       WuvT, bias_cat, Wl2T, WcT, Wk1T, Wp1T, We2T);
    hipLaunchKernelGGL(k_knn, dim3(4096), dim3(256), 0, stream, pts4, knn);
    hipLaunchKernelGGL(k_pf2, dim3(256), dim3(256), 0, stream,
                       h1, We2T, be2, pfb);
    hipLaunchKernelGGL(k_uv, dim3(128, 2), dim3(256), 0, stream,
                       pfb, WuvT, bias_cat, u, v);
    hipLaunchKernelGGL(k_edge, dim3(2048), dim3(256), 0, stream,
                       u, v, knn, Wl2T, bl2, lfb);
    hipLaunchKernelGGL(k_ctx, dim3(128, 2), dim3(256), 0, stream,
                       pfb, lfb, WcT, bc, gf);
    hipLaunchKernelGGL(k_head, dim3(128, 2), dim3(256), 0, stream,
                       pfb, lfb, gf, Wk1T, bk1, Wk2, bk2, Wp1T, bp1, Wp2, bp2, out);
}

// Round 15
// 320.586 us; speedup vs baseline: 4.0065x; 1.0632x over previous
//
#include <hip/hip_runtime.h>

#define B_ 2
#define N_ 8192
#define NP 16384   // B_*N_
#define K_ 16
#define H_ 128
#define KCAP 512

typedef short bf16x8 __attribute__((ext_vector_type(8)));
typedef float f32x4 __attribute__((ext_vector_type(4)));

__device__ inline unsigned short f2b(float f) {
    unsigned u = __builtin_bit_cast(unsigned, f);
    unsigned r = (u + 0x7fff + ((u >> 16) & 1)) >> 16;
    return (unsigned short)r;
}
__device__ inline bf16x8 ldb8(const unsigned short* p) {
    return *(const bf16x8*)p;
}

// ---- Kernel H: h1 = relu(x@We1+be1) bf16; pack pts4; zero gf --------------
__global__ __launch_bounds__(256) void k_h1(
    const float* __restrict__ pts, const float* __restrict__ nrm,
    const float* __restrict__ We1, const float* __restrict__ be1,
    unsigned short* __restrict__ h1, float* __restrict__ gf,
    float4* __restrict__ pts4) {
    int tid = blockIdx.x * 256 + threadIdx.x;
    if (blockIdx.x == 0) { gf[threadIdx.x] = 0.f; gf[256 + threadIdx.x] = 0.f; }
    if (tid < NP) {
        int p = tid;
        float x = pts[p * 3], y = pts[p * 3 + 1], z = pts[p * 3 + 2];
        float sq = __fadd_rn(__fadd_rn(__fmul_rn(x, x), __fmul_rn(y, y)), __fmul_rn(z, z));
        pts4[p] = make_float4(x, y, z, sq);
    }
    for (int o = tid; o < NP * 128; o += gridDim.x * 256) {
        int p = o >> 7, h = o & 127;
        float a = be1[h];
        a += pts[p * 3]     * We1[0 * 128 + h];
        a += pts[p * 3 + 1] * We1[1 * 128 + h];
        a += pts[p * 3 + 2] * We1[2 * 128 + h];
        a += nrm[p * 3]     * We1[3 * 128 + h];
        a += nrm[p * 3 + 1] * We1[4 * 128 + h];
        a += nrm[p * 3 + 2] * We1[5 * 128 + h];
        h1[o] = f2b(fmaxf(a, 0.f));
    }
}

// ---------------- Kernel P: prep factored + transposed bf16 weights --------
__global__ __launch_bounds__(256) void k_prep(
    const float* __restrict__ Wl1, const float* __restrict__ bl1,
    const float* __restrict__ Wl2, const float* __restrict__ Wc,
    const float* __restrict__ Wk1, const float* __restrict__ Wp1,
    const float* __restrict__ We2,
    unsigned short* __restrict__ WuvT, float* __restrict__ bias_cat,
    unsigned short* __restrict__ Wl2T, unsigned short* __restrict__ WcT,
    unsigned short* __restrict__ Wk1T, unsigned short* __restrict__ Wp1T,
    unsigned short* __restrict__ We2T) {
    int tid = blockIdx.x * 256 + threadIdx.x;
    int stride = gridDim.x * 256;
    for (int i = tid; i < 256 * 128; i += stride) {
        int n = i >> 7, k = i & 127;
        float val = (n < 128) ? Wl1[k * 128 + n] - Wl1[(k + 128) * 128 + n]
                              : Wl1[(k + 128) * 128 + (n - 128)];
        WuvT[i] = f2b(val);
    }
    for (int i = tid; i < 256; i += stride) bias_cat[i] = (i < 128) ? bl1[i] : 0.f;
    for (int i = tid; i < 128 * 128; i += stride) {
        int n = i >> 7, k = i & 127;
        Wl2T[i] = f2b(Wl2[k * 128 + n]);
        We2T[i] = f2b(We2[k * 128 + n]);
    }
    for (int i = tid; i < 256 * 256; i += stride) {
        int n = i >> 8, k = i & 255;
        WcT[i] = f2b(Wc[k * 256 + n]);
    }
    for (int i = tid; i < 128 * 512; i += stride) {
        int n = i >> 9, k = i & 511;
        Wk1T[i] = f2b(Wk1[k * 128 + n]);
        Wp1T[i] = f2b(Wp1[k * 128 + n]);
    }
}

// ---- Kernel PF2: pfb(bf16) = relu(h1 @ We2T^T + be2), direct-global -------
__global__ __launch_bounds__(256) void k_pf2(
    const unsigned short* __restrict__ h1, const unsigned short* __restrict__ We2T,
    const float* __restrict__ be2, unsigned short* __restrict__ pfb) {
    int t = threadIdx.x, l = t & 63, w = t >> 6;
    int row0 = blockIdx.x * 64 + w * 16;
    f32x4 acc[8];
    #pragma unroll
    for (int nj = 0; nj < 8; ++nj) acc[nj] = (f32x4){0.f, 0.f, 0.f, 0.f};
    #pragma unroll
    for (int ks = 0; ks < 4; ++ks) {
        bf16x8 a = ldb8(&h1[(size_t)(row0 + (l & 15)) * 128 + ks * 32 + (l >> 4) * 8]);
        #pragma unroll
        for (int nj = 0; nj < 8; ++nj) {
            bf16x8 bfr = ldb8(&We2T[(size_t)(nj * 16 + (l & 15)) * 128 + ks * 32 + (l >> 4) * 8]);
            acc[nj] = __builtin_amdgcn_mfma_f32_16x16x32_bf16(a, bfr, acc[nj], 0, 0, 0);
        }
    }
    #pragma unroll
    for (int nj = 0; nj < 8; ++nj) {
        int col = nj * 16 + (l & 15);
        float bias = be2[col];
        #pragma unroll
        for (int rg = 0; rg < 4; ++rg) {
            int row = row0 + (l >> 4) * 4 + rg;
            pfb[(size_t)row * 128 + col] = f2b(fmaxf(acc[nj][rg] + bias, 0.f));
        }
    }
}

// ---- scan helper: first bucket with cumcount >= 16 -> float threshold -----
__device__ inline float knn_thresh(const int* __restrict__ hh, int l) {
    int h0 = hh[4 * l], h1 = hh[4 * l + 1], h2 = hh[4 * l + 2], h3 = hh[4 * l + 3];
    int c0 = h0, c1 = c0 + h1, c2 = c1 + h2, c3 = c2 + h3;
    int tot = c3;
    int inc = tot;
    for (int off = 1; off < 64; off <<= 1) {
        int vv = __shfl_up(inc, off);
        if (l >= off) inc += vv;
    }
    int excl = inc - tot;
    int Bc = 255;
    if      (excl + c0 >= 16) Bc = 4 * l;
    else if (excl + c1 >= 16) Bc = 4 * l + 1;
    else if (excl + c2 >= 16) Bc = 4 * l + 2;
    else if (excl + c3 >= 16) Bc = 4 * l + 3;
    for (int m = 1; m < 64; m <<= 1) Bc = min(Bc, __shfl_xor(Bc, m));
    return __uint_as_float((unsigned)(Bc + 401) << 21);
}

// ------- Kernel B: 16-NN. 1 query/wave, barrier-free; atomic-append u32
//         survivors (order-free: extraction sorts); exact d2 recompute at
//         extraction; pre-doubled q (bit-identical: rn(2u)=2*rn(u)). --------
__global__ __launch_bounds__(256) void k_knn(
    const float4* __restrict__ pts4, int* __restrict__ knn) {
    __shared__ int hist[4][260];           // 4.16 KB
    __shared__ unsigned buf[4][KCAP];      // 8 KB (u32 idx only)
    __shared__ int wcnt[4];
    int t = threadIdx.x, w = t >> 6, l = t & 63;
    int b = blockIdx.x >> 11;
    int q = (blockIdx.x & 2047) * 4 + w;
    const float4* pb = pts4 + b * N_;
    float4 qp = pb[q];
    float q2x = 2.f * qp.x, q2y = 2.f * qp.y, q2z = 2.f * qp.z;  // exact
    for (int i = l; i < 256; i += 64) hist[w][i] = 0;
    if (l == 0) wcnt[w] = 0;

    // ---- histogram over first 1024 candidates (self -> bucket 255)
    #pragma unroll 2
    for (int i = 0; i < 16; ++i) {
        int j = l + 64 * i;
        float4 c = pb[j];
        float dot2 = __fadd_rn(__fadd_rn(__fmul_rn(q2x, c.x), __fmul_rn(q2y, c.y)), __fmul_rn(q2z, c.z));
        float d2 = __fsub_rn(__fadd_rn(qp.w, c.w), dot2);
        d2 = (j == q) ? 1e30f : d2;
        unsigned uu = __float_as_uint(d2);
        int bk = (d2 < 0.f) ? 0 : min(255, max(0, (int)(uu >> 21) - 400));
        atomicAdd(&hist[w][bk], 1);
    }
    float Tf = knn_thresh(&hist[w][0], l);

    // ---- single filter pass, atomic append (self d2=0 < Tf always enters)
    #pragma unroll 4
    for (int i = 0; i < 128; ++i) {
        int j = l + 64 * i;
        float4 c = pb[j];
        float dot2 = __fadd_rn(__fadd_rn(__fmul_rn(q2x, c.x), __fmul_rn(q2y, c.y)), __fmul_rn(q2z, c.z));
        float d2 = __fsub_rn(__fadd_rn(qp.w, c.w), dot2);
        if (d2 < Tf) {
            int pos = atomicAdd(&wcnt[w], 1);
            if (pos < KCAP) buf[w][pos] = (unsigned)j;
        }
    }
    int m_ = min(wcnt[w], KCAP);

    // ---- extraction: rebuild u64 keys with exact d2 recompute; 17 rounds
    unsigned long long key[8];
    #pragma unroll
    for (int r = 0; r < 8; ++r) {
        int e = l + 64 * r;
        if (e < m_) {
            int idx = (int)buf[w][e];
            float4 c = pb[idx];
            float dot2 = __fadd_rn(__fadd_rn(__fmul_rn(q2x, c.x), __fmul_rn(q2y, c.y)), __fmul_rn(q2z, c.z));
            float d2 = __fsub_rn(__fadd_rn(qp.w, c.w), dot2);
            unsigned du = __float_as_uint(d2);
            unsigned mu = du ^ (unsigned)(((int)du >> 31) | 0x80000000);
            key[r] = ((unsigned long long)mu << 32) | (unsigned)idx;
        } else key[r] = ~0ull;
    }
    unsigned long long lmin = key[0];
    #pragma unroll
    for (int r = 1; r < 8; ++r) lmin = (key[r] < lmin) ? key[r] : lmin;
    int emitted = 0;
    for (int r17 = 0; r17 < 17 && emitted < 16; ++r17) {
        unsigned long long wv = lmin;
        for (int m = 1; m < 64; m <<= 1) {
            unsigned long long o = __shfl_xor(wv, m);
            wv = (o < wv) ? o : wv;
        }
        int idx = (int)(wv & 0xffffffffu);
        if (idx != q) {
            if (l == 0) knn[((size_t)b * N_ + q) * 16 + emitted] = b * N_ + idx;
            ++emitted;
        }
        if (lmin == wv) {
            #pragma unroll
            for (int r = 0; r < 8; ++r) if (key[r] == wv) key[r] = ~0ull;
            lmin = key[0];
            #pragma unroll
            for (int r = 1; r < 8; ++r) lmin = (key[r] < lmin) ? key[r] : lmin;
        }
    }
}

// ---- Kernel U: uv = pfb @ WuvT^T + bias_cat (A and B direct-global) -------
__global__ __launch_bounds__(256) void k_uv(
    const unsigned short* __restrict__ pfb, const unsigned short* __restrict__ WuvT,
    const float* __restrict__ bias_cat,
    float* __restrict__ u, float* __restrict__ v) {
    int t = threadIdx.x;
    int l = t & 63, w = t >> 6;
    int wr = w >> 1, wcn = w & 1;
    int rowbase = blockIdx.x * 128;
    int ncol0 = blockIdx.y * 128;

    f32x4 acc[4][4];
    #pragma unroll
    for (int i = 0; i < 4; ++i)
        #pragma unroll
        for (int j = 0; j < 4; ++j) acc[i][j] = (f32x4){0.f, 0.f, 0.f, 0.f};

    #pragma unroll
    for (int ks = 0; ks < 4; ++ks) {
        bf16x8 bfr[4], afr[4];
        #pragma unroll
        for (int nj = 0; nj < 4; ++nj)
            bfr[nj] = ldb8(&WuvT[(size_t)(ncol0 + wcn * 64 + nj * 16 + (l & 15)) * 128 + ks * 32 + (l >> 4) * 8]);
        #pragma unroll
        for (int mi = 0; mi < 4; ++mi)
            afr[mi] = ldb8(&pfb[(size_t)(rowbase + wr * 64 + mi * 16 + (l & 15)) * 128 + ks * 32 + (l >> 4) * 8]);
        #pragma unroll
        for (int mi = 0; mi < 4; ++mi)
            #pragma unroll
            for (int nj = 0; nj < 4; ++nj)
                acc[mi][nj] = __builtin_amdgcn_mfma_f32_16x16x32_bf16(afr[mi], bfr[nj], acc[mi][nj], 0, 0, 0);
    }
    float* outp = (ncol0 == 0) ? u : v;
    #pragma unroll
    for (int mi = 0; mi < 4; ++mi)
        #pragma unroll
        for (int nj = 0; nj < 4; ++nj) {
            int col = wcn * 64 + nj * 16 + (l & 15);
            float bias = bias_cat[ncol0 + col];
            #pragma unroll
            for (int rg = 0; rg < 4; ++rg) {
                int row = wr * 64 + mi * 16 + (l >> 4) * 4 + rg;
                outp[(size_t)(rowbase + row) * 128 + col] = acc[mi][nj][rg] + bias;
            }
        }
}

// ---------------- Kernel C: edge layer2 GEMM + max over K -> lfb bf16 ------
__global__ __launch_bounds__(256) void k_edge(
    const float* __restrict__ u, const float* __restrict__ v,
    const int* __restrict__ knn, const unsigned short* __restrict__ Wl2T,
    const float* __restrict__ bl2, unsigned short* __restrict__ lfb) {
    __shared__ __align__(16) unsigned short h1s[128 * 136];  // 34816 B
    int t = threadIdx.x;
    int l = t & 63, w = t >> 6;
    int wr = w >> 1, wcn = w & 1;
    int rowbase = blockIdx.x * 128;
    int p0 = blockIdx.x * 8;

    #pragma unroll 2
    for (int i = 0; i < 8; ++i) {
        int ci = t + 256 * i;
        int r = ci >> 4, c8 = (ci & 15) * 8;
        int nb = knn[rowbase + r];
        int pt = p0 + (r >> 4);
        const float4* vp = (const float4*)(v + (size_t)nb * 128 + c8);
        const float4* up = (const float4*)(u + (size_t)pt * 128 + c8);
        float4 va = vp[0], vb = vp[1];
        float4 ua = up[0], ub = up[1];
        unsigned d0 = (unsigned)f2b(fmaxf(ua.x + va.x, 0.f)) | ((unsigned)f2b(fmaxf(ua.y + va.y, 0.f)) << 16);
        unsigned d1 = (unsigned)f2b(fmaxf(ua.z + va.z, 0.f)) | ((unsigned)f2b(fmaxf(ua.w + va.w, 0.f)) << 16);
        unsigned d2 = (unsigned)f2b(fmaxf(ub.x + vb.x, 0.f)) | ((unsigned)f2b(fmaxf(ub.y + vb.y, 0.f)) << 16);
        unsigned d3 = (unsigned)f2b(fmaxf(ub.z + vb.z, 0.f)) | ((unsigned)f2b(fmaxf(ub.w + vb.w, 0.f)) << 16);
        uint4 pk; pk.x = d0; pk.y = d1; pk.z = d2; pk.w = d3;
        *(uint4*)&h1s[r * 136 + c8] = pk;
    }
    __syncthreads();

    f32x4 acc[4][4];
    #pragma unroll
    for (int i = 0; i < 4; ++i)
        #pragma unroll
        for (int j = 0; j < 4; ++j) acc[i][j] = (f32x4){0.f, 0.f, 0.f, 0.f};

    #pragma unroll
    for (int ks = 0; ks < 4; ++ks) {
        bf16x8 bfr[4], afr[4];
        #pragma unroll
        for (int nj = 0; nj < 4; ++nj)
            bfr[nj] = ldb8(&Wl2T[(size_t)(wcn * 64 + nj * 16 + (l & 15)) * 128 + ks * 32 + (l >> 4) * 8]);
        #pragma unroll
        for (int mi = 0; mi < 4; ++mi)
            afr[mi] = ldb8(&h1s[(wr * 64 + mi * 16 + (l & 15)) * 136 + ks * 32 + (l >> 4) * 8]);
        #pragma unroll
        for (int mi = 0; mi < 4; ++mi)
            #pragma unroll
            for (int nj = 0; nj < 4; ++nj)
                acc[mi][nj] = __builtin_amdgcn_mfma_f32_16x16x32_bf16(afr[mi], bfr[nj], acc[mi][nj], 0, 0, 0);
    }

    #pragma unroll
    for (int mi = 0; mi < 4; ++mi)
        #pragma unroll
        for (int nj = 0; nj < 4; ++nj) {
            int col = wcn * 64 + nj * 16 + (l & 15);
            float bias = bl2[col];
            float m = fmaxf(acc[mi][nj][0] + bias, 0.f);
            m = fmaxf(m, fmaxf(acc[mi][nj][1] + bias, 0.f));
            m = fmaxf(m, fmaxf(acc[mi][nj][2] + bias, 0.f));
            m = fmaxf(m, fmaxf(acc[mi][nj][3] + bias, 0.f));
            m = fmaxf(m, __shfl_xor(m, 16));
            m = fmaxf(m, __shfl_xor(m, 32));
            if (l < 16) lfb[(size_t)(p0 + wr * 4 + mi) * 128 + col] = f2b(m);
        }
}

// -- Kernel D: ctx col-max fused in-register; LDS-free (A direct-global) ----
__global__ __launch_bounds__(256) void k_ctx(
    const unsigned short* __restrict__ pfb, const unsigned short* __restrict__ lfb,
    const unsigned short* __restrict__ WcT, const float* __restrict__ bc,
    float* __restrict__ gf) {
    int t = threadIdx.x;
    int l = t & 63, w = t >> 6;
    int wr = w >> 1, wcn = w & 1;
    int rowbase = blockIdx.x * 128;
    int ncol0 = blockIdx.y * 128;
    int b = rowbase >> 13;

    f32x4 acc[4][4];
    #pragma unroll
    for (int i = 0; i < 4; ++i)
        #pragma unroll
        for (int j = 0; j < 4; ++j) acc[i][j] = (f32x4){0.f, 0.f, 0.f, 0.f};

    #pragma unroll
    for (int kb = 0; kb < 2; ++kb) {
        const unsigned short* srcb = kb ? lfb : pfb;
        #pragma unroll
        for (int ks = 0; ks < 4; ++ks) {
            bf16x8 bfr[4], afr[4];
            #pragma unroll
            for (int nj = 0; nj < 4; ++nj)
                bfr[nj] = ldb8(&WcT[(size_t)(ncol0 + wcn * 64 + nj * 16 + (l & 15)) * 256 + kb * 128 + ks * 32 + (l >> 4) * 8]);
            #pragma unroll
            for (int mi = 0; mi < 4; ++mi)
                afr[mi] = ldb8(&srcb[(size_t)(rowbase + wr * 64 + mi * 16 + (l & 15)) * 128 + ks * 32 + (l >> 4) * 8]);
            #pragma unroll
            for (int mi = 0; mi < 4; ++mi)
                #pragma unroll
                for (int nj = 0; nj < 4; ++nj)
                    acc[mi][nj] = __builtin_amdgcn_mfma_f32_16x16x32_bf16(afr[mi], bfr[nj], acc[mi][nj], 0, 0, 0);
        }
    }
    #pragma unroll
    for (int nj = 0; nj < 4; ++nj) {
        int col = ncol0 + wcn * 64 + nj * 16 + (l & 15);
        float m = acc[0][nj][0];
        #pragma unroll
        for (int mi = 0; mi < 4; ++mi)
            #pragma unroll
            for (int rg = 0; rg < 4; ++rg) m = fmaxf(m, acc[mi][nj][rg]);
        m = fmaxf(m + bc[col], 0.f);
        m = fmaxf(m, __shfl_xor(m, 16));
        m = fmaxf(m, __shfl_xor(m, 32));
        if (l < 16) atomicMax((unsigned int*)&gf[b * 256 + col], __float_as_uint(m));
    }
}

// ---------------- Kernel E: heads (pf/lf direct-global, gf tiny LDS) -------
__global__ __launch_bounds__(256) void k_head(
    const unsigned short* __restrict__ pfb, const unsigned short* __restrict__ lfb,
    const float* __restrict__ gf,
    const unsigned short* __restrict__ Wk1T, const float* __restrict__ bk1,
    const float* __restrict__ Wk2, const float* __restrict__ bk2,
    const unsigned short* __restrict__ Wp1T, const float* __restrict__ bp1,
    const float* __restrict__ Wp2, const float* __restrict__ bp2,
    float* __restrict__ out) {
    __shared__ float hs[128 * 132];          // 67584 B
    __shared__ unsigned short gfs[256];      // 512 B
    int t = threadIdx.x;
    int l = t & 63, w = t >> 6;
    int wr = w >> 1, wcn = w & 1;
    int rowbase = blockIdx.x * 128;
    int b = rowbase >> 13;
    int br = blockIdx.y;
    const unsigned short* W1T = br ? Wp1T : Wk1T;
    const float* b1 = br ? bp1 : bk1;
    const float* W2 = br ? Wp2 : Wk2;
    const float* b2p = br ? bp2 : bk2;
    int OC = br ? 8 : 10;
    float* obase = out + (br ? (size_t)NP * 10 : 0);

    gfs[t] = f2b(gf[b * 256 + t]);
    __syncthreads();

    f32x4 acc[4][4];
    #pragma unroll
    for (int i = 0; i < 4; ++i)
        #pragma unroll
        for (int j = 0; j < 4; ++j) acc[i][j] = (f32x4){0.f, 0.f, 0.f, 0.f};

    #pragma unroll
    for (int kb = 0; kb < 4; ++kb) {
        #pragma unroll
        for (int ks = 0; ks < 4; ++ks) {
            bf16x8 bfr[4], afr[4];
            #pragma unroll
            for (int nj = 0; nj < 4; ++nj)
                bfr[nj] = ldb8(&W1T[(size_t)(wcn * 64 + nj * 16 + (l & 15)) * 512 + kb * 128 + ks * 32 + (l >> 4) * 8]);
            #pragma unroll
            for (int mi = 0; mi < 4; ++mi) {
                if (kb == 0)
                    afr[mi] = ldb8(&pfb[(size_t)(rowbase + wr * 64 + mi * 16 + (l & 15)) * 128 + ks * 32 + (l >> 4) * 8]);
                else if (kb == 1)
                    afr[mi] = ldb8(&lfb[(size_t)(rowbase + wr * 64 + mi * 16 + (l & 15)) * 128 + ks * 32 + (l >> 4) * 8]);
                else
                    afr[mi] = ldb8(&gfs[(kb - 2) * 128 + ks * 32 + (l >> 4) * 8]);  // row-broadcast
            }
            #pragma unroll
            for (int mi = 0; mi < 4; ++mi)
                #pragma unroll
                for (int nj = 0; nj < 4; ++nj)
                    acc[mi][nj] = __builtin_amdgcn_mfma_f32_16x16x32_bf16(afr[mi], bfr[nj], acc[mi][nj], 0, 0, 0);
        }
    }
    #pragma unroll
    for (int mi = 0; mi < 4; ++mi)
        #pragma unroll
        for (int nj = 0; nj < 4; ++nj)
            #pragma unroll
            for (int rg = 0; rg < 4; ++rg) {
                int row = wr * 64 + mi * 16 + (l >> 4) * 4 + rg;
                int col = wcn * 64 + nj * 16 + (l & 15);
                hs[row * 132 + col] = fmaxf(acc[mi][nj][rg] + b1[col], 0.f);
            }
    __syncthreads();
    for (int o = t; o < 128 * OC; o += 256) {
        int r = o / OC, c = o % OC;
        float a = b2p[c];
        for (int k2 = 0; k2 < 128; ++k2) a += hs[r * 132 + k2] * W2[k2 * OC + c];
        obase[(size_t)(rowbase + r) * OC + c] = a;
    }
}

extern "C" void kernel_launch(void* const* d_in, const int* in_sizes, int n_in,
                              void* d_out, int out_size, void* d_ws, size_t ws_size,
                              hipStream_t stream) {
    const float* pts = (const float*)d_in[0];
    const float* nrm = (const float*)d_in[1];
    const float* We1 = (const float*)d_in[2];
    const float* be1 = (const float*)d_in[3];
    const float* We2 = (const float*)d_in[4];
    const float* be2 = (const float*)d_in[5];
    const float* Wl1 = (const float*)d_in[6];
    const float* bl1 = (const float*)d_in[7];
    const float* Wl2 = (const float*)d_in[8];
    const float* bl2 = (const float*)d_in[9];
    const float* Wc  = (const float*)d_in[10];
    const float* bc  = (const float*)d_in[11];
    const float* Wk1 = (const float*)d_in[12];
    const float* bk1 = (const float*)d_in[13];
    const float* Wk2 = (const float*)d_in[14];
    const float* bk2 = (const float*)d_in[15];
    const float* Wp1 = (const float*)d_in[16];
    const float* bp1 = (const float*)d_in[17];
    const float* Wp2 = (const float*)d_in[18];
    const float* bp2 = (const float*)d_in[19];
    float* out = (float*)d_out;

    char* ws = (char*)d_ws;
    size_t off = 0;
    unsigned short* pfb = (unsigned short*)(ws + off); off += (size_t)NP * 128 * 2;  // 4.19 MB
    unsigned short* lfb = (unsigned short*)(ws + off); off += (size_t)NP * 128 * 2;  // 4.19 MB
    float* u  = (float*)(ws + off);       off += (size_t)NP * 128 * 4;   // 8.39 MB
    float* v  = (float*)(ws + off);       off += (size_t)NP * 128 * 4;   // 8.39 MB
    int* knn  = (int*)(ws + off);         off += (size_t)NP * 16 * 4;    // 1.05 MB
    float* gf = (float*)(ws + off);       off += 2048;
    float4* pts4 = (float4*)(ws + off);   off += (size_t)NP * 16;        // 256 KB
    float* bias_cat = (float*)(ws + off); off += 1024;
    unsigned short* WuvT = (unsigned short*)(ws + off); off += 256 * 128 * 2;
    unsigned short* Wl2T = (unsigned short*)(ws + off); off += 128 * 128 * 2;
    unsigned short* WcT  = (unsigned short*)(ws + off); off += 256 * 256 * 2;
    unsigned short* Wk1T = (unsigned short*)(ws + off); off += 128 * 512 * 2;
    unsigned short* Wp1T = (unsigned short*)(ws + off); off += 128 * 512 * 2;
    unsigned short* We2T = (unsigned short*)(ws + off); off += 128 * 128 * 2;
    unsigned short* h1   = (unsigned short*)(ws + off); off += (size_t)NP * 128 * 2;  // 4.19 MB

    hipLaunchKernelGGL(k_h1, dim3(2048), dim3(256), 0, stream,
                       pts, nrm, We1, be1, h1, gf, pts4);
    hipLaunchKernelGGL(k_prep, dim3(64), dim3(256), 0, stream,
                       Wl1, bl1, Wl2, Wc, Wk1, Wp1, We2,
                       WuvT, bias_cat, Wl2T, WcT, Wk1T, Wp1T, We2T);
    hipLaunchKernelGGL(k_knn, dim3(4096), dim3(256), 0, stream, pts4, knn);
    hipLaunchKernelGGL(k_pf2, dim3(256), dim3(256), 0, stream,
                       h1, We2T, be2, pfb);
    hipLaunchKernelGGL(k_uv, dim3(128, 2), dim3(256), 0, stream,
                       pfb, WuvT, bias_cat, u, v);
    hipLaunchKernelGGL(k_edge, dim3(2048), dim3(256), 0, stream,
                       u, v, knn, Wl2T, bl2, lfb);
    hipLaunchKernelGGL(k_ctx, dim3(128, 2), dim3(256), 0, stream,
                       pfb, lfb, WcT, bc, gf);
    hipLaunchKernelGGL(k_head, dim3(128, 2), dim3(256), 0, stream,
                       pfb, lfb, gf, Wk1T, bk1, Wk2, bk2, Wp1T, bp1, Wp2, bp2, out);
}